// Round 5
// baseline (986.567 us; speedup 1.0000x reference)
//
#include <hip/hip_runtime.h>
#include <hip/hip_bf16.h>
#include <math.h>

#define GG 256
#define NP 24
#define LL 3
#define CC 256
#define NN (GG*NP)   // 6144 nodes
#define HH 4
#define DH 64

typedef __hip_bfloat16 bf;
typedef __attribute__((ext_vector_type(8))) short bfrag;   // 8 bf16 (4 VGPR)
typedef __attribute__((ext_vector_type(4))) float ffrag;   // 4 fp32 acc

__device__ __forceinline__ short pk(float x) {
    union { bf h; short s; } u; u.h = __float2bfloat16(x); return u.s;
}
__device__ __forceinline__ float b2f_s(short x) {
    union { short s; bf h; } u; u.s = x; return __bfloat162float(u.h);
}

// ---------------------------------------------------------------------------
__global__ void detect_int_k(const unsigned int* __restrict__ at, int* flags) {
    __shared__ int ok;
    if (threadIdx.x == 0) ok = 1;
    __syncthreads();
    if (at[2 * threadIdx.x + 1] != 0u) ok = 0;   // benign race
    __syncthreads();
    if (threadIdx.x == 0) flags[0] = ok;
}

__global__ void signal_k(float* out, int n, float val) {
    int i = blockIdx.x * 256 + threadIdx.x;
    if (i < n) out[i] = val;
}

// ---------------------------------------------------------------------------
// Combined weight prep (9 segments in ONE dispatch): fp32 [L][K][N] ->
// bf16 [L][N][K] at wt+dstOff.
// ---------------------------------------------------------------------------
struct TArgs {
    const float* src[9];
    long dstOff[9];
    int K[9], N[9], L[9];
    int blk0[10];
};
__global__ void transp_all(TArgs a, bf* __restrict__ wt) {
    int bid = blockIdx.x;
    int s = 0;
    while (s < 8 && bid >= a.blk0[s + 1]) ++s;
    long idx = (long)(bid - a.blk0[s]) * 256 + threadIdx.x;
    int KN = a.K[s] * a.N[s];
    long sz = (long)KN * a.L[s];
    if (idx >= sz) return;
    int l = (int)(idx / KN);
    int rem = (int)(idx % KN);
    int k = rem / a.N[s], n = rem % a.N[s];
    wt[a.dstOff[s] + (long)l * KN + (long)n * a.K[s] + k] =
        __float2bfloat16(a.src[s][idx]);
}

// ---------------------------------------------------------------------------
// GINE edge-weight prep: geW fp32 [L][69][256] -> split bf16 W^T
// [L][half][n 0..127][k 0..63] (k<60 real, else 0), hi and lo parts.
// ---------------------------------------------------------------------------
__global__ void prep_gew(const float* __restrict__ geW, short* __restrict__ wh,
                         short* __restrict__ wl) {
    int idx = blockIdx.x * 256 + threadIdx.x;   // 3*2*128*64 = 49152
    if (idx >= 49152) return;
    int k = idx & 63;
    int n = (idx >> 6) & 127;
    int half = (idx >> 13) & 1;
    int l = idx >> 14;
    float v = (k < 60) ? geW[(long)l * 69 * 256 + (long)k * 256 + half * 128 + n] : 0.f;
    short hi = pk(v);
    short lo = pk(v - b2f_s(hi));
    wh[idx] = hi;
    wl[idx] = lo;
}

// ---------------------------------------------------------------------------
// E-table precompute: sin/cos edge features depend only on frac — layer- and
// half-independent. Built once, bit-identically to the original in-kernel
// expression, in MFMA-fragment layout [(g*24+j)*24+i][k 0..63].
// ---------------------------------------------------------------------------
#define ETAB_ELEMS (GG * 24 * 24 * 64)   // 9437184
__global__ void prep_etab(const float* __restrict__ frac, short* __restrict__ eh,
                          short* __restrict__ el) {
    int idx = blockIdx.x * 256 + threadIdx.x;
    if (idx >= ETAB_ELEMS) return;
    int k = idx & 63;
    int rem = idx >> 6;           // (g*24 + j)*24 + i
    int i = rem % 24;
    int rem2 = rem / 24;
    int j = rem2 % 24;
    int g = rem2 / 24;
    float val = 0.f;
    if (k < 60) {
        int r = (k < 30) ? k : k - 30;
        int d = r / 10, f = r % 10;
        float fd = frac[g * 72 + j * 3 + d] - frac[g * 72 + i * 3 + d];
        fd -= floorf(fd);
        float ang = 6.283185307179586f * (float)f * fd;
        val = (k < 30) ? sinf(ang) : cosf(ang);
    }
    short hi = pk(val);
    eh[idx] = hi;
    el[idx] = pk(val - b2f_s(hi));
}

// ---------------------------------------------------------------------------
// A = [type_emb[atom_types] | time_emb]  (N x 512, fp32)
// ---------------------------------------------------------------------------
__global__ void build_A(const float* __restrict__ t, const float* __restrict__ type_emb,
                        const unsigned int* __restrict__ atoms,
                        float* __restrict__ A, const int* __restrict__ flags) {
    int i64 = flags[0];
    int idx = blockIdx.x * 256 + threadIdx.x;
    if (idx >= NN * 512) return;
    int n = idx >> 9;
    int k = idx & 511;
    if (k < 256) {
        int a = i64 ? (int)atoms[2 * n] : (int)atoms[n];
        A[idx] = type_emb[(long)a * CC + k];
    } else {
        int d = k - 256;
        int g = n / NP;
        float tv = t[g];
        int dd = (d < 128) ? d : d - 128;
        float tf = expf(dd * (-9.210340371976184f / 127.0f));
        float ang = tv * tf;
        A[idx] = (d < 128) ? sinf(ang) : cosf(ang);
    }
}

// ---------------------------------------------------------------------------
// MFMA bf16 GEMM (validated R11). C = epi(A@W + bias) (+res), Wt = bf16 W^T.
// ---------------------------------------------------------------------------
__global__ __launch_bounds__(256) void gemm_mfma(
        const float* __restrict__ A, const bf* __restrict__ Wt,
        const float* __restrict__ bias, const float* __restrict__ res,
        float* __restrict__ C, int M, int K, int N, int act) {
    __shared__ short As[64 * 40];
    __shared__ short Bs[128 * 40];
    int tid = threadIdx.x;
    int lane = tid & 63, w = tid >> 6;
    int wm = w & 1, wn = w >> 1;
    int m0 = blockIdx.x * 64, n0 = blockIdx.y * 128;
    ffrag acc[2][4] = {};
    int sa_m = tid >> 2, sa_k = (tid & 3) << 3;
    int sb_n = tid >> 1, sb_k = (tid & 1) << 4;
    int fr_row = lane & 15, fr_k = (lane >> 4) << 3;

    for (int k0 = 0; k0 < K; k0 += 32) {
        const float* Ap = A + (long)(m0 + sa_m) * K + k0 + sa_k;
        float4 a1 = *(const float4*)Ap;
        float4 a2 = *(const float4*)(Ap + 4);
        const float4* Bp = (const float4*)(Wt + (long)(n0 + sb_n) * K + k0 + sb_k);
        float4 b1 = Bp[0], b2 = Bp[1];
        __syncthreads();
        bfrag av;
        av[0] = pk(a1.x); av[1] = pk(a1.y); av[2] = pk(a1.z); av[3] = pk(a1.w);
        av[4] = pk(a2.x); av[5] = pk(a2.y); av[6] = pk(a2.z); av[7] = pk(a2.w);
        *(bfrag*)(&As[sa_m * 40 + sa_k]) = av;
        *(float4*)(&Bs[sb_n * 40 + sb_k]) = b1;
        *(float4*)(&Bs[sb_n * 40 + sb_k + 8]) = b2;
        __syncthreads();
        bfrag af[2], bg[4];
#pragma unroll
        for (int mt = 0; mt < 2; ++mt)
            af[mt] = *(const bfrag*)(&As[(wm * 32 + mt * 16 + fr_row) * 40 + fr_k]);
#pragma unroll
        for (int nt = 0; nt < 4; ++nt)
            bg[nt] = *(const bfrag*)(&Bs[(wn * 64 + nt * 16 + fr_row) * 40 + fr_k]);
#pragma unroll
        for (int mt = 0; mt < 2; ++mt)
#pragma unroll
            for (int nt = 0; nt < 4; ++nt)
                acc[mt][nt] = __builtin_amdgcn_mfma_f32_16x16x32_bf16(
                    af[mt], bg[nt], acc[mt][nt], 0, 0, 0);
    }

    int mbase = (lane >> 4) << 2;
#pragma unroll
    for (int mt = 0; mt < 2; ++mt) {
#pragma unroll
        for (int nt = 0; nt < 4; ++nt) {
            int n = n0 + wn * 64 + nt * 16 + (lane & 15);
            float bv = bias ? bias[n] : 0.f;
#pragma unroll
            for (int r = 0; r < 4; ++r) {
                int m = m0 + wm * 32 + mt * 16 + mbase + r;
                float v = acc[mt][nt][r] + bv;
                if (act == 1) v = fmaxf(v, 0.f);
                else if (act == 2) v = v / (1.f + expf(-v));
                if (res) v += res[(long)m * N + n];
                C[(long)m * N + n] = v;
            }
        }
    }
}

// ---------------------------------------------------------------------------
// fp32 tiled GEMM (small/odd-N). Validated R9-R13.
// ---------------------------------------------------------------------------
__global__ __launch_bounds__(256) void gemm_k(
        const float* __restrict__ A, const float* __restrict__ W,
        const float* __restrict__ bias, const float* __restrict__ res,
        float* __restrict__ Cf, int M, int K, int Nc, int act) {
    __shared__ __align__(16) float Asf[32][64];
    __shared__ __align__(16) float Bsf[32][64];
    int tid = threadIdx.x;
    int tx = tid & 15, ty = tid >> 4;
    int m0 = blockIdx.x * 64, n0 = blockIdx.y * 64;
    float acc[4][4] = {{0.f}};
    int am = tid >> 2;
    int ak = (tid & 3) << 3;
    int bk = tid >> 4;
    int bn = (tid & 15) << 2;

    for (int k0 = 0; k0 < K; k0 += 32) {
        const float* Ap = A + (long)(m0 + am) * K + k0 + ak;
        float4 a1 = *(const float4*)Ap;
        float4 a2 = *(const float4*)(Ap + 4);
        float w1[4], w2[4];
#pragma unroll
        for (int u = 0; u < 4; ++u) {
            int n = n0 + bn + u;
            w1[u] = (n < Nc) ? W[(long)(k0 + bk) * Nc + n] : 0.f;
            w2[u] = (n < Nc) ? W[(long)(k0 + bk + 16) * Nc + n] : 0.f;
        }
        __syncthreads();
        Asf[ak + 0][am] = a1.x; Asf[ak + 1][am] = a1.y;
        Asf[ak + 2][am] = a1.z; Asf[ak + 3][am] = a1.w;
        Asf[ak + 4][am] = a2.x; Asf[ak + 5][am] = a2.y;
        Asf[ak + 6][am] = a2.z; Asf[ak + 7][am] = a2.w;
#pragma unroll
        for (int u = 0; u < 4; ++u) {
            Bsf[bk][bn + u] = w1[u];
            Bsf[bk + 16][bn + u] = w2[u];
        }
        __syncthreads();
#pragma unroll
        for (int k = 0; k < 32; ++k) {
            float4 a = *(const float4*)(&Asf[k][ty << 2]);
            float4 b = *(const float4*)(&Bsf[k][tx << 2]);
            acc[0][0] += a.x * b.x; acc[0][1] += a.x * b.y; acc[0][2] += a.x * b.z; acc[0][3] += a.x * b.w;
            acc[1][0] += a.y * b.x; acc[1][1] += a.y * b.y; acc[1][2] += a.y * b.z; acc[1][3] += a.y * b.w;
            acc[2][0] += a.z * b.x; acc[2][1] += a.z * b.y; acc[2][2] += a.z * b.z; acc[2][3] += a.z * b.w;
            acc[3][0] += a.w * b.x; acc[3][1] += a.w * b.y; acc[3][2] += a.w * b.z; acc[3][3] += a.w * b.w;
        }
    }
#pragma unroll
    for (int i = 0; i < 4; ++i) {
        int m = m0 + (ty << 2) + i;
#pragma unroll
        for (int j = 0; j < 4; ++j) {
            int n = n0 + (tx << 2) + j;
            if (n >= Nc) continue;
            float v = acc[i][j];
            if (bias) v += bias[n];
            if (act == 1) v = fmaxf(v, 0.f);
            else if (act == 2) v = v / (1.f + expf(-v));
            if (res) v += res[(long)m * Nc + n];
            Cf[(long)m * Nc + n] = v;
        }
    }
}

// ---------------------------------------------------------------------------
// GINE v12 — R4 body (named scalars, validated numerics) + the two measured
// limiters fixed:
//  * TLP: grid GG*8 (6 j's/block), launch_bounds(256,4) -> VGPR cap 64,
//    kernel needs 48 (R4-measured) -> no spill. 2048 blocks = 8 blocks/CU
//    = 32 waves/CU; whole grid co-resident. (R3 proved the split correct;
//    its spill came from the arg-8 VGPR cap of 32.)
//  * XCD locality: g in LOW bits of blockIdx (g = bid&255). Blocks sharing
//    the same etab/x rows (same g, different half/jq) are 256 apart;
//    256 % 8 XCDs == 0 -> all 8 land on the SAME XCD and are co-resident ->
//    etab hits that XCD's L2 (~200cy) instead of HBM (~900cy), FETCH drops.
// Per-j arithmetic & MFMA order unchanged EXACTLY (absmax invariant).
// ---------------------------------------------------------------------------
#define MF(a, b, c) c = __builtin_amdgcn_mfma_f32_16x16x32_bf16(a, b, c, 0, 0, 0)

__global__ __launch_bounds__(256, 4) void gine4(
        const float* __restrict__ x,
        const float* __restrict__ lattice, const float* __restrict__ geW,
        const float* __restrict__ geb, const short* __restrict__ gewt_h,
        const short* __restrict__ gewt_l, const short* __restrict__ et_h,
        const short* __restrict__ et_l, float* __restrict__ z, int l) {
    __shared__ __align__(16) float xls[24 * 132];  // 12672 B
    __shared__ float basel[128];                   // 512 B

    int tid = threadIdx.x;
    int lane = tid & 63, w = tid >> 6, quad = lane >> 4, l16 = lane & 15;
    int bid = blockIdx.x;
    int g = bid & 255;                 // low bits: same-XCD for same g
    int jq = (bid >> 8) & 3;           // j range jq*6 .. jq*6+5
    int half = (bid >> 10) & 1;

    // ---- stage x half (float4), base ----
    {
        const float4* xg = (const float4*)x;
        for (int idx = tid; idx < 768; idx += 256) {
            int i = idx >> 5, c4 = idx & 31;
            ((float4*)(xls + i * 132))[c4] =
                xg[((long)(g * NP + i) * CC + half * 128) / 4 + c4];
        }
    }
    if (tid < 128) {
        int cg = half * 128 + tid;
        float bv = geb[(long)l * CC + cg];
#pragma unroll
        for (int q = 0; q < 9; ++q)
            bv += lattice[(long)g * 9 + q] * geW[(long)l * 69 * 256 + (long)(60 + q) * 256 + cg];
        basel[tid] = bv;
    }

    // ---- B fragments direct from global (loop-invariant, named scalars) ----
    bfrag bh00, bh01, bh10, bh11, bl00, bl01, bl10, bl11;
    {
        long base = (long)(l * 2 + half) * 8192;   // shorts: 128 rows x 64
        int nrow0 = w * 32 + l16;                  // nt=0
        int nrow1 = w * 32 + 16 + l16;             // nt=1
        const short* p0h = gewt_h + base + nrow0 * 64 + quad * 8;
        const short* p1h = gewt_h + base + nrow1 * 64 + quad * 8;
        const short* p0l = gewt_l + base + nrow0 * 64 + quad * 8;
        const short* p1l = gewt_l + base + nrow1 * 64 + quad * 8;
        bh00 = *(const bfrag*)(p0h);      bh01 = *(const bfrag*)(p0h + 32);
        bh10 = *(const bfrag*)(p1h);      bh11 = *(const bfrag*)(p1h + 32);
        bl00 = *(const bfrag*)(p0l);      bl01 = *(const bfrag*)(p0l + 32);
        bl10 = *(const bfrag*)(p1l);      bl11 = *(const bfrag*)(p1l + 32);
    }
    __syncthreads();
    float bse0 = basel[w * 32 + l16];
    float bse1 = basel[w * 32 + 16 + l16];

    const short* ehg = et_h + (long)g * (24 * 24 * 64);
    const short* elg = et_l + (long)g * (24 * 24 * 64);

    // ---- chunk loop over dst j (6 per block) ----
    for (int jc = 0; jc < 6; ++jc) {
        int j = jq * 6 + jc;
        const short* ej_h = ehg + (long)j * 1536;
        const short* ej_l = elg + (long)j * 1536;
        int r0 = l16 * 64 + quad * 8;          // mt=0 fragment row offset
        int r1 = (16 + l16) * 64 + quad * 8;   // mt=1

        // batch ALL 8 A-fragment loads (named scalars; in-flight together)
        bfrag ah00 = *(const bfrag*)(ej_h + r0);
        bfrag ah01 = *(const bfrag*)(ej_h + r0 + 32);
        bfrag ah10 = *(const bfrag*)(ej_h + r1);
        bfrag ah11 = *(const bfrag*)(ej_h + r1 + 32);
        bfrag al00 = *(const bfrag*)(ej_l + r0);
        bfrag al01 = *(const bfrag*)(ej_l + r0 + 32);
        bfrag al10 = *(const bfrag*)(ej_l + r1);
        bfrag al11 = *(const bfrag*)(ej_l + r1 + 32);

        ffrag a00 = {}, a01 = {}, a10 = {}, a11 = {};   // acc[mt][nt]
        // mt=0, ks=0
        MF(ah00, bh00, a00); MF(ah00, bl00, a00); MF(al00, bh00, a00);
        MF(ah00, bh10, a01); MF(ah00, bl10, a01); MF(al00, bh10, a01);
        // mt=0, ks=1
        MF(ah01, bh01, a00); MF(ah01, bl01, a00); MF(al01, bh01, a00);
        MF(ah01, bh11, a01); MF(ah01, bl11, a01); MF(al01, bh11, a01);
        // mt=1, ks=0
        MF(ah10, bh00, a10); MF(ah10, bl00, a10); MF(al10, bh00, a10);
        MF(ah10, bh10, a11); MF(ah10, bl10, a11); MF(al10, bh10, a11);
        // mt=1, ks=1
        MF(ah11, bh01, a10); MF(ah11, bl01, a10); MF(al11, bh01, a10);
        MF(ah11, bh11, a11); MF(ah11, bl11, a11); MF(al11, bh11, a11);

        // epilogue: relu + reduce over i, write z[g*24+j][cg]
#pragma unroll
        for (int nt = 0; nt < 2; ++nt) {
            int cl = w * 32 + nt * 16 + l16;
            float bse = nt ? bse1 : bse0;
            ffrag am0 = nt ? a01 : a00;   // mt=0 acc (ibase = quad*4, always < 24)
            ffrag am1 = nt ? a11 : a10;   // mt=1 acc (ibase = 16+quad*4, quad<2 only)
            float part = 0.f;
            {
                int ibase = quad * 4;
#pragma unroll
                for (int r = 0; r < 4; ++r) {
                    float xv = xls[(ibase + r) * 132 + cl];
                    part += fmaxf(xv + bse + am0[r], 0.f);
                }
            }
            if (quad < 2) {
                int ibase = 16 + quad * 4;
#pragma unroll
                for (int r = 0; r < 4; ++r) {
                    float xv = xls[(ibase + r) * 132 + cl];
                    part += fmaxf(xv + bse + am1[r], 0.f);
                }
            }
            part += __shfl_xor(part, 16);
            part += __shfl_xor(part, 32);
            if (lane < 16)
                z[(long)(g * NP + j) * CC + half * 128 + cl] = xls[j * 132 + cl] + part;
        }
    }
}

// ---------------------------------------------------------------------------
__global__ void bn_stats1(const float* __restrict__ in, float* __restrict__ part) {
    int c = threadIdx.x, b = blockIdx.x;
    float s = 0.f, q = 0.f;
    for (int r = 0; r < 64; ++r) {
        float v = in[(long)(b * 64 + r) * CC + c];
        s += v; q += v * v;
    }
    part[b * 512 + c] = s;
    part[b * 512 + 256 + c] = q;
}
__global__ void bn_stats2(const float* __restrict__ part, float* __restrict__ stats) {
    int c = threadIdx.x;
    float s = 0.f, q = 0.f;
    for (int b = 0; b < 96; ++b) { s += part[b * 512 + c]; q += part[b * 512 + 256 + c]; }
    float m = s / (float)NN;
    float var = q / (float)NN - m * m;
    stats[c] = m;
    stats[256 + c] = rsqrtf(var + 1e-5f);
}
__global__ void bn_apply(const float* __restrict__ in, const float* __restrict__ stats,
                         const float* __restrict__ gma, const float* __restrict__ bta,
                         const float* __restrict__ add, float* __restrict__ out) {
    long idx = (long)blockIdx.x * 256 + threadIdx.x;
    int c = (int)(idx & 255);
    float v = (in[idx] - stats[c]) * stats[256 + c] * gma[c] + bta[c];
    if (add) v += add[idx];
    out[idx] = v;
}

// ---------------------------------------------------------------------------
// Attention v2 (validated R10).
// ---------------------------------------------------------------------------
__global__ __launch_bounds__(256, 2) void attn2(const float* __restrict__ qkv,
                                                float* __restrict__ o) {
    __shared__ __align__(16) float Kl[24 * 4 * 68];
    __shared__ __align__(16) float Vl[24 * 4 * 68];
    __shared__ float S[4 * 24 * 25];
    int tid = threadIdx.x, g = blockIdx.x;

    const float4* qkv4 = (const float4*)(qkv + (long)g * NP * 768);
    for (int idx = tid; idx < 24 * 128; idx += 256) {
        int row = idx >> 7;
        int c4 = idx & 127;
        int isV = c4 >> 6;
        int cc = c4 & 63;
        int h = cc >> 4, d4 = cc & 15;
        float4 val = qkv4[row * 192 + 64 + c4];
        float* dst = (isV ? Vl : Kl) + (row * 4 + h) * 68 + d4 * 4;
        *(float4*)dst = val;
    }
    __syncthreads();

    if (tid < 96) {
        int h = tid & 3, i = tid >> 2;
        const float4* qp = (const float4*)(qkv + ((long)(g * NP + i)) * 768 + h * 64);
        float4 q[16];
#pragma unroll
        for (int k = 0; k < 16; ++k) q[k] = qp[k];
        float sc[24];
        float mx = -1e30f;
        for (int j = 0; j < 24; ++j) {
            const float4* kp = (const float4*)(Kl + (j * 4 + h) * 68);
            float da = 0.f, db = 0.f;
#pragma unroll
            for (int k = 0; k < 16; k += 2) {
                float4 kv = kp[k];
                da += q[k].x * kv.x; da += q[k].y * kv.y;
                da += q[k].z * kv.z; da += q[k].w * kv.w;
                float4 kv2 = kp[k + 1];
                db += q[k + 1].x * kv2.x; db += q[k + 1].y * kv2.y;
                db += q[k + 1].z * kv2.z; db += q[k + 1].w * kv2.w;
            }
            float s = (da + db) * 0.125f;
            sc[j] = s;
            mx = fmaxf(mx, s);
        }
        float sum = 0.f;
#pragma unroll
        for (int j = 0; j < 24; ++j) { float p = expf(sc[j] - mx); sc[j] = p; sum += p; }
        float inv = 1.f / sum;
#pragma unroll
        for (int j = 0; j < 24; ++j) S[(h * 24 + i) * 25 + j] = sc[j] * inv;
    }
    __syncthreads();

    int h = tid >> 6, d = tid & 63;
    for (int i = 0; i < 24; ++i) {
        const float* Sp = S + (h * 24 + i) * 25;
        float a0 = 0.f, a1 = 0.f;
#pragma unroll
        for (int j = 0; j < 24; j += 2) {
            a0 += Sp[j] * Vl[(j * 4 + h) * 68 + d];
            a1 += Sp[j + 1] * Vl[((j + 1) * 4 + h) * 68 + d];
        }
        o[(long)(g * NP + i) * CC + h * 64 + d] = a0 + a1;
    }
}

// ---------------------------------------------------------------------------
__global__ __launch_bounds__(256) void ln_kernel(const float* __restrict__ x,
        const float* __restrict__ gma, const float* __restrict__ bta,
        float* __restrict__ out) {
    __shared__ float red[256];
    int n = blockIdx.x, c = threadIdx.x;
    float v = x[(long)n * CC + c];
    red[c] = v;
    __syncthreads();
    for (int s = 128; s > 0; s >>= 1) { if (c < s) red[c] += red[c + s]; __syncthreads(); }
    float m = red[0] * (1.f / 256.f);
    __syncthreads();
    float dv = v - m;
    red[c] = dv * dv;
    __syncthreads();
    for (int s = 128; s > 0; s >>= 1) { if (c < s) red[c] += red[c + s]; __syncthreads(); }
    float var = red[0] * (1.f / 256.f);
    out[(long)n * CC + c] = dv * rsqrtf(var + 1e-5f) * gma[c] + bta[c];
}

__global__ void pool_kernel(const float* __restrict__ hn, float* __restrict__ gf) {
    int g = blockIdx.x, c = threadIdx.x;
    float s = 0.f;
    for (int j = 0; j < NP; ++j) s += hn[(long)(g * NP + j) * CC + c];
    gf[g * CC + c] = s * (1.f / 24.f);
}

// ---------------------------------------------------------------------------
static void gemm(hipStream_t st, const float* A, const float* W, const float* bias,
                 const float* res, float* Cf, int M, int K, int Nc, int act) {
    dim3 grid(M / 64, (Nc + 63) / 64);
    gemm_k<<<grid, 256, 0, st>>>(A, W, bias, res, Cf, M, K, Nc, act);
}

static void gemmM(hipStream_t st, const float* A, const bf* Wt, const float* bias,
                  const float* res, float* Cf, int M, int K, int N, int act) {
    dim3 grid(M / 64, N / 128);
    gemm_mfma<<<grid, 256, 0, st>>>(A, Wt, bias, res, Cf, M, K, N, act);
}

static void run_bn(hipStream_t st, const float* in, float* part, float* stats,
                   const float* g_, const float* b_, const float* add, float* out) {
    bn_stats1<<<96, 256, 0, st>>>(in, part);
    bn_stats2<<<1, 256, 0, st>>>(part, stats);
    bn_apply<<<NN, 256, 0, st>>>(in, stats, g_, b_, add, out);
}

extern "C" void kernel_launch(void* const* d_in, const int* in_sizes, int n_in,
                              void* d_out, int out_size, void* d_ws, size_t ws_size,
                              hipStream_t stream) {
    float* out = (float*)d_out;
    int sigN = out_size < 256 ? out_size : 256;

    static const int EXP_SIZES[46] = {
        256, 18432, 2304, 25600, 131072, 256, 52992, 768, 196608, 768,
        196608, 768, 589824, 2304, 196608, 768, 393216, 1536, 393216, 768,
        768, 768, 768, 768, 768, 768, 256, 256, 32768, 128,
        12800, 100, 32768, 128, 8192, 64, 576, 32768, 128, 8192,
        64, 192, 6144, 6144, 147456, 147456 };
    if (n_in != 46) { signal_k<<<1, 256, 0, stream>>>(out, sigN, 3000.f + 8.f * n_in); return; }
    for (int i = 0; i < 46; ++i)
        if (in_sizes[i] != EXP_SIZES[i]) { signal_k<<<1, 256, 0, stream>>>(out, sigN, 512.f + 8.f * i); return; }
    if (out_size != NN * 100 + GG * 9 + NN * 3) { signal_k<<<1, 256, 0, stream>>>(out, sigN, 7777.f); return; }

    // ---- workspace ----
    char* base = (char*)d_ws;
    int* flags = (int*)base;                       // 256 B
    float* f32a = (float*)(base + 256);
    float* x  = f32a;                              // N*256
    float* s1 = x  + (size_t)NN * 256;             // N*256
    float* s2 = s1 + (size_t)NN * 256;             // N*256
    float* big = s2 + (size_t)NN * 256;            // N*768
    float* s3 = big + (size_t)NN * 512;            // alias of big's tail (lifetimes audited)
    float* part = big + (size_t)NN * 768;          // 96*512
    float* stats = part + 96 * 512;                // 512
    float* gf  = stats + 512;                      // G*256
    float* l1b = gf + GG * 256;                    // G*128
    float* l2b = l1b + GG * 128;                   // G*64
    bf* wt = (bf*)(l2b + GG * 64);                 // bf16 W^T mirrors
    const long O_NA = 0, O_G1 = 131072, O_G2 = 327680, O_AI = 524288,
               O_AO = 1114112, O_M1 = 1310720, O_M2 = 1703936,
               O_TRO = 2097152, O_FC = 2129920, WT_TOT = 2162688;
    short* gewt_h = (short*)(wt + WT_TOT);         // 49152 shorts
    short* gewt_l = gewt_h + 49152;                // 49152 shorts
    // E tables: ETAB_ELEMS shorts each + 1024-short pad (mt=1 fragment rows
    // 24..31 of the last (g,j) block read past the 24-row payload).
    short* et_h = gewt_l + 49152;
    short* et_l = et_h + (ETAB_ELEMS + 1024);
    size_t REQ = 256 + ((size_t)NN * 1536 + 96 * 512 + 512 + GG * 448) * 4
               + WT_TOT * 2 + 49152 * 2 * 2
               + ((size_t)ETAB_ELEMS + 1024) * 2 * 2;
    if (ws_size < REQ) { signal_k<<<1, 256, 0, stream>>>(out, sigN, 9999.f); return; }

    const float* t       = (const float*)d_in[0];
    const float* frac    = (const float*)d_in[1];
    const float* lattice = (const float*)d_in[2];
    const float* type_emb = (const float*)d_in[3];

    detect_int_k<<<1, 256, 0, stream>>>((const unsigned int*)d_in[42], flags);

    // combined weight prep (one dispatch for the 9 transposes)
    {
        TArgs ta;
        const int srcIdx[9] = {4, 8, 10, 12, 14, 16, 18, 28, 37};
        const long dof[9]  = {O_NA, O_G1, O_G2, O_AI, O_AO, O_M1, O_M2, O_TRO, O_FC};
        const int Ks[9] = {512, 256, 256, 256, 256, 256, 512, 256, 256};
        const int Ns[9] = {256, 256, 256, 768, 256, 512, 256, 128, 128};
        const int Ls[9] = {1, 3, 3, 3, 3, 3, 3, 1, 1};
        int blk = 0;
        for (int s = 0; s < 9; ++s) {
            ta.src[s] = (const float*)d_in[srcIdx[s]];
            ta.dstOff[s] = dof[s];
            ta.K[s] = Ks[s]; ta.N[s] = Ns[s]; ta.L[s] = Ls[s];
            ta.blk0[s] = blk;
            blk += (Ks[s] * Ns[s] * Ls[s] + 255) / 256;
        }
        ta.blk0[9] = blk;
        transp_all<<<blk, 256, 0, stream>>>(ta, wt);
    }
    prep_gew<<<192, 256, 0, stream>>>((const float*)d_in[6], gewt_h, gewt_l);
    prep_etab<<<(ETAB_ELEMS + 255) / 256, 256, 0, stream>>>(frac, et_h, et_l);

    // x0 = concat(type_emb[atoms], time_emb) @ naW + nab
    build_A<<<(NN * 512 + 255) / 256, 256, 0, stream>>>(t, type_emb,
        (const unsigned int*)d_in[42], big, flags);
    gemmM(stream, big, wt + O_NA, (const float*)d_in[5], nullptr, x, NN, 512, 256, 0);

    for (int l = 0; l < LL; ++l) {
        // GINE: s1 = x + aggr (MFMA split-bf16, E table, XCD-local 2048 blks)
        gine4<<<GG * 8, 256, 0, stream>>>(x, lattice,
            (const float*)d_in[6], (const float*)d_in[7], gewt_h, gewt_l,
            et_h, et_l, s1, l);
        // s2 = silu(s1@gW1+gb1); s3 = s2@gW2+gb2 + x; h1 = BN(s3) -> s2
        gemmM(stream, s1, wt + O_G1 + (long)l * 65536, (const float*)d_in[9]  + l * 256, nullptr, s2, NN, 256, 256, 2);
        gemmM(stream, s2, wt + O_G2 + (long)l * 65536, (const float*)d_in[11] + l * 256, x, s3, NN, 256, 256, 0);
        run_bn(stream, s3, part, stats, (const float*)d_in[20] + l * 256, (const float*)d_in[21] + l * 256, nullptr, s2);
        // attention: qkv=big; o=s1; s3 = s1@aoW+aob + x; s1 = h1 + BN(s3)
        gemmM(stream, x, wt + O_AI + (long)l * 196608, (const float*)d_in[13] + l * 768, nullptr, big, NN, 256, 768, 0);
        attn2<<<GG, 256, 0, stream>>>(big, s1);
        gemmM(stream, s1, wt + O_AO + (long)l * 65536, (const float*)d_in[15] + l * 256, x, s3, NN, 256, 256, 0);
        run_bn(stream, s3, part, stats, (const float*)d_in[22] + l * 256, (const float*)d_in[23] + l * 256, s2, s1);
        // MLP: big = relu(s1@mW1+mb1); s3 = big@mW2+mb2 + s1; x = BN(s3)
        gemmM(stream, s1, wt + O_M1 + (long)l * 131072, (const float*)d_in[17] + l * 512, nullptr, big, NN, 256, 512, 1);
        gemmM(stream, big, wt + O_M2 + (long)l * 131072, (const float*)d_in[19] + l * 256, s1, s3, NN, 512, 256, 0);
        run_bn(stream, s3, part, stats, (const float*)d_in[24] + l * 256, (const float*)d_in[25] + l * 256, nullptr, x);
    }

    ln_kernel<<<NN, 256, 0, stream>>>(x, (const float*)d_in[26], (const float*)d_in[27], s1);
    pool_kernel<<<GG, 256, 0, stream>>>(s1, gf);

    // types_pred -> out[0 : N*100]
    gemmM(stream, s1, wt + O_TRO, (const float*)d_in[29], nullptr, s2, NN, 256, 128, 2);
    gemm(stream, s2, (const float*)d_in[30], (const float*)d_in[31], nullptr, out, NN, 128, 100, 0);
    // lattice_pred -> out[N*100 : +G*9]
    gemm(stream, gf,  (const float*)d_in[32], (const float*)d_in[33], nullptr, l1b, GG, 256, 128, 2);
    gemm(stream, l1b, (const float*)d_in[34], (const float*)d_in[35], nullptr, l2b, GG, 128, 64, 2);
    gemm(stream, l2b, (const float*)d_in[36], nullptr, nullptr, out + (size_t)NN * 100, GG, 64, 9, 0);
    // frac_pred -> out[N*100+G*9 : ]
    gemmM(stream, s1, wt + O_FC, (const float*)d_in[38], nullptr, s2, NN, 256, 128, 2);
    gemm(stream, s2, (const float*)d_in[39], (const float*)d_in[40], nullptr, s3, NN, 128, 64, 2);
    gemm(stream, s3, (const float*)d_in[41], nullptr, nullptr, out + (size_t)NN * 100 + GG * 9, NN, 64, 3, 0);
}

// Round 6
// 890.034 us; speedup vs baseline: 1.1085x; 1.1085x over previous
//
#include <hip/hip_runtime.h>
#include <hip/hip_bf16.h>
#include <math.h>

#define GG 256
#define NP 24
#define LL 3
#define CC 256
#define NN (GG*NP)   // 6144 nodes
#define HH 4
#define DH 64

typedef __hip_bfloat16 bf;
typedef __attribute__((ext_vector_type(8))) short bfrag;   // 8 bf16 (4 VGPR)
typedef __attribute__((ext_vector_type(4))) float ffrag;   // 4 fp32 acc

__device__ __forceinline__ short pk(float x) {
    union { bf h; short s; } u; u.h = __float2bfloat16(x); return u.s;
}
__device__ __forceinline__ float b2f_s(short x) {
    union { short s; bf h; } u; u.s = x; return __bfloat162float(u.h);
}

// ---------------------------------------------------------------------------
__global__ void detect_int_k(const unsigned int* __restrict__ at, int* flags) {
    __shared__ int ok;
    if (threadIdx.x == 0) ok = 1;
    __syncthreads();
    if (at[2 * threadIdx.x + 1] != 0u) ok = 0;   // benign race
    __syncthreads();
    if (threadIdx.x == 0) flags[0] = ok;
}

__global__ void signal_k(float* out, int n, float val) {
    int i = blockIdx.x * 256 + threadIdx.x;
    if (i < n) out[i] = val;
}

// ---------------------------------------------------------------------------
// Combined weight prep (9 segments in ONE dispatch): fp32 [L][K][N] ->
// bf16 [L][N][K] at wt+dstOff.
// ---------------------------------------------------------------------------
struct TArgs {
    const float* src[9];
    long dstOff[9];
    int K[9], N[9], L[9];
    int blk0[10];
};
__global__ void transp_all(TArgs a, bf* __restrict__ wt) {
    int bid = blockIdx.x;
    int s = 0;
    while (s < 8 && bid >= a.blk0[s + 1]) ++s;
    long idx = (long)(bid - a.blk0[s]) * 256 + threadIdx.x;
    int KN = a.K[s] * a.N[s];
    long sz = (long)KN * a.L[s];
    if (idx >= sz) return;
    int l = (int)(idx / KN);
    int rem = (int)(idx % KN);
    int k = rem / a.N[s], n = rem % a.N[s];
    wt[a.dstOff[s] + (long)l * KN + (long)n * a.K[s] + k] =
        __float2bfloat16(a.src[s][idx]);
}

// ---------------------------------------------------------------------------
// GINE edge-weight prep: geW fp32 [L][69][256] -> split bf16 W^T
// [L][half][n 0..127][k 0..63] (k<60 real, else 0), hi and lo parts.
// ---------------------------------------------------------------------------
__global__ void prep_gew(const float* __restrict__ geW, short* __restrict__ wh,
                         short* __restrict__ wl) {
    int idx = blockIdx.x * 256 + threadIdx.x;   // 3*2*128*64 = 49152
    if (idx >= 49152) return;
    int k = idx & 63;
    int n = (idx >> 6) & 127;
    int half = (idx >> 13) & 1;
    int l = idx >> 14;
    float v = (k < 60) ? geW[(long)l * 69 * 256 + (long)k * 256 + half * 128 + n] : 0.f;
    short hi = pk(v);
    short lo = pk(v - b2f_s(hi));
    wh[idx] = hi;
    wl[idx] = lo;
}

// ---------------------------------------------------------------------------
// E-table precompute: sin/cos edge features depend only on frac — layer- and
// half-independent. Built once, bit-identically to the original in-kernel
// expression, in MFMA-fragment layout [(g*24+j)*24+i][k 0..63].
// ---------------------------------------------------------------------------
#define ETAB_ELEMS (GG * 24 * 24 * 64)   // 9437184
__global__ void prep_etab(const float* __restrict__ frac, short* __restrict__ eh,
                          short* __restrict__ el) {
    int idx = blockIdx.x * 256 + threadIdx.x;
    if (idx >= ETAB_ELEMS) return;
    int k = idx & 63;
    int rem = idx >> 6;           // (g*24 + j)*24 + i
    int i = rem % 24;
    int rem2 = rem / 24;
    int j = rem2 % 24;
    int g = rem2 / 24;
    float val = 0.f;
    if (k < 60) {
        int r = (k < 30) ? k : k - 30;
        int d = r / 10, f = r % 10;
        float fd = frac[g * 72 + j * 3 + d] - frac[g * 72 + i * 3 + d];
        fd -= floorf(fd);
        float ang = 6.283185307179586f * (float)f * fd;
        val = (k < 30) ? sinf(ang) : cosf(ang);
    }
    short hi = pk(val);
    eh[idx] = hi;
    el[idx] = pk(val - b2f_s(hi));
}

// ---------------------------------------------------------------------------
// A = [type_emb[atom_types] | time_emb]  (N x 512, fp32)
// ---------------------------------------------------------------------------
__global__ void build_A(const float* __restrict__ t, const float* __restrict__ type_emb,
                        const unsigned int* __restrict__ atoms,
                        float* __restrict__ A, const int* __restrict__ flags) {
    int i64 = flags[0];
    int idx = blockIdx.x * 256 + threadIdx.x;
    if (idx >= NN * 512) return;
    int n = idx >> 9;
    int k = idx & 511;
    if (k < 256) {
        int a = i64 ? (int)atoms[2 * n] : (int)atoms[n];
        A[idx] = type_emb[(long)a * CC + k];
    } else {
        int d = k - 256;
        int g = n / NP;
        float tv = t[g];
        int dd = (d < 128) ? d : d - 128;
        float tf = expf(dd * (-9.210340371976184f / 127.0f));
        float ang = tv * tf;
        A[idx] = (d < 128) ? sinf(ang) : cosf(ang);
    }
}

// ---------------------------------------------------------------------------
// MFMA bf16 GEMM (validated R11). C = epi(A@W + bias) (+res), Wt = bf16 W^T.
// ---------------------------------------------------------------------------
__global__ __launch_bounds__(256) void gemm_mfma(
        const float* __restrict__ A, const bf* __restrict__ Wt,
        const float* __restrict__ bias, const float* __restrict__ res,
        float* __restrict__ C, int M, int K, int N, int act) {
    __shared__ short As[64 * 40];
    __shared__ short Bs[128 * 40];
    int tid = threadIdx.x;
    int lane = tid & 63, w = tid >> 6;
    int wm = w & 1, wn = w >> 1;
    int m0 = blockIdx.x * 64, n0 = blockIdx.y * 128;
    ffrag acc[2][4] = {};
    int sa_m = tid >> 2, sa_k = (tid & 3) << 3;
    int sb_n = tid >> 1, sb_k = (tid & 1) << 4;
    int fr_row = lane & 15, fr_k = (lane >> 4) << 3;

    for (int k0 = 0; k0 < K; k0 += 32) {
        const float* Ap = A + (long)(m0 + sa_m) * K + k0 + sa_k;
        float4 a1 = *(const float4*)Ap;
        float4 a2 = *(const float4*)(Ap + 4);
        const float4* Bp = (const float4*)(Wt + (long)(n0 + sb_n) * K + k0 + sb_k);
        float4 b1 = Bp[0], b2 = Bp[1];
        __syncthreads();
        bfrag av;
        av[0] = pk(a1.x); av[1] = pk(a1.y); av[2] = pk(a1.z); av[3] = pk(a1.w);
        av[4] = pk(a2.x); av[5] = pk(a2.y); av[6] = pk(a2.z); av[7] = pk(a2.w);
        *(bfrag*)(&As[sa_m * 40 + sa_k]) = av;
        *(float4*)(&Bs[sb_n * 40 + sb_k]) = b1;
        *(float4*)(&Bs[sb_n * 40 + sb_k + 8]) = b2;
        __syncthreads();
        bfrag af[2], bg[4];
#pragma unroll
        for (int mt = 0; mt < 2; ++mt)
            af[mt] = *(const bfrag*)(&As[(wm * 32 + mt * 16 + fr_row) * 40 + fr_k]);
#pragma unroll
        for (int nt = 0; nt < 4; ++nt)
            bg[nt] = *(const bfrag*)(&Bs[(wn * 64 + nt * 16 + fr_row) * 40 + fr_k]);
#pragma unroll
        for (int mt = 0; mt < 2; ++mt)
#pragma unroll
            for (int nt = 0; nt < 4; ++nt)
                acc[mt][nt] = __builtin_amdgcn_mfma_f32_16x16x32_bf16(
                    af[mt], bg[nt], acc[mt][nt], 0, 0, 0);
    }

    int mbase = (lane >> 4) << 2;
#pragma unroll
    for (int mt = 0; mt < 2; ++mt) {
#pragma unroll
        for (int nt = 0; nt < 4; ++nt) {
            int n = n0 + wn * 64 + nt * 16 + (lane & 15);
            float bv = bias ? bias[n] : 0.f;
#pragma unroll
            for (int r = 0; r < 4; ++r) {
                int m = m0 + wm * 32 + mt * 16 + mbase + r;
                float v = acc[mt][nt][r] + bv;
                if (act == 1) v = fmaxf(v, 0.f);
                else if (act == 2) v = v / (1.f + expf(-v));
                if (res) v += res[(long)m * N + n];
                C[(long)m * N + n] = v;
            }
        }
    }
}

// ---------------------------------------------------------------------------
// fp32 tiled GEMM (small/odd-N). Validated R9-R13.
// ---------------------------------------------------------------------------
__global__ __launch_bounds__(256) void gemm_k(
        const float* __restrict__ A, const float* __restrict__ W,
        const float* __restrict__ bias, const float* __restrict__ res,
        float* __restrict__ Cf, int M, int K, int Nc, int act) {
    __shared__ __align__(16) float Asf[32][64];
    __shared__ __align__(16) float Bsf[32][64];
    int tid = threadIdx.x;
    int tx = tid & 15, ty = tid >> 4;
    int m0 = blockIdx.x * 64, n0 = blockIdx.y * 64;
    float acc[4][4] = {{0.f}};
    int am = tid >> 2;
    int ak = (tid & 3) << 3;
    int bk = tid >> 4;
    int bn = (tid & 15) << 2;

    for (int k0 = 0; k0 < K; k0 += 32) {
        const float* Ap = A + (long)(m0 + am) * K + k0 + ak;
        float4 a1 = *(const float4*)Ap;
        float4 a2 = *(const float4*)(Ap + 4);
        float w1[4], w2[4];
#pragma unroll
        for (int u = 0; u < 4; ++u) {
            int n = n0 + bn + u;
            w1[u] = (n < Nc) ? W[(long)(k0 + bk) * Nc + n] : 0.f;
            w2[u] = (n < Nc) ? W[(long)(k0 + bk + 16) * Nc + n] : 0.f;
        }
        __syncthreads();
        Asf[ak + 0][am] = a1.x; Asf[ak + 1][am] = a1.y;
        Asf[ak + 2][am] = a1.z; Asf[ak + 3][am] = a1.w;
        Asf[ak + 4][am] = a2.x; Asf[ak + 5][am] = a2.y;
        Asf[ak + 6][am] = a2.z; Asf[ak + 7][am] = a2.w;
#pragma unroll
        for (int u = 0; u < 4; ++u) {
            Bsf[bk][bn + u] = w1[u];
            Bsf[bk + 16][bn + u] = w2[u];
        }
        __syncthreads();
#pragma unroll
        for (int k = 0; k < 32; ++k) {
            float4 a = *(const float4*)(&Asf[k][ty << 2]);
            float4 b = *(const float4*)(&Bsf[k][tx << 2]);
            acc[0][0] += a.x * b.x; acc[0][1] += a.x * b.y; acc[0][2] += a.x * b.z; acc[0][3] += a.x * b.w;
            acc[1][0] += a.y * b.x; acc[1][1] += a.y * b.y; acc[1][2] += a.y * b.z; acc[1][3] += a.y * b.w;
            acc[2][0] += a.z * b.x; acc[2][1] += a.z * b.y; acc[2][2] += a.z * b.z; acc[2][3] += a.z * b.w;
            acc[3][0] += a.w * b.x; acc[3][1] += a.w * b.y; acc[3][2] += a.w * b.z; acc[3][3] += a.w * b.w;
        }
    }
#pragma unroll
    for (int i = 0; i < 4; ++i) {
        int m = m0 + (ty << 2) + i;
#pragma unroll
        for (int j = 0; j < 4; ++j) {
            int n = n0 + (tx << 2) + j;
            if (n >= Nc) continue;
            float v = acc[i][j];
            if (bias) v += bias[n];
            if (act == 1) v = fmaxf(v, 0.f);
            else if (act == 2) v = v / (1.f + expf(-v));
            if (res) v += res[(long)m * Nc + n];
            Cf[(long)m * Nc + n] = v;
        }
    }
}

// ---------------------------------------------------------------------------
// GINE v13 — R1/R4 structure (grid GG*4, best-known 54 µs) + async DMA
// double-buffered E staging. R1-R5 established: the 54 µs wall is exposed
// L3/HBM latency on the per-chunk A-fragment loads (all pipes <14% busy),
// occupancy can't be raised (launch_bounds arg governs residency; arg 8
// forces a 32-VGPR spill), and register pipelining spills. The remaining
// documented fix is __builtin_amdgcn_global_load_lds: chunk j+1's 6 KB
// E-tile is DMA'd into LDS buf^1 while chunk j computes; the per-chunk
// barrier drains a transfer issued ~500 cy earlier instead of stalling on
// fresh loads. Values, MFMA order, epilogue — all bit-identical to R4
// (LDS tile holds the same bytes the VGPR loads fetched; mt=1 rows 24..31
// read stale LDS instead of next-j global data — both garbage, both
// confined to discarded acc rows).
// ---------------------------------------------------------------------------
#define MF(a, b, c) c = __builtin_amdgcn_mfma_f32_16x16x32_bf16(a, b, c, 0, 0, 0)

typedef __attribute__((address_space(1))) const void gv_t;
typedef __attribute__((address_space(3))) void lv_t;

// Stage one 24x64-short E-tile pair (eh->lds[0..1535], el->lds[2048..3583])
// as 6 DMA chunks of 512 shorts (64 lanes x 16 B). Wave w: chunks w, w+4.
__device__ __forceinline__ void stage_etile(const short* __restrict__ ej_h,
                                            const short* __restrict__ ej_l,
                                            short* lds_base, int w, int lane) {
    {
        int c = w;   // 0..3
        const short* src = (c < 3) ? (ej_h + c * 512) : (ej_l + (c - 3) * 512);
        int doff = (c < 3) ? c * 512 : 2048 + (c - 3) * 512;
        __builtin_amdgcn_global_load_lds((gv_t*)(src + lane * 8),
                                         (lv_t*)(lds_base + doff), 16, 0, 0);
    }
    if (w < 2) {
        int c = w + 4;   // 4,5 -> el chunks 1,2
        const short* src = ej_l + (c - 3) * 512;
        int doff = 2048 + (c - 3) * 512;
        __builtin_amdgcn_global_load_lds((gv_t*)(src + lane * 8),
                                         (lv_t*)(lds_base + doff), 16, 0, 0);
    }
}

__global__ __launch_bounds__(256, 4) void gine4(
        const float* __restrict__ x,
        const float* __restrict__ lattice, const float* __restrict__ geW,
        const float* __restrict__ geb, const short* __restrict__ gewt_h,
        const short* __restrict__ gewt_l, const short* __restrict__ et_h,
        const short* __restrict__ et_l, float* __restrict__ z, int l) {
    __shared__ __align__(16) float xls[24 * 132];  // 12672 B
    __shared__ float basel[128];                   // 512 B
    // 2 buffers x (eh 32 rows + el 32 rows) x 64 shorts = 8192 shorts (16 KB).
    // Rows 24..31 of each part are never staged (stale) — reads of them feed
    // only acc rows the epilogue discards (same as R4's next-j garbage).
    __shared__ __align__(16) short ebuf[8192];

    int tid = threadIdx.x;
    int lane = tid & 63, w = tid >> 6, quad = lane >> 4, l16 = lane & 15;
    int g = blockIdx.x >> 2;
    int half = (blockIdx.x >> 1) & 1;
    int jh = blockIdx.x & 1;           // j range jh*12 .. jh*12+11

    // ---- stage x half (float4), base ----
    {
        const float4* xg = (const float4*)x;
        for (int idx = tid; idx < 768; idx += 256) {
            int i = idx >> 5, c4 = idx & 31;
            ((float4*)(xls + i * 132))[c4] =
                xg[((long)(g * NP + i) * CC + half * 128) / 4 + c4];
        }
    }
    if (tid < 128) {
        int cg = half * 128 + tid;
        float bv = geb[(long)l * CC + cg];
#pragma unroll
        for (int q = 0; q < 9; ++q)
            bv += lattice[(long)g * 9 + q] * geW[(long)l * 69 * 256 + (long)(60 + q) * 256 + cg];
        basel[tid] = bv;
    }

    // ---- B fragments direct from global (loop-invariant, named scalars) ----
    bfrag bh00, bh01, bh10, bh11, bl00, bl01, bl10, bl11;
    {
        long base = (long)(l * 2 + half) * 8192;   // shorts: 128 rows x 64
        int nrow0 = w * 32 + l16;                  // nt=0
        int nrow1 = w * 32 + 16 + l16;             // nt=1
        const short* p0h = gewt_h + base + nrow0 * 64 + quad * 8;
        const short* p1h = gewt_h + base + nrow1 * 64 + quad * 8;
        const short* p0l = gewt_l + base + nrow0 * 64 + quad * 8;
        const short* p1l = gewt_l + base + nrow1 * 64 + quad * 8;
        bh00 = *(const bfrag*)(p0h);      bh01 = *(const bfrag*)(p0h + 32);
        bh10 = *(const bfrag*)(p1h);      bh11 = *(const bfrag*)(p1h + 32);
        bl00 = *(const bfrag*)(p0l);      bl01 = *(const bfrag*)(p0l + 32);
        bl10 = *(const bfrag*)(p1l);      bl11 = *(const bfrag*)(p1l + 32);
    }

    const short* ehg = et_h + (long)g * (24 * 24 * 64);
    const short* elg = et_l + (long)g * (24 * 24 * 64);
    int j0 = jh * 12;

    // prologue: DMA first tile into buf 0
    stage_etile(ehg + (long)j0 * 1536, elg + (long)j0 * 1536, ebuf, w, lane);
    __syncthreads();   // drains DMA + makes xls/basel visible

    float bse0 = basel[w * 32 + l16];
    float bse1 = basel[w * 32 + 16 + l16];

    int cur = 0;
    for (int jc = 0; jc < 12; ++jc) {
        int j = j0 + jc;
        // issue next tile's DMA into the other buffer (hidden under compute)
        if (jc < 11) {
            stage_etile(ehg + (long)(j + 1) * 1536, elg + (long)(j + 1) * 1536,
                        ebuf + (cur ^ 1) * 4096, w, lane);
        }

        const short* eb = ebuf + cur * 4096;
        int r0 = l16 * 64 + quad * 8;          // mt=0 row offset (shorts)
        int r1 = (16 + l16) * 64 + quad * 8;   // mt=1
        bfrag ah00 = *(const bfrag*)(eb + r0);
        bfrag ah01 = *(const bfrag*)(eb + r0 + 32);
        bfrag ah10 = *(const bfrag*)(eb + r1);
        bfrag ah11 = *(const bfrag*)(eb + r1 + 32);
        bfrag al00 = *(const bfrag*)(eb + 2048 + r0);
        bfrag al01 = *(const bfrag*)(eb + 2048 + r0 + 32);
        bfrag al10 = *(const bfrag*)(eb + 2048 + r1);
        bfrag al11 = *(const bfrag*)(eb + 2048 + r1 + 32);

        ffrag a00 = {}, a01 = {}, a10 = {}, a11 = {};   // acc[mt][nt]
        // mt=0, ks=0
        MF(ah00, bh00, a00); MF(ah00, bl00, a00); MF(al00, bh00, a00);
        MF(ah00, bh10, a01); MF(ah00, bl10, a01); MF(al00, bh10, a01);
        // mt=0, ks=1
        MF(ah01, bh01, a00); MF(ah01, bl01, a00); MF(al01, bh01, a00);
        MF(ah01, bh11, a01); MF(ah01, bl11, a01); MF(al01, bh11, a01);
        // mt=1, ks=0
        MF(ah10, bh00, a10); MF(ah10, bl00, a10); MF(al10, bh00, a10);
        MF(ah10, bh10, a11); MF(ah10, bl10, a11); MF(al10, bh10, a11);
        // mt=1, ks=1
        MF(ah11, bh01, a10); MF(ah11, bl01, a10); MF(al11, bh01, a10);
        MF(ah11, bh11, a11); MF(ah11, bl11, a11); MF(al11, bh11, a11);

        // epilogue: relu + reduce over i, write z[g*24+j][cg]
#pragma unroll
        for (int nt = 0; nt < 2; ++nt) {
            int cl = w * 32 + nt * 16 + l16;
            float bse = nt ? bse1 : bse0;
            ffrag am0 = nt ? a01 : a00;   // mt=0 acc (ibase = quad*4, < 24)
            ffrag am1 = nt ? a11 : a10;   // mt=1 acc (valid only quad<2)
            float part = 0.f;
            {
                int ibase = quad * 4;
#pragma unroll
                for (int r = 0; r < 4; ++r) {
                    float xv = xls[(ibase + r) * 132 + cl];
                    part += fmaxf(xv + bse + am0[r], 0.f);
                }
            }
            if (quad < 2) {
                int ibase = 16 + quad * 4;
#pragma unroll
                for (int r = 0; r < 4; ++r) {
                    float xv = xls[(ibase + r) * 132 + cl];
                    part += fmaxf(xv + bse + am1[r], 0.f);
                }
            }
            part += __shfl_xor(part, 16);
            part += __shfl_xor(part, 32);
            if (lane < 16)
                z[(long)(g * NP + j) * CC + half * 128 + cl] = xls[j * 132 + cl] + part;
        }
        // barrier: (a) next buffer's DMA (issued before compute) is drained,
        // (b) all waves done reading buf[cur] before it is re-staged.
        __syncthreads();
        cur ^= 1;
    }
}

// ---------------------------------------------------------------------------
__global__ void bn_stats1(const float* __restrict__ in, float* __restrict__ part) {
    int c = threadIdx.x, b = blockIdx.x;
    float s = 0.f, q = 0.f;
    for (int r = 0; r < 64; ++r) {
        float v = in[(long)(b * 64 + r) * CC + c];
        s += v; q += v * v;
    }
    part[b * 512 + c] = s;
    part[b * 512 + 256 + c] = q;
}
__global__ void bn_stats2(const float* __restrict__ part, float* __restrict__ stats) {
    int c = threadIdx.x;
    float s = 0.f, q = 0.f;
    for (int b = 0; b < 96; ++b) { s += part[b * 512 + c]; q += part[b * 512 + 256 + c]; }
    float m = s / (float)NN;
    float var = q / (float)NN - m * m;
    stats[c] = m;
    stats[256 + c] = rsqrtf(var + 1e-5f);
}
__global__ void bn_apply(const float* __restrict__ in, const float* __restrict__ stats,
                         const float* __restrict__ gma, const float* __restrict__ bta,
                         const float* __restrict__ add, float* __restrict__ out) {
    long idx = (long)blockIdx.x * 256 + threadIdx.x;
    int c = (int)(idx & 255);
    float v = (in[idx] - stats[c]) * stats[256 + c] * gma[c] + bta[c];
    if (add) v += add[idx];
    out[idx] = v;
}

// ---------------------------------------------------------------------------
// Attention v2 (validated R10).
// ---------------------------------------------------------------------------
__global__ __launch_bounds__(256, 2) void attn2(const float* __restrict__ qkv,
                                                float* __restrict__ o) {
    __shared__ __align__(16) float Kl[24 * 4 * 68];
    __shared__ __align__(16) float Vl[24 * 4 * 68];
    __shared__ float S[4 * 24 * 25];
    int tid = threadIdx.x, g = blockIdx.x;

    const float4* qkv4 = (const float4*)(qkv + (long)g * NP * 768);
    for (int idx = tid; idx < 24 * 128; idx += 256) {
        int row = idx >> 7;
        int c4 = idx & 127;
        int isV = c4 >> 6;
        int cc = c4 & 63;
        int h = cc >> 4, d4 = cc & 15;
        float4 val = qkv4[row * 192 + 64 + c4];
        float* dst = (isV ? Vl : Kl) + (row * 4 + h) * 68 + d4 * 4;
        *(float4*)dst = val;
    }
    __syncthreads();

    if (tid < 96) {
        int h = tid & 3, i = tid >> 2;
        const float4* qp = (const float4*)(qkv + ((long)(g * NP + i)) * 768 + h * 64);
        float4 q[16];
#pragma unroll
        for (int k = 0; k < 16; ++k) q[k] = qp[k];
        float sc[24];
        float mx = -1e30f;
        for (int j = 0; j < 24; ++j) {
            const float4* kp = (const float4*)(Kl + (j * 4 + h) * 68);
            float da = 0.f, db = 0.f;
#pragma unroll
            for (int k = 0; k < 16; k += 2) {
                float4 kv = kp[k];
                da += q[k].x * kv.x; da += q[k].y * kv.y;
                da += q[k].z * kv.z; da += q[k].w * kv.w;
                float4 kv2 = kp[k + 1];
                db += q[k + 1].x * kv2.x; db += q[k + 1].y * kv2.y;
                db += q[k + 1].z * kv2.z; db += q[k + 1].w * kv2.w;
            }
            float s = (da + db) * 0.125f;
            sc[j] = s;
            mx = fmaxf(mx, s);
        }
        float sum = 0.f;
#pragma unroll
        for (int j = 0; j < 24; ++j) { float p = expf(sc[j] - mx); sc[j] = p; sum += p; }
        float inv = 1.f / sum;
#pragma unroll
        for (int j = 0; j < 24; ++j) S[(h * 24 + i) * 25 + j] = sc[j] * inv;
    }
    __syncthreads();

    int h = tid >> 6, d = tid & 63;
    for (int i = 0; i < 24; ++i) {
        const float* Sp = S + (h * 24 + i) * 25;
        float a0 = 0.f, a1 = 0.f;
#pragma unroll
        for (int j = 0; j < 24; j += 2) {
            a0 += Sp[j] * Vl[(j * 4 + h) * 68 + d];
            a1 += Sp[j + 1] * Vl[((j + 1) * 4 + h) * 68 + d];
        }
        o[(long)(g * NP + i) * CC + h * 64 + d] = a0 + a1;
    }
}

// ---------------------------------------------------------------------------
__global__ __launch_bounds__(256) void ln_kernel(const float* __restrict__ x,
        const float* __restrict__ gma, const float* __restrict__ bta,
        float* __restrict__ out) {
    __shared__ float red[256];
    int n = blockIdx.x, c = threadIdx.x;
    float v = x[(long)n * CC + c];
    red[c] = v;
    __syncthreads();
    for (int s = 128; s > 0; s >>= 1) { if (c < s) red[c] += red[c + s]; __syncthreads(); }
    float m = red[0] * (1.f / 256.f);
    __syncthreads();
    float dv = v - m;
    red[c] = dv * dv;
    __syncthreads();
    for (int s = 128; s > 0; s >>= 1) { if (c < s) red[c] += red[c + s]; __syncthreads(); }
    float var = red[0] * (1.f / 256.f);
    out[(long)n * CC + c] = dv * rsqrtf(var + 1e-5f) * gma[c] + bta[c];
}

__global__ void pool_kernel(const float* __restrict__ hn, float* __restrict__ gf) {
    int g = blockIdx.x, c = threadIdx.x;
    float s = 0.f;
    for (int j = 0; j < NP; ++j) s += hn[(long)(g * NP + j) * CC + c];
    gf[g * CC + c] = s * (1.f / 24.f);
}

// ---------------------------------------------------------------------------
static void gemm(hipStream_t st, const float* A, const float* W, const float* bias,
                 const float* res, float* Cf, int M, int K, int Nc, int act) {
    dim3 grid(M / 64, (Nc + 63) / 64);
    gemm_k<<<grid, 256, 0, st>>>(A, W, bias, res, Cf, M, K, Nc, act);
}

static void gemmM(hipStream_t st, const float* A, const bf* Wt, const float* bias,
                  const float* res, float* Cf, int M, int K, int N, int act) {
    dim3 grid(M / 64, N / 128);
    gemm_mfma<<<grid, 256, 0, st>>>(A, Wt, bias, res, Cf, M, K, N, act);
}

static void run_bn(hipStream_t st, const float* in, float* part, float* stats,
                   const float* g_, const float* b_, const float* add, float* out) {
    bn_stats1<<<96, 256, 0, st>>>(in, part);
    bn_stats2<<<1, 256, 0, st>>>(part, stats);
    bn_apply<<<NN, 256, 0, st>>>(in, stats, g_, b_, add, out);
}

extern "C" void kernel_launch(void* const* d_in, const int* in_sizes, int n_in,
                              void* d_out, int out_size, void* d_ws, size_t ws_size,
                              hipStream_t stream) {
    float* out = (float*)d_out;
    int sigN = out_size < 256 ? out_size : 256;

    static const int EXP_SIZES[46] = {
        256, 18432, 2304, 25600, 131072, 256, 52992, 768, 196608, 768,
        196608, 768, 589824, 2304, 196608, 768, 393216, 1536, 393216, 768,
        768, 768, 768, 768, 768, 768, 256, 256, 32768, 128,
        12800, 100, 32768, 128, 8192, 64, 576, 32768, 128, 8192,
        64, 192, 6144, 6144, 147456, 147456 };
    if (n_in != 46) { signal_k<<<1, 256, 0, stream>>>(out, sigN, 3000.f + 8.f * n_in); return; }
    for (int i = 0; i < 46; ++i)
        if (in_sizes[i] != EXP_SIZES[i]) { signal_k<<<1, 256, 0, stream>>>(out, sigN, 512.f + 8.f * i); return; }
    if (out_size != NN * 100 + GG * 9 + NN * 3) { signal_k<<<1, 256, 0, stream>>>(out, sigN, 7777.f); return; }

    // ---- workspace ----
    char* base = (char*)d_ws;
    int* flags = (int*)base;                       // 256 B
    float* f32a = (float*)(base + 256);
    float* x  = f32a;                              // N*256
    float* s1 = x  + (size_t)NN * 256;             // N*256
    float* s2 = s1 + (size_t)NN * 256;             // N*256
    float* big = s2 + (size_t)NN * 256;            // N*768
    float* s3 = big + (size_t)NN * 512;            // alias of big's tail (lifetimes audited)
    float* part = big + (size_t)NN * 768;          // 96*512
    float* stats = part + 96 * 512;                // 512
    float* gf  = stats + 512;                      // G*256
    float* l1b = gf + GG * 256;                    // G*128
    float* l2b = l1b + GG * 128;                   // G*64
    bf* wt = (bf*)(l2b + GG * 64);                 // bf16 W^T mirrors
    const long O_NA = 0, O_G1 = 131072, O_G2 = 327680, O_AI = 524288,
               O_AO = 1114112, O_M1 = 1310720, O_M2 = 1703936,
               O_TRO = 2097152, O_FC = 2129920, WT_TOT = 2162688;
    short* gewt_h = (short*)(wt + WT_TOT);         // 49152 shorts
    short* gewt_l = gewt_h + 49152;                // 49152 shorts
    // E tables: ETAB_ELEMS shorts each + 1024-short pad.
    short* et_h = gewt_l + 49152;
    short* et_l = et_h + (ETAB_ELEMS + 1024);
    size_t REQ = 256 + ((size_t)NN * 1536 + 96 * 512 + 512 + GG * 448) * 4
               + WT_TOT * 2 + 49152 * 2 * 2
               + ((size_t)ETAB_ELEMS + 1024) * 2 * 2;
    if (ws_size < REQ) { signal_k<<<1, 256, 0, stream>>>(out, sigN, 9999.f); return; }

    const float* t       = (const float*)d_in[0];
    const float* frac    = (const float*)d_in[1];
    const float* lattice = (const float*)d_in[2];
    const float* type_emb = (const float*)d_in[3];

    detect_int_k<<<1, 256, 0, stream>>>((const unsigned int*)d_in[42], flags);

    // combined weight prep (one dispatch for the 9 transposes)
    {
        TArgs ta;
        const int srcIdx[9] = {4, 8, 10, 12, 14, 16, 18, 28, 37};
        const long dof[9]  = {O_NA, O_G1, O_G2, O_AI, O_AO, O_M1, O_M2, O_TRO, O_FC};
        const int Ks[9] = {512, 256, 256, 256, 256, 256, 512, 256, 256};
        const int Ns[9] = {256, 256, 256, 768, 256, 512, 256, 128, 128};
        const int Ls[9] = {1, 3, 3, 3, 3, 3, 3, 1, 1};
        int blk = 0;
        for (int s = 0; s < 9; ++s) {
            ta.src[s] = (const float*)d_in[srcIdx[s]];
            ta.dstOff[s] = dof[s];
            ta.K[s] = Ks[s]; ta.N[s] = Ns[s]; ta.L[s] = Ls[s];
            ta.blk0[s] = blk;
            blk += (Ks[s] * Ns[s] * Ls[s] + 255) / 256;
        }
        ta.blk0[9] = blk;
        transp_all<<<blk, 256, 0, stream>>>(ta, wt);
    }
    prep_gew<<<192, 256, 0, stream>>>((const float*)d_in[6], gewt_h, gewt_l);
    prep_etab<<<(ETAB_ELEMS + 255) / 256, 256, 0, stream>>>(frac, et_h, et_l);

    // x0 = concat(type_emb[atoms], time_emb) @ naW + nab
    build_A<<<(NN * 512 + 255) / 256, 256, 0, stream>>>(t, type_emb,
        (const unsigned int*)d_in[42], big, flags);
    gemmM(stream, big, wt + O_NA, (const float*)d_in[5], nullptr, x, NN, 512, 256, 0);

    for (int l = 0; l < LL; ++l) {
        // GINE: s1 = x + aggr (MFMA split-bf16, DMA double-buffered E tiles)
        gine4<<<GG * 4, 256, 0, stream>>>(x, lattice,
            (const float*)d_in[6], (const float*)d_in[7], gewt_h, gewt_l,
            et_h, et_l, s1, l);
        // s2 = silu(s1@gW1+gb1); s3 = s2@gW2+gb2 + x; h1 = BN(s3) -> s2
        gemmM(stream, s1, wt + O_G1 + (long)l * 65536, (const float*)d_in[9]  + l * 256, nullptr, s2, NN, 256, 256, 2);
        gemmM(stream, s2, wt + O_G2 + (long)l * 65536, (const float*)d_in[11] + l * 256, x, s3, NN, 256, 256, 0);
        run_bn(stream, s3, part, stats, (const float*)d_in[20] + l * 256, (const float*)d_in[21] + l * 256, nullptr, s2);
        // attention: qkv=big; o=s1; s3 = s1@aoW+aob + x; s1 = h1 + BN(s3)
        gemmM(stream, x, wt + O_AI + (long)l * 196608, (const float*)d_in[13] + l * 768, nullptr, big, NN, 256, 768, 0);
        attn2<<<GG, 256, 0, stream>>>(big, s1);
        gemmM(stream, s1, wt + O_AO + (long)l * 65536, (const float*)d_in[15] + l * 256, x, s3, NN, 256, 256, 0);
        run_bn(stream, s3, part, stats, (const float*)d_in[22] + l * 256, (const float*)d_in[23] + l * 256, s2, s1);
        // MLP: big = relu(s1@mW1+mb1); s3 = big@mW2+mb2 + s1; x = BN(s3)
        gemmM(stream, s1, wt + O_M1 + (long)l * 131072, (const float*)d_in[17] + l * 512, nullptr, big, NN, 256, 512, 1);
        gemmM(stream, big, wt + O_M2 + (long)l * 131072, (const float*)d_in[19] + l * 256, s1, s3, NN, 512, 256, 0);
        run_bn(stream, s3, part, stats, (const float*)d_in[24] + l * 256, (const float*)d_in[25] + l * 256, nullptr, x);
    }

    ln_kernel<<<NN, 256, 0, stream>>>(x, (const float*)d_in[26], (const float*)d_in[27], s1);
    pool_kernel<<<GG, 256, 0, stream>>>(s1, gf);

    // types_pred -> out[0 : N*100]
    gemmM(stream, s1, wt + O_TRO, (const float*)d_in[29], nullptr, s2, NN, 256, 128, 2);
    gemm(stream, s2, (const float*)d_in[30], (const float*)d_in[31], nullptr, out, NN, 128, 100, 0);
    // lattice_pred -> out[N*100 : +G*9]
    gemm(stream, gf,  (const float*)d_in[32], (const float*)d_in[33], nullptr, l1b, GG, 256, 128, 2);
    gemm(stream, l1b, (const float*)d_in[34], (const float*)d_in[35], nullptr, l2b, GG, 128, 64, 2);
    gemm(stream, l2b, (const float*)d_in[36], nullptr, nullptr, out + (size_t)NN * 100, GG, 64, 9, 0);
    // frac_pred -> out[N*100+G*9 : ]
    gemmM(stream, s1, wt + O_FC, (const float*)d_in[38], nullptr, s2, NN, 256, 128, 2);
    gemm(stream, s2, (const float*)d_in[39], (const float*)d_in[40], nullptr, s3, NN, 128, 64, 2);
    gemm(stream, s3, (const float*)d_in[41], nullptr, nullptr, out + (size_t)NN * 100 + GG * 9, NN, 64, 3, 0);
}

// Round 7
// 854.823 us; speedup vs baseline: 1.1541x; 1.0412x over previous
//
#include <hip/hip_runtime.h>
#include <hip/hip_bf16.h>
#include <math.h>

#define GG 256
#define NP 24
#define LL 3
#define CC 256
#define NN (GG*NP)   // 6144 nodes
#define HH 4
#define DH 64

typedef __hip_bfloat16 bf;
typedef __attribute__((ext_vector_type(8))) short bfrag;   // 8 bf16 (4 VGPR)
typedef __attribute__((ext_vector_type(4))) float ffrag;   // 4 fp32 acc

__device__ __forceinline__ short pk(float x) {
    union { bf h; short s; } u; u.h = __float2bfloat16(x); return u.s;
}
__device__ __forceinline__ float b2f_s(short x) {
    union { short s; bf h; } u; u.s = x; return __bfloat162float(u.h);
}

// ---------------------------------------------------------------------------
__global__ void detect_int_k(const unsigned int* __restrict__ at, int* flags) {
    __shared__ int ok;
    if (threadIdx.x == 0) ok = 1;
    __syncthreads();
    if (at[2 * threadIdx.x + 1] != 0u) ok = 0;   // benign race
    __syncthreads();
    if (threadIdx.x == 0) flags[0] = ok;
}

__global__ void signal_k(float* out, int n, float val) {
    int i = blockIdx.x * 256 + threadIdx.x;
    if (i < n) out[i] = val;
}

// ---------------------------------------------------------------------------
// Combined weight prep (9 segments in ONE dispatch): fp32 [L][K][N] ->
// bf16 [L][N][K] at wt+dstOff.
// ---------------------------------------------------------------------------
struct TArgs {
    const float* src[9];
    long dstOff[9];
    int K[9], N[9], L[9];
    int blk0[10];
};
__global__ void transp_all(TArgs a, bf* __restrict__ wt) {
    int bid = blockIdx.x;
    int s = 0;
    while (s < 8 && bid >= a.blk0[s + 1]) ++s;
    long idx = (long)(bid - a.blk0[s]) * 256 + threadIdx.x;
    int KN = a.K[s] * a.N[s];
    long sz = (long)KN * a.L[s];
    if (idx >= sz) return;
    int l = (int)(idx / KN);
    int rem = (int)(idx % KN);
    int k = rem / a.N[s], n = rem % a.N[s];
    wt[a.dstOff[s] + (long)l * KN + (long)n * a.K[s] + k] =
        __float2bfloat16(a.src[s][idx]);
}

// ---------------------------------------------------------------------------
// GINE edge-weight prep: geW fp32 [L][69][256] -> split bf16 W^T
// [L][half][n 0..127][k 0..63] (k<60 real, else 0), hi and lo parts.
// ---------------------------------------------------------------------------
__global__ void prep_gew(const float* __restrict__ geW, short* __restrict__ wh,
                         short* __restrict__ wl) {
    int idx = blockIdx.x * 256 + threadIdx.x;   // 3*2*128*64 = 49152
    if (idx >= 49152) return;
    int k = idx & 63;
    int n = (idx >> 6) & 127;
    int half = (idx >> 13) & 1;
    int l = idx >> 14;
    float v = (k < 60) ? geW[(long)l * 69 * 256 + (long)k * 256 + half * 128 + n] : 0.f;
    short hi = pk(v);
    short lo = pk(v - b2f_s(hi));
    wh[idx] = hi;
    wl[idx] = lo;
}

// ---------------------------------------------------------------------------
// E-table precompute: sin/cos edge features depend only on frac — layer- and
// half-independent. Built once, bit-identically to the original in-kernel
// expression, in MFMA-fragment layout [(g*24+j)*24+i][k 0..63].
// ---------------------------------------------------------------------------
#define ETAB_ELEMS (GG * 24 * 24 * 64)   // 9437184
__global__ void prep_etab(const float* __restrict__ frac, short* __restrict__ eh,
                          short* __restrict__ el) {
    int idx = blockIdx.x * 256 + threadIdx.x;
    if (idx >= ETAB_ELEMS) return;
    int k = idx & 63;
    int rem = idx >> 6;           // (g*24 + j)*24 + i
    int i = rem % 24;
    int rem2 = rem / 24;
    int j = rem2 % 24;
    int g = rem2 / 24;
    float val = 0.f;
    if (k < 60) {
        int r = (k < 30) ? k : k - 30;
        int d = r / 10, f = r % 10;
        float fd = frac[g * 72 + j * 3 + d] - frac[g * 72 + i * 3 + d];
        fd -= floorf(fd);
        float ang = 6.283185307179586f * (float)f * fd;
        val = (k < 30) ? sinf(ang) : cosf(ang);
    }
    short hi = pk(val);
    eh[idx] = hi;
    el[idx] = pk(val - b2f_s(hi));
}

// ---------------------------------------------------------------------------
// A = [type_emb[atom_types] | time_emb]  (N x 512, fp32)
// ---------------------------------------------------------------------------
__global__ void build_A(const float* __restrict__ t, const float* __restrict__ type_emb,
                        const unsigned int* __restrict__ atoms,
                        float* __restrict__ A, const int* __restrict__ flags) {
    int i64 = flags[0];
    int idx = blockIdx.x * 256 + threadIdx.x;
    if (idx >= NN * 512) return;
    int n = idx >> 9;
    int k = idx & 511;
    if (k < 256) {
        int a = i64 ? (int)atoms[2 * n] : (int)atoms[n];
        A[idx] = type_emb[(long)a * CC + k];
    } else {
        int d = k - 256;
        int g = n / NP;
        float tv = t[g];
        int dd = (d < 128) ? d : d - 128;
        float tf = expf(dd * (-9.210340371976184f / 127.0f));
        float ang = tv * tf;
        A[idx] = (d < 128) ? sinf(ang) : cosf(ang);
    }
}

// ---------------------------------------------------------------------------
// MFMA bf16 GEMM (validated R11). C = epi(A@W + bias) (+res), Wt = bf16 W^T.
// ---------------------------------------------------------------------------
__global__ __launch_bounds__(256) void gemm_mfma(
        const float* __restrict__ A, const bf* __restrict__ Wt,
        const float* __restrict__ bias, const float* __restrict__ res,
        float* __restrict__ C, int M, int K, int N, int act) {
    __shared__ short As[64 * 40];
    __shared__ short Bs[128 * 40];
    int tid = threadIdx.x;
    int lane = tid & 63, w = tid >> 6;
    int wm = w & 1, wn = w >> 1;
    int m0 = blockIdx.x * 64, n0 = blockIdx.y * 128;
    ffrag acc[2][4] = {};
    int sa_m = tid >> 2, sa_k = (tid & 3) << 3;
    int sb_n = tid >> 1, sb_k = (tid & 1) << 4;
    int fr_row = lane & 15, fr_k = (lane >> 4) << 3;

    for (int k0 = 0; k0 < K; k0 += 32) {
        const float* Ap = A + (long)(m0 + sa_m) * K + k0 + sa_k;
        float4 a1 = *(const float4*)Ap;
        float4 a2 = *(const float4*)(Ap + 4);
        const float4* Bp = (const float4*)(Wt + (long)(n0 + sb_n) * K + k0 + sb_k);
        float4 b1 = Bp[0], b2 = Bp[1];
        __syncthreads();
        bfrag av;
        av[0] = pk(a1.x); av[1] = pk(a1.y); av[2] = pk(a1.z); av[3] = pk(a1.w);
        av[4] = pk(a2.x); av[5] = pk(a2.y); av[6] = pk(a2.z); av[7] = pk(a2.w);
        *(bfrag*)(&As[sa_m * 40 + sa_k]) = av;
        *(float4*)(&Bs[sb_n * 40 + sb_k]) = b1;
        *(float4*)(&Bs[sb_n * 40 + sb_k + 8]) = b2;
        __syncthreads();
        bfrag af[2], bg[4];
#pragma unroll
        for (int mt = 0; mt < 2; ++mt)
            af[mt] = *(const bfrag*)(&As[(wm * 32 + mt * 16 + fr_row) * 40 + fr_k]);
#pragma unroll
        for (int nt = 0; nt < 4; ++nt)
            bg[nt] = *(const bfrag*)(&Bs[(wn * 64 + nt * 16 + fr_row) * 40 + fr_k]);
#pragma unroll
        for (int mt = 0; mt < 2; ++mt)
#pragma unroll
            for (int nt = 0; nt < 4; ++nt)
                acc[mt][nt] = __builtin_amdgcn_mfma_f32_16x16x32_bf16(
                    af[mt], bg[nt], acc[mt][nt], 0, 0, 0);
    }

    int mbase = (lane >> 4) << 2;
#pragma unroll
    for (int mt = 0; mt < 2; ++mt) {
#pragma unroll
        for (int nt = 0; nt < 4; ++nt) {
            int n = n0 + wn * 64 + nt * 16 + (lane & 15);
            float bv = bias ? bias[n] : 0.f;
#pragma unroll
            for (int r = 0; r < 4; ++r) {
                int m = m0 + wm * 32 + mt * 16 + mbase + r;
                float v = acc[mt][nt][r] + bv;
                if (act == 1) v = fmaxf(v, 0.f);
                else if (act == 2) v = v / (1.f + expf(-v));
                if (res) v += res[(long)m * N + n];
                C[(long)m * N + n] = v;
            }
        }
    }
}

// ---------------------------------------------------------------------------
// fp32 tiled GEMM (small/odd-N). Validated R9-R13.
// ---------------------------------------------------------------------------
__global__ __launch_bounds__(256) void gemm_k(
        const float* __restrict__ A, const float* __restrict__ W,
        const float* __restrict__ bias, const float* __restrict__ res,
        float* __restrict__ Cf, int M, int K, int Nc, int act) {
    __shared__ __align__(16) float Asf[32][64];
    __shared__ __align__(16) float Bsf[32][64];
    int tid = threadIdx.x;
    int tx = tid & 15, ty = tid >> 4;
    int m0 = blockIdx.x * 64, n0 = blockIdx.y * 64;
    float acc[4][4] = {{0.f}};
    int am = tid >> 2;
    int ak = (tid & 3) << 3;
    int bk = tid >> 4;
    int bn = (tid & 15) << 2;

    for (int k0 = 0; k0 < K; k0 += 32) {
        const float* Ap = A + (long)(m0 + am) * K + k0 + ak;
        float4 a1 = *(const float4*)Ap;
        float4 a2 = *(const float4*)(Ap + 4);
        float w1[4], w2[4];
#pragma unroll
        for (int u = 0; u < 4; ++u) {
            int n = n0 + bn + u;
            w1[u] = (n < Nc) ? W[(long)(k0 + bk) * Nc + n] : 0.f;
            w2[u] = (n < Nc) ? W[(long)(k0 + bk + 16) * Nc + n] : 0.f;
        }
        __syncthreads();
        Asf[ak + 0][am] = a1.x; Asf[ak + 1][am] = a1.y;
        Asf[ak + 2][am] = a1.z; Asf[ak + 3][am] = a1.w;
        Asf[ak + 4][am] = a2.x; Asf[ak + 5][am] = a2.y;
        Asf[ak + 6][am] = a2.z; Asf[ak + 7][am] = a2.w;
#pragma unroll
        for (int u = 0; u < 4; ++u) {
            Bsf[bk][bn + u] = w1[u];
            Bsf[bk + 16][bn + u] = w2[u];
        }
        __syncthreads();
#pragma unroll
        for (int k = 0; k < 32; ++k) {
            float4 a = *(const float4*)(&Asf[k][ty << 2]);
            float4 b = *(const float4*)(&Bsf[k][tx << 2]);
            acc[0][0] += a.x * b.x; acc[0][1] += a.x * b.y; acc[0][2] += a.x * b.z; acc[0][3] += a.x * b.w;
            acc[1][0] += a.y * b.x; acc[1][1] += a.y * b.y; acc[1][2] += a.y * b.z; acc[1][3] += a.y * b.w;
            acc[2][0] += a.z * b.x; acc[2][1] += a.z * b.y; acc[2][2] += a.z * b.z; acc[2][3] += a.z * b.w;
            acc[3][0] += a.w * b.x; acc[3][1] += a.w * b.y; acc[3][2] += a.w * b.z; acc[3][3] += a.w * b.w;
        }
    }
#pragma unroll
    for (int i = 0; i < 4; ++i) {
        int m = m0 + (ty << 2) + i;
#pragma unroll
        for (int j = 0; j < 4; ++j) {
            int n = n0 + (tx << 2) + j;
            if (n >= Nc) continue;
            float v = acc[i][j];
            if (bias) v += bias[n];
            if (act == 1) v = fmaxf(v, 0.f);
            else if (act == 2) v = v / (1.f + expf(-v));
            if (res) v += res[(long)m * Nc + n];
            Cf[(long)m * Nc + n] = v;
        }
    }
}

// ---------------------------------------------------------------------------
// GINE v13 — R1/R4 structure + async DMA double-buffered E staging.
// WIN R6: 957 -> 890 µs total (gine4 dropped out of top-5, < 42 µs).
// Unchanged this round.
// ---------------------------------------------------------------------------
#define MF(a, b, c) c = __builtin_amdgcn_mfma_f32_16x16x32_bf16(a, b, c, 0, 0, 0)

typedef __attribute__((address_space(1))) const void gv_t;
typedef __attribute__((address_space(3))) void lv_t;

// Stage one 24x64-short E-tile pair (eh->lds[0..1535], el->lds[2048..3583])
// as 6 DMA chunks of 512 shorts (64 lanes x 16 B). Wave w: chunks w, w+4.
__device__ __forceinline__ void stage_etile(const short* __restrict__ ej_h,
                                            const short* __restrict__ ej_l,
                                            short* lds_base, int w, int lane) {
    {
        int c = w;   // 0..3
        const short* src = (c < 3) ? (ej_h + c * 512) : (ej_l + (c - 3) * 512);
        int doff = (c < 3) ? c * 512 : 2048 + (c - 3) * 512;
        __builtin_amdgcn_global_load_lds((gv_t*)(src + lane * 8),
                                         (lv_t*)(lds_base + doff), 16, 0, 0);
    }
    if (w < 2) {
        int c = w + 4;   // 4,5 -> el chunks 1,2
        const short* src = ej_l + (c - 3) * 512;
        int doff = 2048 + (c - 3) * 512;
        __builtin_amdgcn_global_load_lds((gv_t*)(src + lane * 8),
                                         (lv_t*)(lds_base + doff), 16, 0, 0);
    }
}

__global__ __launch_bounds__(256, 4) void gine4(
        const float* __restrict__ x,
        const float* __restrict__ lattice, const float* __restrict__ geW,
        const float* __restrict__ geb, const short* __restrict__ gewt_h,
        const short* __restrict__ gewt_l, const short* __restrict__ et_h,
        const short* __restrict__ et_l, float* __restrict__ z, int l) {
    __shared__ __align__(16) float xls[24 * 132];  // 12672 B
    __shared__ float basel[128];                   // 512 B
    __shared__ __align__(16) short ebuf[8192];     // 2 x (eh 32r + el 32r) x 64

    int tid = threadIdx.x;
    int lane = tid & 63, w = tid >> 6, quad = lane >> 4, l16 = lane & 15;
    int g = blockIdx.x >> 2;
    int half = (blockIdx.x >> 1) & 1;
    int jh = blockIdx.x & 1;           // j range jh*12 .. jh*12+11

    // ---- stage x half (float4), base ----
    {
        const float4* xg = (const float4*)x;
        for (int idx = tid; idx < 768; idx += 256) {
            int i = idx >> 5, c4 = idx & 31;
            ((float4*)(xls + i * 132))[c4] =
                xg[((long)(g * NP + i) * CC + half * 128) / 4 + c4];
        }
    }
    if (tid < 128) {
        int cg = half * 128 + tid;
        float bv = geb[(long)l * CC + cg];
#pragma unroll
        for (int q = 0; q < 9; ++q)
            bv += lattice[(long)g * 9 + q] * geW[(long)l * 69 * 256 + (long)(60 + q) * 256 + cg];
        basel[tid] = bv;
    }

    // ---- B fragments direct from global (loop-invariant, named scalars) ----
    bfrag bh00, bh01, bh10, bh11, bl00, bl01, bl10, bl11;
    {
        long base = (long)(l * 2 + half) * 8192;   // shorts: 128 rows x 64
        int nrow0 = w * 32 + l16;                  // nt=0
        int nrow1 = w * 32 + 16 + l16;             // nt=1
        const short* p0h = gewt_h + base + nrow0 * 64 + quad * 8;
        const short* p1h = gewt_h + base + nrow1 * 64 + quad * 8;
        const short* p0l = gewt_l + base + nrow0 * 64 + quad * 8;
        const short* p1l = gewt_l + base + nrow1 * 64 + quad * 8;
        bh00 = *(const bfrag*)(p0h);      bh01 = *(const bfrag*)(p0h + 32);
        bh10 = *(const bfrag*)(p1h);      bh11 = *(const bfrag*)(p1h + 32);
        bl00 = *(const bfrag*)(p0l);      bl01 = *(const bfrag*)(p0l + 32);
        bl10 = *(const bfrag*)(p1l);      bl11 = *(const bfrag*)(p1l + 32);
    }

    const short* ehg = et_h + (long)g * (24 * 24 * 64);
    const short* elg = et_l + (long)g * (24 * 24 * 64);
    int j0 = jh * 12;

    // prologue: DMA first tile into buf 0
    stage_etile(ehg + (long)j0 * 1536, elg + (long)j0 * 1536, ebuf, w, lane);
    __syncthreads();   // drains DMA + makes xls/basel visible

    float bse0 = basel[w * 32 + l16];
    float bse1 = basel[w * 32 + 16 + l16];

    int cur = 0;
    for (int jc = 0; jc < 12; ++jc) {
        int j = j0 + jc;
        // issue next tile's DMA into the other buffer (hidden under compute)
        if (jc < 11) {
            stage_etile(ehg + (long)(j + 1) * 1536, elg + (long)(j + 1) * 1536,
                        ebuf + (cur ^ 1) * 4096, w, lane);
        }

        const short* eb = ebuf + cur * 4096;
        int r0 = l16 * 64 + quad * 8;          // mt=0 row offset (shorts)
        int r1 = (16 + l16) * 64 + quad * 8;   // mt=1
        bfrag ah00 = *(const bfrag*)(eb + r0);
        bfrag ah01 = *(const bfrag*)(eb + r0 + 32);
        bfrag ah10 = *(const bfrag*)(eb + r1);
        bfrag ah11 = *(const bfrag*)(eb + r1 + 32);
        bfrag al00 = *(const bfrag*)(eb + 2048 + r0);
        bfrag al01 = *(const bfrag*)(eb + 2048 + r0 + 32);
        bfrag al10 = *(const bfrag*)(eb + 2048 + r1);
        bfrag al11 = *(const bfrag*)(eb + 2048 + r1 + 32);

        ffrag a00 = {}, a01 = {}, a10 = {}, a11 = {};   // acc[mt][nt]
        // mt=0, ks=0
        MF(ah00, bh00, a00); MF(ah00, bl00, a00); MF(al00, bh00, a00);
        MF(ah00, bh10, a01); MF(ah00, bl10, a01); MF(al00, bh10, a01);
        // mt=0, ks=1
        MF(ah01, bh01, a00); MF(ah01, bl01, a00); MF(al01, bh01, a00);
        MF(ah01, bh11, a01); MF(ah01, bl11, a01); MF(al01, bh11, a01);
        // mt=1, ks=0
        MF(ah10, bh00, a10); MF(ah10, bl00, a10); MF(al10, bh00, a10);
        MF(ah10, bh10, a11); MF(ah10, bl10, a11); MF(al10, bh10, a11);
        // mt=1, ks=1
        MF(ah11, bh01, a10); MF(ah11, bl01, a10); MF(al11, bh01, a10);
        MF(ah11, bh11, a11); MF(ah11, bl11, a11); MF(al11, bh11, a11);

        // epilogue: relu + reduce over i, write z[g*24+j][cg]
#pragma unroll
        for (int nt = 0; nt < 2; ++nt) {
            int cl = w * 32 + nt * 16 + l16;
            float bse = nt ? bse1 : bse0;
            ffrag am0 = nt ? a01 : a00;   // mt=0 acc (ibase = quad*4, < 24)
            ffrag am1 = nt ? a11 : a10;   // mt=1 acc (valid only quad<2)
            float part = 0.f;
            {
                int ibase = quad * 4;
#pragma unroll
                for (int r = 0; r < 4; ++r) {
                    float xv = xls[(ibase + r) * 132 + cl];
                    part += fmaxf(xv + bse + am0[r], 0.f);
                }
            }
            if (quad < 2) {
                int ibase = 16 + quad * 4;
#pragma unroll
                for (int r = 0; r < 4; ++r) {
                    float xv = xls[(ibase + r) * 132 + cl];
                    part += fmaxf(xv + bse + am1[r], 0.f);
                }
            }
            part += __shfl_xor(part, 16);
            part += __shfl_xor(part, 32);
            if (lane < 16)
                z[(long)(g * NP + j) * CC + half * 128 + cl] = xls[j * 132 + cl] + part;
        }
        __syncthreads();
        cur ^= 1;
    }
}

// ---------------------------------------------------------------------------
// BN: stats1 unchanged; stats2 folded into apply (R7). Each of 768 blocks
// recomputes the channel stats from the 96 partials with the VERBATIM
// bn_stats2 expressions (same ascending-b loop, s/NN, q/NN - m*m,
// rsqrtf(var+1e-5)) — deterministic and bit-identical per channel — then
// grid-strides 8 rows. Removes the 1-block bn_stats2 dispatch (9/forward,
// each pure launch+serial latency).
// ---------------------------------------------------------------------------
__global__ void bn_stats1(const float* __restrict__ in, float* __restrict__ part) {
    int c = threadIdx.x, b = blockIdx.x;
    float s = 0.f, q = 0.f;
    for (int r = 0; r < 64; ++r) {
        float v = in[(long)(b * 64 + r) * CC + c];
        s += v; q += v * v;
    }
    part[b * 512 + c] = s;
    part[b * 512 + 256 + c] = q;
}
__global__ __launch_bounds__(256) void bn_apply2(
        const float* __restrict__ in, const float* __restrict__ part,
        const float* __restrict__ gma, const float* __restrict__ bta,
        const float* __restrict__ add, float* __restrict__ out) {
    int c = threadIdx.x;
    float s = 0.f, q = 0.f;
    for (int b = 0; b < 96; ++b) { s += part[b * 512 + c]; q += part[b * 512 + 256 + c]; }
    float m = s / (float)NN;
    float var = q / (float)NN - m * m;
    float stats_c = m;
    float stats_rs = rsqrtf(var + 1e-5f);
    float gc = gma[c], bc = bta[c];
    for (int r = blockIdx.x; r < NN; r += 768) {
        long idx = (long)r * CC + c;
        float v = (in[idx] - stats_c) * stats_rs * gc + bc;
        if (add) v += add[idx];
        out[idx] = v;
    }
}

// ---------------------------------------------------------------------------
// Attention v2 (validated R10).
// ---------------------------------------------------------------------------
__global__ __launch_bounds__(256, 2) void attn2(const float* __restrict__ qkv,
                                                float* __restrict__ o) {
    __shared__ __align__(16) float Kl[24 * 4 * 68];
    __shared__ __align__(16) float Vl[24 * 4 * 68];
    __shared__ float S[4 * 24 * 25];
    int tid = threadIdx.x, g = blockIdx.x;

    const float4* qkv4 = (const float4*)(qkv + (long)g * NP * 768);
    for (int idx = tid; idx < 24 * 128; idx += 256) {
        int row = idx >> 7;
        int c4 = idx & 127;
        int isV = c4 >> 6;
        int cc = c4 & 63;
        int h = cc >> 4, d4 = cc & 15;
        float4 val = qkv4[row * 192 + 64 + c4];
        float* dst = (isV ? Vl : Kl) + (row * 4 + h) * 68 + d4 * 4;
        *(float4*)dst = val;
    }
    __syncthreads();

    if (tid < 96) {
        int h = tid & 3, i = tid >> 2;
        const float4* qp = (const float4*)(qkv + ((long)(g * NP + i)) * 768 + h * 64);
        float4 q[16];
#pragma unroll
        for (int k = 0; k < 16; ++k) q[k] = qp[k];
        float sc[24];
        float mx = -1e30f;
        for (int j = 0; j < 24; ++j) {
            const float4* kp = (const float4*)(Kl + (j * 4 + h) * 68);
            float da = 0.f, db = 0.f;
#pragma unroll
            for (int k = 0; k < 16; k += 2) {
                float4 kv = kp[k];
                da += q[k].x * kv.x; da += q[k].y * kv.y;
                da += q[k].z * kv.z; da += q[k].w * kv.w;
                float4 kv2 = kp[k + 1];
                db += q[k + 1].x * kv2.x; db += q[k + 1].y * kv2.y;
                db += q[k + 1].z * kv2.z; db += q[k + 1].w * kv2.w;
            }
            float s = (da + db) * 0.125f;
            sc[j] = s;
            mx = fmaxf(mx, s);
        }
        float sum = 0.f;
#pragma unroll
        for (int j = 0; j < 24; ++j) { float p = expf(sc[j] - mx); sc[j] = p; sum += p; }
        float inv = 1.f / sum;
#pragma unroll
        for (int j = 0; j < 24; ++j) S[(h * 24 + i) * 25 + j] = sc[j] * inv;
    }
    __syncthreads();

    int h = tid >> 6, d = tid & 63;
    for (int i = 0; i < 24; ++i) {
        const float* Sp = S + (h * 24 + i) * 25;
        float a0 = 0.f, a1 = 0.f;
#pragma unroll
        for (int j = 0; j < 24; j += 2) {
            a0 += Sp[j] * Vl[(j * 4 + h) * 68 + d];
            a1 += Sp[j + 1] * Vl[((j + 1) * 4 + h) * 68 + d];
        }
        o[(long)(g * NP + i) * CC + h * 64 + d] = a0 + a1;
    }
}

// ---------------------------------------------------------------------------
__global__ __launch_bounds__(256) void ln_kernel(const float* __restrict__ x,
        const float* __restrict__ gma, const float* __restrict__ bta,
        float* __restrict__ out) {
    __shared__ float red[256];
    int n = blockIdx.x, c = threadIdx.x;
    float v = x[(long)n * CC + c];
    red[c] = v;
    __syncthreads();
    for (int s = 128; s > 0; s >>= 1) { if (c < s) red[c] += red[c + s]; __syncthreads(); }
    float m = red[0] * (1.f / 256.f);
    __syncthreads();
    float dv = v - m;
    red[c] = dv * dv;
    __syncthreads();
    for (int s = 128; s > 0; s >>= 1) { if (c < s) red[c] += red[c + s]; __syncthreads(); }
    float var = red[0] * (1.f / 256.f);
    out[(long)n * CC + c] = dv * rsqrtf(var + 1e-5f) * gma[c] + bta[c];
}

__global__ void pool_kernel(const float* __restrict__ hn, float* __restrict__ gf) {
    int g = blockIdx.x, c = threadIdx.x;
    float s = 0.f;
    for (int j = 0; j < NP; ++j) s += hn[(long)(g * NP + j) * CC + c];
    gf[g * CC + c] = s * (1.f / 24.f);
}

// ---------------------------------------------------------------------------
// Fused lattice head (R7): silu(silu(gf@W1+b1)@W2+b2)@W3 in ONE dispatch.
// One block per graph. Bitwise: strictly sequential ascending-k accumulation
// with `acc += a*b` (same contraction pattern as gemm_k's inner loop), then
// `+bias` then the verbatim silu — matching gemm_k's per-output order.
// Replaces 3 tiny launch-bound gemm_k dispatches (8/4/2 blocks).
// ---------------------------------------------------------------------------
__global__ __launch_bounds__(256) void lat_head(
        const float* __restrict__ gf, const float* __restrict__ W1,
        const float* __restrict__ b1, const float* __restrict__ W2,
        const float* __restrict__ b2, const float* __restrict__ W3,
        float* __restrict__ out) {
    __shared__ float gfl[256];
    __shared__ float h1[128];
    __shared__ float h2[64];
    int g = blockIdx.x, t = threadIdx.x;
    gfl[t] = gf[(long)g * 256 + t];
    __syncthreads();
    if (t < 128) {
        float acc = 0.f;
        for (int k = 0; k < 256; ++k) acc += gfl[k] * W1[k * 128 + t];
        float v = acc;
        v += b1[t];
        v = v / (1.f + expf(-v));
        h1[t] = v;
    }
    __syncthreads();
    if (t < 64) {
        float acc = 0.f;
        for (int k = 0; k < 128; ++k) acc += h1[k] * W2[k * 64 + t];
        float v = acc;
        v += b2[t];
        v = v / (1.f + expf(-v));
        h2[t] = v;
    }
    __syncthreads();
    if (t < 9) {
        float acc = 0.f;
        for (int k = 0; k < 64; ++k) acc += h2[k] * W3[k * 9 + t];
        out[(long)g * 9 + t] = acc;
    }
}

// ---------------------------------------------------------------------------
static void gemm(hipStream_t st, const float* A, const float* W, const float* bias,
                 const float* res, float* Cf, int M, int K, int Nc, int act) {
    dim3 grid(M / 64, (Nc + 63) / 64);
    gemm_k<<<grid, 256, 0, st>>>(A, W, bias, res, Cf, M, K, Nc, act);
}

static void gemmM(hipStream_t st, const float* A, const bf* Wt, const float* bias,
                  const float* res, float* Cf, int M, int K, int N, int act) {
    dim3 grid(M / 64, N / 128);
    gemm_mfma<<<grid, 256, 0, st>>>(A, Wt, bias, res, Cf, M, K, N, act);
}

static void run_bn(hipStream_t st, const float* in, float* part, float* stats,
                   const float* g_, const float* b_, const float* add, float* out) {
    (void)stats;
    bn_stats1<<<96, 256, 0, st>>>(in, part);
    bn_apply2<<<768, 256, 0, st>>>(in, part, g_, b_, add, out);
}

extern "C" void kernel_launch(void* const* d_in, const int* in_sizes, int n_in,
                              void* d_out, int out_size, void* d_ws, size_t ws_size,
                              hipStream_t stream) {
    float* out = (float*)d_out;
    int sigN = out_size < 256 ? out_size : 256;

    static const int EXP_SIZES[46] = {
        256, 18432, 2304, 25600, 131072, 256, 52992, 768, 196608, 768,
        196608, 768, 589824, 2304, 196608, 768, 393216, 1536, 393216, 768,
        768, 768, 768, 768, 768, 768, 256, 256, 32768, 128,
        12800, 100, 32768, 128, 8192, 64, 576, 32768, 128, 8192,
        64, 192, 6144, 6144, 147456, 147456 };
    if (n_in != 46) { signal_k<<<1, 256, 0, stream>>>(out, sigN, 3000.f + 8.f * n_in); return; }
    for (int i = 0; i < 46; ++i)
        if (in_sizes[i] != EXP_SIZES[i]) { signal_k<<<1, 256, 0, stream>>>(out, sigN, 512.f + 8.f * i); return; }
    if (out_size != NN * 100 + GG * 9 + NN * 3) { signal_k<<<1, 256, 0, stream>>>(out, sigN, 7777.f); return; }

    // ---- workspace ----
    char* base = (char*)d_ws;
    int* flags = (int*)base;                       // 256 B
    float* f32a = (float*)(base + 256);
    float* x  = f32a;                              // N*256
    float* s1 = x  + (size_t)NN * 256;             // N*256
    float* s2 = s1 + (size_t)NN * 256;             // N*256
    float* big = s2 + (size_t)NN * 256;            // N*768
    float* s3 = big + (size_t)NN * 512;            // alias of big's tail (lifetimes audited)
    float* part = big + (size_t)NN * 768;          // 96*512
    float* stats = part + 96 * 512;                // 512 (unused since R7)
    float* gf  = stats + 512;                      // G*256
    float* l1b = gf + GG * 256;                    // G*128
    float* l2b = l1b + GG * 128;                   // G*64
    bf* wt = (bf*)(l2b + GG * 64);                 // bf16 W^T mirrors
    const long O_NA = 0, O_G1 = 131072, O_G2 = 327680, O_AI = 524288,
               O_AO = 1114112, O_M1 = 1310720, O_M2 = 1703936,
               O_TRO = 2097152, O_FC = 2129920, WT_TOT = 2162688;
    short* gewt_h = (short*)(wt + WT_TOT);         // 49152 shorts
    short* gewt_l = gewt_h + 49152;                // 49152 shorts
    // E tables: ETAB_ELEMS shorts each + 1024-short pad.
    short* et_h = gewt_l + 49152;
    short* et_l = et_h + (ETAB_ELEMS + 1024);
    size_t REQ = 256 + ((size_t)NN * 1536 + 96 * 512 + 512 + GG * 448) * 4
               + WT_TOT * 2 + 49152 * 2 * 2
               + ((size_t)ETAB_ELEMS + 1024) * 2 * 2;
    if (ws_size < REQ) { signal_k<<<1, 256, 0, stream>>>(out, sigN, 9999.f); return; }

    const float* t       = (const float*)d_in[0];
    const float* frac    = (const float*)d_in[1];
    const float* lattice = (const float*)d_in[2];
    const float* type_emb = (const float*)d_in[3];

    detect_int_k<<<1, 256, 0, stream>>>((const unsigned int*)d_in[42], flags);

    // combined weight prep (one dispatch for the 9 transposes)
    {
        TArgs ta;
        const int srcIdx[9] = {4, 8, 10, 12, 14, 16, 18, 28, 37};
        const long dof[9]  = {O_NA, O_G1, O_G2, O_AI, O_AO, O_M1, O_M2, O_TRO, O_FC};
        const int Ks[9] = {512, 256, 256, 256, 256, 256, 512, 256, 256};
        const int Ns[9] = {256, 256, 256, 768, 256, 512, 256, 128, 128};
        const int Ls[9] = {1, 3, 3, 3, 3, 3, 3, 1, 1};
        int blk = 0;
        for (int s = 0; s < 9; ++s) {
            ta.src[s] = (const float*)d_in[srcIdx[s]];
            ta.dstOff[s] = dof[s];
            ta.K[s] = Ks[s]; ta.N[s] = Ns[s]; ta.L[s] = Ls[s];
            ta.blk0[s] = blk;
            blk += (Ks[s] * Ns[s] * Ls[s] + 255) / 256;
        }
        ta.blk0[9] = blk;
        transp_all<<<blk, 256, 0, stream>>>(ta, wt);
    }
    prep_gew<<<192, 256, 0, stream>>>((const float*)d_in[6], gewt_h, gewt_l);
    prep_etab<<<(ETAB_ELEMS + 255) / 256, 256, 0, stream>>>(frac, et_h, et_l);

    // x0 = concat(type_emb[atoms], time_emb) @ naW + nab
    build_A<<<(NN * 512 + 255) / 256, 256, 0, stream>>>(t, type_emb,
        (const unsigned int*)d_in[42], big, flags);
    gemmM(stream, big, wt + O_NA, (const float*)d_in[5], nullptr, x, NN, 512, 256, 0);

    for (int l = 0; l < LL; ++l) {
        // GINE: s1 = x + aggr (MFMA split-bf16, DMA double-buffered E tiles)
        gine4<<<GG * 4, 256, 0, stream>>>(x, lattice,
            (const float*)d_in[6], (const float*)d_in[7], gewt_h, gewt_l,
            et_h, et_l, s1, l);
        // s2 = silu(s1@gW1+gb1); s3 = s2@gW2+gb2 + x; h1 = BN(s3) -> s2
        gemmM(stream, s1, wt + O_G1 + (long)l * 65536, (const float*)d_in[9]  + l * 256, nullptr, s2, NN, 256, 256, 2);
        gemmM(stream, s2, wt + O_G2 + (long)l * 65536, (const float*)d_in[11] + l * 256, x, s3, NN, 256, 256, 0);
        run_bn(stream, s3, part, stats, (const float*)d_in[20] + l * 256, (const float*)d_in[21] + l * 256, nullptr, s2);
        // attention: qkv=big; o=s1; s3 = s1@aoW+aob + x; s1 = h1 + BN(s3)
        gemmM(stream, x, wt + O_AI + (long)l * 196608, (const float*)d_in[13] + l * 768, nullptr, big, NN, 256, 768, 0);
        attn2<<<GG, 256, 0, stream>>>(big, s1);
        gemmM(stream, s1, wt + O_AO + (long)l * 65536, (const float*)d_in[15] + l * 256, x, s3, NN, 256, 256, 0);
        run_bn(stream, s3, part, stats, (const float*)d_in[22] + l * 256, (const float*)d_in[23] + l * 256, s2, s1);
        // MLP: big = relu(s1@mW1+mb1); s3 = big@mW2+mb2 + s1; x = BN(s3)
        gemmM(stream, s1, wt + O_M1 + (long)l * 131072, (const float*)d_in[17] + l * 512, nullptr, big, NN, 256, 512, 1);
        gemmM(stream, big, wt + O_M2 + (long)l * 131072, (const float*)d_in[19] + l * 256, s1, s3, NN, 512, 256, 0);
        run_bn(stream, s3, part, stats, (const float*)d_in[24] + l * 256, (const float*)d_in[25] + l * 256, nullptr, x);
    }

    ln_kernel<<<NN, 256, 0, stream>>>(x, (const float*)d_in[26], (const float*)d_in[27], s1);
    pool_kernel<<<GG, 256, 0, stream>>>(s1, gf);

    // types_pred -> out[0 : N*100]
    gemmM(stream, s1, wt + O_TRO, (const float*)d_in[29], nullptr, s2, NN, 256, 128, 2);
    gemm(stream, s2, (const float*)d_in[30], (const float*)d_in[31], nullptr, out, NN, 128, 100, 0);
    // lattice_pred -> out[N*100 : +G*9]  (fused 3-stage head, R7)
    lat_head<<<GG, 256, 0, stream>>>(gf, (const float*)d_in[32], (const float*)d_in[33],
        (const float*)d_in[34], (const float*)d_in[35], (const float*)d_in[36],
        out + (size_t)NN * 100);
    // frac_pred -> out[N*100+G*9 : ]
    gemmM(stream, s1, wt + O_FC, (const float*)d_in[38], nullptr, s2, NN, 256, 128, 2);
    gemm(stream, s2, (const float*)d_in[39], (const float*)d_in[40], nullptr, s3, NN, 128, 64, 2);
    gemm(stream, s3, (const float*)d_in[41], nullptr, nullptr, out + (size_t)NN * 100 + GG * 9, NN, 64, 3, 0);
}

// Round 9
// 764.082 us; speedup vs baseline: 1.2912x; 1.1188x over previous
//
#include <hip/hip_runtime.h>
#include <hip/hip_bf16.h>
#include <math.h>

#define GG 256
#define NP 24
#define LL 3
#define CC 256
#define NN (GG*NP)   // 6144 nodes
#define HH 4
#define DH 64

typedef __hip_bfloat16 bf;
typedef __attribute__((ext_vector_type(8))) short bfrag;   // 8 bf16 (4 VGPR)
typedef __attribute__((ext_vector_type(4))) float ffrag;   // 4 fp32 acc

__device__ __forceinline__ short pk(float x) {
    union { bf h; short s; } u; u.h = __float2bfloat16(x); return u.s;
}
__device__ __forceinline__ float b2f_s(short x) {
    union { short s; bf h; } u; u.s = x; return __bfloat162float(u.h);
}

// ---------------------------------------------------------------------------
__global__ void detect_int_k(const unsigned int* __restrict__ at, int* flags) {
    __shared__ int ok;
    if (threadIdx.x == 0) ok = 1;
    __syncthreads();
    if (at[2 * threadIdx.x + 1] != 0u) ok = 0;   // benign race
    __syncthreads();
    if (threadIdx.x == 0) flags[0] = ok;
}

__global__ void signal_k(float* out, int n, float val) {
    int i = blockIdx.x * 256 + threadIdx.x;
    if (i < n) out[i] = val;
}

// ---------------------------------------------------------------------------
// Combined weight prep (9 segments in ONE dispatch): fp32 [L][K][N] ->
// bf16 [L][N][K] at wt+dstOff.
// ---------------------------------------------------------------------------
struct TArgs {
    const float* src[9];
    long dstOff[9];
    int K[9], N[9], L[9];
    int blk0[10];
};
__global__ void transp_all(TArgs a, bf* __restrict__ wt) {
    int bid = blockIdx.x;
    int s = 0;
    while (s < 8 && bid >= a.blk0[s + 1]) ++s;
    long idx = (long)(bid - a.blk0[s]) * 256 + threadIdx.x;
    int KN = a.K[s] * a.N[s];
    long sz = (long)KN * a.L[s];
    if (idx >= sz) return;
    int l = (int)(idx / KN);
    int rem = (int)(idx % KN);
    int k = rem / a.N[s], n = rem % a.N[s];
    wt[a.dstOff[s] + (long)l * KN + (long)n * a.K[s] + k] =
        __float2bfloat16(a.src[s][idx]);
}

// ---------------------------------------------------------------------------
// GINE edge-weight prep: geW fp32 [L][69][256] -> split bf16 W^T
// [L][half][n 0..127][k 0..63] (k<60 real, else 0), hi and lo parts.
// ---------------------------------------------------------------------------
__global__ void prep_gew(const float* __restrict__ geW, short* __restrict__ wh,
                         short* __restrict__ wl) {
    int idx = blockIdx.x * 256 + threadIdx.x;   // 3*2*128*64 = 49152
    if (idx >= 49152) return;
    int k = idx & 63;
    int n = (idx >> 6) & 127;
    int half = (idx >> 13) & 1;
    int l = idx >> 14;
    float v = (k < 60) ? geW[(long)l * 69 * 256 + (long)k * 256 + half * 128 + n] : 0.f;
    short hi = pk(v);
    short lo = pk(v - b2f_s(hi));
    wh[idx] = hi;
    wl[idx] = lo;
}

// ---------------------------------------------------------------------------
// E-table precompute: sin/cos edge features depend only on frac — layer- and
// half-independent. Built once, bit-identically to the original in-kernel
// expression, in MFMA-fragment layout [(g*24+j)*24+i][k 0..63].
// ---------------------------------------------------------------------------
#define ETAB_ELEMS (GG * 24 * 24 * 64)   // 9437184
__global__ void prep_etab(const float* __restrict__ frac, short* __restrict__ eh,
                          short* __restrict__ el) {
    int idx = blockIdx.x * 256 + threadIdx.x;
    if (idx >= ETAB_ELEMS) return;
    int k = idx & 63;
    int rem = idx >> 6;           // (g*24 + j)*24 + i
    int i = rem % 24;
    int rem2 = rem / 24;
    int j = rem2 % 24;
    int g = rem2 / 24;
    float val = 0.f;
    if (k < 60) {
        int r = (k < 30) ? k : k - 30;
        int d = r / 10, f = r % 10;
        float fd = frac[g * 72 + j * 3 + d] - frac[g * 72 + i * 3 + d];
        fd -= floorf(fd);
        float ang = 6.283185307179586f * (float)f * fd;
        val = (k < 30) ? sinf(ang) : cosf(ang);
    }
    short hi = pk(val);
    eh[idx] = hi;
    el[idx] = pk(val - b2f_s(hi));
}

// ---------------------------------------------------------------------------
// A = [type_emb[atom_types] | time_emb]  (N x 512, fp32)
// ---------------------------------------------------------------------------
__global__ void build_A(const float* __restrict__ t, const float* __restrict__ type_emb,
                        const unsigned int* __restrict__ atoms,
                        float* __restrict__ A, const int* __restrict__ flags) {
    int i64 = flags[0];
    int idx = blockIdx.x * 256 + threadIdx.x;
    if (idx >= NN * 512) return;
    int n = idx >> 9;
    int k = idx & 511;
    if (k < 256) {
        int a = i64 ? (int)atoms[2 * n] : (int)atoms[n];
        A[idx] = type_emb[(long)a * CC + k];
    } else {
        int d = k - 256;
        int g = n / NP;
        float tv = t[g];
        int dd = (d < 128) ? d : d - 128;
        float tf = expf(dd * (-9.210340371976184f / 127.0f));
        float ang = tv * tf;
        A[idx] = (d < 128) ? sinf(ang) : cosf(ang);
    }
}

// ---------------------------------------------------------------------------
// MFMA bf16 GEMM — R9 retile 64x128 -> 64x64. R8's lesson: the absmax
// threshold has ZERO headroom; only bit-exact-by-CONSTRUCTION changes pass.
// The retile qualifies: each output element's accumulator receives exactly
// one MFMA per k0-step, k0 ascending, regardless of tile partition — the
// partition changes WHICH wave computes an output, never its op sequence;
// the epilogue text is untouched. Why: at 64x128 the N=256 gemms had only
// 192 blocks (<1/CU, half the CUs idle — same occupancy trap gine4 had).
// 64x64 gives 384/768/1152 blocks (N=256/512/768) at 10 KB LDS/block.
// ---------------------------------------------------------------------------
__global__ __launch_bounds__(256) void gemm_mfma(
        const float* __restrict__ A, const bf* __restrict__ Wt,
        const float* __restrict__ bias, const float* __restrict__ res,
        float* __restrict__ C, int M, int K, int N, int act) {
    __shared__ short As[64 * 40];
    __shared__ short Bs[64 * 40];
    int tid = threadIdx.x;
    int lane = tid & 63, w = tid >> 6;
    int wm = w & 1, wn = w >> 1;
    int m0 = blockIdx.x * 64, n0 = blockIdx.y * 64;
    ffrag acc[2][2] = {};
    int sa_m = tid >> 2, sa_k = (tid & 3) << 3;
    int sb_n = tid >> 2, sb_k = (tid & 3) << 3;
    int fr_row = lane & 15, fr_k = (lane >> 4) << 3;

    for (int k0 = 0; k0 < K; k0 += 32) {
        const float* Ap = A + (long)(m0 + sa_m) * K + k0 + sa_k;
        float4 a1 = *(const float4*)Ap;
        float4 a2 = *(const float4*)(Ap + 4);
        float4 b1 = *(const float4*)(Wt + (long)(n0 + sb_n) * K + k0 + sb_k);
        __syncthreads();
        bfrag av;
        av[0] = pk(a1.x); av[1] = pk(a1.y); av[2] = pk(a1.z); av[3] = pk(a1.w);
        av[4] = pk(a2.x); av[5] = pk(a2.y); av[6] = pk(a2.z); av[7] = pk(a2.w);
        *(bfrag*)(&As[sa_m * 40 + sa_k]) = av;
        *(float4*)(&Bs[sb_n * 40 + sb_k]) = b1;
        __syncthreads();
        bfrag af[2], bg[2];
#pragma unroll
        for (int mt = 0; mt < 2; ++mt)
            af[mt] = *(const bfrag*)(&As[(wm * 32 + mt * 16 + fr_row) * 40 + fr_k]);
#pragma unroll
        for (int nt = 0; nt < 2; ++nt)
            bg[nt] = *(const bfrag*)(&Bs[(wn * 32 + nt * 16 + fr_row) * 40 + fr_k]);
#pragma unroll
        for (int mt = 0; mt < 2; ++mt)
#pragma unroll
            for (int nt = 0; nt < 2; ++nt)
                acc[mt][nt] = __builtin_amdgcn_mfma_f32_16x16x32_bf16(
                    af[mt], bg[nt], acc[mt][nt], 0, 0, 0);
    }

    int mbase = (lane >> 4) << 2;
#pragma unroll
    for (int mt = 0; mt < 2; ++mt) {
#pragma unroll
        for (int nt = 0; nt < 2; ++nt) {
            int n = n0 + wn * 32 + nt * 16 + (lane & 15);
            float bv = bias ? bias[n] : 0.f;
#pragma unroll
            for (int r = 0; r < 4; ++r) {
                int m = m0 + wm * 32 + mt * 16 + mbase + r;
                float v = acc[mt][nt][r] + bv;
                if (act == 1) v = fmaxf(v, 0.f);
                else if (act == 2) v = v / (1.f + expf(-v));
                if (res) v += res[(long)m * N + n];
                C[(long)m * N + n] = v;
            }
        }
    }
}

// ---------------------------------------------------------------------------
// fp32 tiled GEMM (small/odd-N). Validated R9-R13.
// ---------------------------------------------------------------------------
__global__ __launch_bounds__(256) void gemm_k(
        const float* __restrict__ A, const float* __restrict__ W,
        const float* __restrict__ bias, const float* __restrict__ res,
        float* __restrict__ Cf, int M, int K, int Nc, int act) {
    __shared__ __align__(16) float Asf[32][64];
    __shared__ __align__(16) float Bsf[32][64];
    int tid = threadIdx.x;
    int tx = tid & 15, ty = tid >> 4;
    int m0 = blockIdx.x * 64, n0 = blockIdx.y * 64;
    float acc[4][4] = {{0.f}};
    int am = tid >> 2;
    int ak = (tid & 3) << 3;
    int bk = tid >> 4;
    int bn = (tid & 15) << 2;

    for (int k0 = 0; k0 < K; k0 += 32) {
        const float* Ap = A + (long)(m0 + am) * K + k0 + ak;
        float4 a1 = *(const float4*)Ap;
        float4 a2 = *(const float4*)(Ap + 4);
        float w1[4], w2[4];
#pragma unroll
        for (int u = 0; u < 4; ++u) {
            int n = n0 + bn + u;
            w1[u] = (n < Nc) ? W[(long)(k0 + bk) * Nc + n] : 0.f;
            w2[u] = (n < Nc) ? W[(long)(k0 + bk + 16) * Nc + n] : 0.f;
        }
        __syncthreads();
        Asf[ak + 0][am] = a1.x; Asf[ak + 1][am] = a1.y;
        Asf[ak + 2][am] = a1.z; Asf[ak + 3][am] = a1.w;
        Asf[ak + 4][am] = a2.x; Asf[ak + 5][am] = a2.y;
        Asf[ak + 6][am] = a2.z; Asf[ak + 7][am] = a2.w;
#pragma unroll
        for (int u = 0; u < 4; ++u) {
            Bsf[bk][bn + u] = w1[u];
            Bsf[bk + 16][bn + u] = w2[u];
        }
        __syncthreads();
#pragma unroll
        for (int k = 0; k < 32; ++k) {
            float4 a = *(const float4*)(&Asf[k][ty << 2]);
            float4 b = *(const float4*)(&Bsf[k][tx << 2]);
            acc[0][0] += a.x * b.x; acc[0][1] += a.x * b.y; acc[0][2] += a.x * b.z; acc[0][3] += a.x * b.w;
            acc[1][0] += a.y * b.x; acc[1][1] += a.y * b.y; acc[1][2] += a.y * b.z; acc[1][3] += a.y * b.w;
            acc[2][0] += a.z * b.x; acc[2][1] += a.z * b.y; acc[2][2] += a.z * b.z; acc[2][3] += a.z * b.w;
            acc[3][0] += a.w * b.x; acc[3][1] += a.w * b.y; acc[3][2] += a.w * b.z; acc[3][3] += a.w * b.w;
        }
    }
#pragma unroll
    for (int i = 0; i < 4; ++i) {
        int m = m0 + (ty << 2) + i;
#pragma unroll
        for (int j = 0; j < 4; ++j) {
            int n = n0 + (tx << 2) + j;
            if (n >= Nc) continue;
            float v = acc[i][j];
            if (bias) v += bias[n];
            if (act == 1) v = fmaxf(v, 0.f);
            else if (act == 2) v = v / (1.f + expf(-v));
            if (res) v += res[(long)m * Nc + n];
            Cf[(long)m * Nc + n] = v;
        }
    }
}

// ---------------------------------------------------------------------------
// GINE v13 — R1/R4 structure + async DMA double-buffered E staging.
// WIN R6: 957 -> 890 µs. Unchanged since.
// ---------------------------------------------------------------------------
#define MF(a, b, c) c = __builtin_amdgcn_mfma_f32_16x16x32_bf16(a, b, c, 0, 0, 0)

typedef __attribute__((address_space(1))) const void gv_t;
typedef __attribute__((address_space(3))) void lv_t;

// Stage one 24x64-short E-tile pair (eh->lds[0..1535], el->lds[2048..3583])
// as 6 DMA chunks of 512 shorts (64 lanes x 16 B). Wave w: chunks w, w+4.
__device__ __forceinline__ void stage_etile(const short* __restrict__ ej_h,
                                            const short* __restrict__ ej_l,
                                            short* lds_base, int w, int lane) {
    {
        int c = w;   // 0..3
        const short* src = (c < 3) ? (ej_h + c * 512) : (ej_l + (c - 3) * 512);
        int doff = (c < 3) ? c * 512 : 2048 + (c - 3) * 512;
        __builtin_amdgcn_global_load_lds((gv_t*)(src + lane * 8),
                                         (lv_t*)(lds_base + doff), 16, 0, 0);
    }
    if (w < 2) {
        int c = w + 4;   // 4,5 -> el chunks 1,2
        const short* src = ej_l + (c - 3) * 512;
        int doff = 2048 + (c - 3) * 512;
        __builtin_amdgcn_global_load_lds((gv_t*)(src + lane * 8),
                                         (lv_t*)(lds_base + doff), 16, 0, 0);
    }
}

__global__ __launch_bounds__(256, 4) void gine4(
        const float* __restrict__ x,
        const float* __restrict__ lattice, const float* __restrict__ geW,
        const float* __restrict__ geb, const short* __restrict__ gewt_h,
        const short* __restrict__ gewt_l, const short* __restrict__ et_h,
        const short* __restrict__ et_l, float* __restrict__ z, int l) {
    __shared__ __align__(16) float xls[24 * 132];  // 12672 B
    __shared__ float basel[128];                   // 512 B
    __shared__ __align__(16) short ebuf[8192];     // 2 x (eh 32r + el 32r) x 64

    int tid = threadIdx.x;
    int lane = tid & 63, w = tid >> 6, quad = lane >> 4, l16 = lane & 15;
    int g = blockIdx.x >> 2;
    int half = (blockIdx.x >> 1) & 1;
    int jh = blockIdx.x & 1;           // j range jh*12 .. jh*12+11

    // ---- stage x half (float4), base ----
    {
        const float4* xg = (const float4*)x;
        for (int idx = tid; idx < 768; idx += 256) {
            int i = idx >> 5, c4 = idx & 31;
            ((float4*)(xls + i * 132))[c4] =
                xg[((long)(g * NP + i) * CC + half * 128) / 4 + c4];
        }
    }
    if (tid < 128) {
        int cg = half * 128 + tid;
        float bv = geb[(long)l * CC + cg];
#pragma unroll
        for (int q = 0; q < 9; ++q)
            bv += lattice[(long)g * 9 + q] * geW[(long)l * 69 * 256 + (long)(60 + q) * 256 + cg];
        basel[tid] = bv;
    }

    // ---- B fragments direct from global (loop-invariant, named scalars) ----
    bfrag bh00, bh01, bh10, bh11, bl00, bl01, bl10, bl11;
    {
        long base = (long)(l * 2 + half) * 8192;   // shorts: 128 rows x 64
        int nrow0 = w * 32 + l16;                  // nt=0
        int nrow1 = w * 32 + 16 + l16;             // nt=1
        const short* p0h = gewt_h + base + nrow0 * 64 + quad * 8;
        const short* p1h = gewt_h + base + nrow1 * 64 + quad * 8;
        const short* p0l = gewt_l + base + nrow0 * 64 + quad * 8;
        const short* p1l = gewt_l + base + nrow1 * 64 + quad * 8;
        bh00 = *(const bfrag*)(p0h);      bh01 = *(const bfrag*)(p0h + 32);
        bh10 = *(const bfrag*)(p1h);      bh11 = *(const bfrag*)(p1h + 32);
        bl00 = *(const bfrag*)(p0l);      bl01 = *(const bfrag*)(p0l + 32);
        bl10 = *(const bfrag*)(p1l);      bl11 = *(const bfrag*)(p1l + 32);
    }

    const short* ehg = et_h + (long)g * (24 * 24 * 64);
    const short* elg = et_l + (long)g * (24 * 24 * 64);
    int j0 = jh * 12;

    // prologue: DMA first tile into buf 0
    stage_etile(ehg + (long)j0 * 1536, elg + (long)j0 * 1536, ebuf, w, lane);
    __syncthreads();   // drains DMA + makes xls/basel visible

    float bse0 = basel[w * 32 + l16];
    float bse1 = basel[w * 32 + 16 + l16];

    int cur = 0;
    for (int jc = 0; jc < 12; ++jc) {
        int j = j0 + jc;
        // issue next tile's DMA into the other buffer (hidden under compute)
        if (jc < 11) {
            stage_etile(ehg + (long)(j + 1) * 1536, elg + (long)(j + 1) * 1536,
                        ebuf + (cur ^ 1) * 4096, w, lane);
        }

        const short* eb = ebuf + cur * 4096;
        int r0 = l16 * 64 + quad * 8;          // mt=0 row offset (shorts)
        int r1 = (16 + l16) * 64 + quad * 8;   // mt=1
        bfrag ah00 = *(const bfrag*)(eb + r0);
        bfrag ah01 = *(const bfrag*)(eb + r0 + 32);
        bfrag ah10 = *(const bfrag*)(eb + r1);
        bfrag ah11 = *(const bfrag*)(eb + r1 + 32);
        bfrag al00 = *(const bfrag*)(eb + 2048 + r0);
        bfrag al01 = *(const bfrag*)(eb + 2048 + r0 + 32);
        bfrag al10 = *(const bfrag*)(eb + 2048 + r1);
        bfrag al11 = *(const bfrag*)(eb + 2048 + r1 + 32);

        ffrag a00 = {}, a01 = {}, a10 = {}, a11 = {};   // acc[mt][nt]
        // mt=0, ks=0
        MF(ah00, bh00, a00); MF(ah00, bl00, a00); MF(al00, bh00, a00);
        MF(ah00, bh10, a01); MF(ah00, bl10, a01); MF(al00, bh10, a01);
        // mt=0, ks=1
        MF(ah01, bh01, a00); MF(ah01, bl01, a00); MF(al01, bh01, a00);
        MF(ah01, bh11, a01); MF(ah01, bl11, a01); MF(al01, bh11, a01);
        // mt=1, ks=0
        MF(ah10, bh00, a10); MF(ah10, bl00, a10); MF(al10, bh00, a10);
        MF(ah10, bh10, a11); MF(ah10, bl10, a11); MF(al10, bh10, a11);
        // mt=1, ks=1
        MF(ah11, bh01, a10); MF(ah11, bl01, a10); MF(al11, bh01, a10);
        MF(ah11, bh11, a11); MF(ah11, bl11, a11); MF(al11, bh11, a11);

        // epilogue: relu + reduce over i, write z[g*24+j][cg]
#pragma unroll
        for (int nt = 0; nt < 2; ++nt) {
            int cl = w * 32 + nt * 16 + l16;
            float bse = nt ? bse1 : bse0;
            ffrag am0 = nt ? a01 : a00;   // mt=0 acc (ibase = quad*4, < 24)
            ffrag am1 = nt ? a11 : a10;   // mt=1 acc (valid only quad<2)
            float part = 0.f;
            {
                int ibase = quad * 4;
#pragma unroll
                for (int r = 0; r < 4; ++r) {
                    float xv = xls[(ibase + r) * 132 + cl];
                    part += fmaxf(xv + bse + am0[r], 0.f);
                }
            }
            if (quad < 2) {
                int ibase = 16 + quad * 4;
#pragma unroll
                for (int r = 0; r < 4; ++r) {
                    float xv = xls[(ibase + r) * 132 + cl];
                    part += fmaxf(xv + bse + am1[r], 0.f);
                }
            }
            part += __shfl_xor(part, 16);
            part += __shfl_xor(part, 32);
            if (lane < 16)
                z[(long)(g * NP + j) * CC + half * 128 + cl] = xls[j * 132 + cl] + part;
        }
        __syncthreads();
        cur ^= 1;
    }
}

// ---------------------------------------------------------------------------
// BN: R7-exact structure (R8's stats-fusion + dual-apply shifted absmax one
// quantum over threshold — reverted; only bit-exact-by-construction changes
// are allowed on this problem).
// ---------------------------------------------------------------------------
__global__ void bn_stats1(const float* __restrict__ in, float* __restrict__ part) {
    int c = threadIdx.x, b = blockIdx.x;
    float s = 0.f, q = 0.f;
    for (int r = 0; r < 64; ++r) {
        float v = in[(long)(b * 64 + r) * CC + c];
        s += v; q += v * v;
    }
    part[b * 512 + c] = s;
    part[b * 512 + 256 + c] = q;
}
__global__ __launch_bounds__(256) void bn_apply2(
        const float* __restrict__ in, const float* __restrict__ part,
        const float* __restrict__ gma, const float* __restrict__ bta,
        const float* __restrict__ add, float* __restrict__ out) {
    int c = threadIdx.x;
    float s = 0.f, q = 0.f;
    for (int b = 0; b < 96; ++b) { s += part[b * 512 + c]; q += part[b * 512 + 256 + c]; }
    float m = s / (float)NN;
    float var = q / (float)NN - m * m;
    float stats_c = m;
    float stats_rs = rsqrtf(var + 1e-5f);
    float gc = gma[c], bc = bta[c];
    for (int r = blockIdx.x; r < NN; r += 768) {
        long idx = (long)r * CC + c;
        float v = (in[idx] - stats_c) * stats_rs * gc + bc;
        if (add) v += add[idx];
        out[idx] = v;
    }
}

// ---------------------------------------------------------------------------
// Attention v2 (validated R10).
// ---------------------------------------------------------------------------
__global__ __launch_bounds__(256, 2) void attn2(const float* __restrict__ qkv,
                                                float* __restrict__ o) {
    __shared__ __align__(16) float Kl[24 * 4 * 68];
    __shared__ __align__(16) float Vl[24 * 4 * 68];
    __shared__ float S[4 * 24 * 25];
    int tid = threadIdx.x, g = blockIdx.x;

    const float4* qkv4 = (const float4*)(qkv + (long)g * NP * 768);
    for (int idx = tid; idx < 24 * 128; idx += 256) {
        int row = idx >> 7;
        int c4 = idx & 127;
        int isV = c4 >> 6;
        int cc = c4 & 63;
        int h = cc >> 4, d4 = cc & 15;
        float4 val = qkv4[row * 192 + 64 + c4];
        float* dst = (isV ? Vl : Kl) + (row * 4 + h) * 68 + d4 * 4;
        *(float4*)dst = val;
    }
    __syncthreads();

    if (tid < 96) {
        int h = tid & 3, i = tid >> 2;
        const float4* qp = (const float4*)(qkv + ((long)(g * NP + i)) * 768 + h * 64);
        float4 q[16];
#pragma unroll
        for (int k = 0; k < 16; ++k) q[k] = qp[k];
        float sc[24];
        float mx = -1e30f;
        for (int j = 0; j < 24; ++j) {
            const float4* kp = (const float4*)(Kl + (j * 4 + h) * 68);
            float da = 0.f, db = 0.f;
#pragma unroll
            for (int k = 0; k < 16; k += 2) {
                float4 kv = kp[k];
                da += q[k].x * kv.x; da += q[k].y * kv.y;
                da += q[k].z * kv.z; da += q[k].w * kv.w;
                float4 kv2 = kp[k + 1];
                db += q[k + 1].x * kv2.x; db += q[k + 1].y * kv2.y;
                db += q[k + 1].z * kv2.z; db += q[k + 1].w * kv2.w;
            }
            float s = (da + db) * 0.125f;
            sc[j] = s;
            mx = fmaxf(mx, s);
        }
        float sum = 0.f;
#pragma unroll
        for (int j = 0; j < 24; ++j) { float p = expf(sc[j] - mx); sc[j] = p; sum += p; }
        float inv = 1.f / sum;
#pragma unroll
        for (int j = 0; j < 24; ++j) S[(h * 24 + i) * 25 + j] = sc[j] * inv;
    }
    __syncthreads();

    int h = tid >> 6, d = tid & 63;
    for (int i = 0; i < 24; ++i) {
        const float* Sp = S + (h * 24 + i) * 25;
        float a0 = 0.f, a1 = 0.f;
#pragma unroll
        for (int j = 0; j < 24; j += 2) {
            a0 += Sp[j] * Vl[(j * 4 + h) * 68 + d];
            a1 += Sp[j + 1] * Vl[((j + 1) * 4 + h) * 68 + d];
        }
        o[(long)(g * NP + i) * CC + h * 64 + d] = a0 + a1;
    }
}

// ---------------------------------------------------------------------------
__global__ __launch_bounds__(256) void ln_kernel(const float* __restrict__ x,
        const float* __restrict__ gma, const float* __restrict__ bta,
        float* __restrict__ out) {
    __shared__ float red[256];
    int n = blockIdx.x, c = threadIdx.x;
    float v = x[(long)n * CC + c];
    red[c] = v;
    __syncthreads();
    for (int s = 128; s > 0; s >>= 1) { if (c < s) red[c] += red[c + s]; __syncthreads(); }
    float m = red[0] * (1.f / 256.f);
    __syncthreads();
    float dv = v - m;
    red[c] = dv * dv;
    __syncthreads();
    for (int s = 128; s > 0; s >>= 1) { if (c < s) red[c] += red[c + s]; __syncthreads(); }
    float var = red[0] * (1.f / 256.f);
    out[(long)n * CC + c] = dv * rsqrtf(var + 1e-5f) * gma[c] + bta[c];
}

__global__ void pool_kernel(const float* __restrict__ hn, float* __restrict__ gf) {
    int g = blockIdx.x, c = threadIdx.x;
    float s = 0.f;
    for (int j = 0; j < NP; ++j) s += hn[(long)(g * NP + j) * CC + c];
    gf[g * CC + c] = s * (1.f / 24.f);
}

// ---------------------------------------------------------------------------
// Fused lattice head (R7, validated): silu(silu(gf@W1+b1)@W2+b2)@W3, one
// dispatch, bitwise ascending-k accumulation.
// ---------------------------------------------------------------------------
__global__ __launch_bounds__(256) void lat_head(
        const float* __restrict__ gf, const float* __restrict__ W1,
        const float* __restrict__ b1, const float* __restrict__ W2,
        const float* __restrict__ b2, const float* __restrict__ W3,
        float* __restrict__ out) {
    __shared__ float gfl[256];
    __shared__ float h1[128];
    __shared__ float h2[64];
    int g = blockIdx.x, t = threadIdx.x;
    gfl[t] = gf[(long)g * 256 + t];
    __syncthreads();
    if (t < 128) {
        float acc = 0.f;
        for (int k = 0; k < 256; ++k) acc += gfl[k] * W1[k * 128 + t];
        float v = acc;
        v += b1[t];
        v = v / (1.f + expf(-v));
        h1[t] = v;
    }
    __syncthreads();
    if (t < 64) {
        float acc = 0.f;
        for (int k = 0; k < 128; ++k) acc += h1[k] * W2[k * 64 + t];
        float v = acc;
        v += b2[t];
        v = v / (1.f + expf(-v));
        h2[t] = v;
    }
    __syncthreads();
    if (t < 9) {
        float acc = 0.f;
        for (int k = 0; k < 64; ++k) acc += h2[k] * W3[k * 9 + t];
        out[(long)g * 9 + t] = acc;
    }
}

// ---------------------------------------------------------------------------
static void gemm(hipStream_t st, const float* A, const float* W, const float* bias,
                 const float* res, float* Cf, int M, int K, int Nc, int act) {
    dim3 grid(M / 64, (Nc + 63) / 64);
    gemm_k<<<grid, 256, 0, st>>>(A, W, bias, res, Cf, M, K, Nc, act);
}

static void gemmM(hipStream_t st, const float* A, const bf* Wt, const float* bias,
                  const float* res, float* Cf, int M, int K, int N, int act) {
    dim3 grid(M / 64, N / 64);
    gemm_mfma<<<grid, 256, 0, st>>>(A, Wt, bias, res, Cf, M, K, N, act);
}

static void run_bn(hipStream_t st, const float* in, float* part, float* stats,
                   const float* g_, const float* b_, const float* add, float* out) {
    (void)stats;
    bn_stats1<<<96, 256, 0, st>>>(in, part);
    bn_apply2<<<768, 256, 0, st>>>(in, part, g_, b_, add, out);
}

extern "C" void kernel_launch(void* const* d_in, const int* in_sizes, int n_in,
                              void* d_out, int out_size, void* d_ws, size_t ws_size,
                              hipStream_t stream) {
    float* out = (float*)d_out;
    int sigN = out_size < 256 ? out_size : 256;

    static const int EXP_SIZES[46] = {
        256, 18432, 2304, 25600, 131072, 256, 52992, 768, 196608, 768,
        196608, 768, 589824, 2304, 196608, 768, 393216, 1536, 393216, 768,
        768, 768, 768, 768, 768, 768, 256, 256, 32768, 128,
        12800, 100, 32768, 128, 8192, 64, 576, 32768, 128, 8192,
        64, 192, 6144, 6144, 147456, 147456 };
    if (n_in != 46) { signal_k<<<1, 256, 0, stream>>>(out, sigN, 3000.f + 8.f * n_in); return; }
    for (int i = 0; i < 46; ++i)
        if (in_sizes[i] != EXP_SIZES[i]) { signal_k<<<1, 256, 0, stream>>>(out, sigN, 512.f + 8.f * i); return; }
    if (out_size != NN * 100 + GG * 9 + NN * 3) { signal_k<<<1, 256, 0, stream>>>(out, sigN, 7777.f); return; }

    // ---- workspace (R7-exact layout) ----
    char* base = (char*)d_ws;
    int* flags = (int*)base;                       // 256 B
    float* f32a = (float*)(base + 256);
    float* x  = f32a;                              // N*256
    float* s1 = x  + (size_t)NN * 256;             // N*256
    float* s2 = s1 + (size_t)NN * 256;             // N*256
    float* big = s2 + (size_t)NN * 256;            // N*768
    float* s3 = big + (size_t)NN * 512;            // alias of big's tail (lifetimes audited)
    float* part = big + (size_t)NN * 768;          // 96*512
    float* stats = part + 96 * 512;                // 512 (unused)
    float* gf  = stats + 512;                      // G*256
    float* l1b = gf + GG * 256;                    // G*128 (unused since lat_head)
    float* l2b = l1b + GG * 128;                   // G*64  (unused since lat_head)
    bf* wt = (bf*)(l2b + GG * 64);                 // bf16 W^T mirrors
    const long O_NA = 0, O_G1 = 131072, O_G2 = 327680, O_AI = 524288,
               O_AO = 1114112, O_M1 = 1310720, O_M2 = 1703936,
               O_TRO = 2097152, O_FC = 2129920, WT_TOT = 2162688;
    short* gewt_h = (short*)(wt + WT_TOT);         // 49152 shorts
    short* gewt_l = gewt_h + 49152;                // 49152 shorts
    // E tables: ETAB_ELEMS shorts each + 1024-short pad.
    short* et_h = gewt_l + 49152;
    short* et_l = et_h + (ETAB_ELEMS + 1024);
    size_t REQ = 256 + ((size_t)NN * 1536 + 96 * 512 + 512 + GG * 448) * 4
               + WT_TOT * 2 + 49152 * 2 * 2
               + ((size_t)ETAB_ELEMS + 1024) * 2 * 2;
    if (ws_size < REQ) { signal_k<<<1, 256, 0, stream>>>(out, sigN, 9999.f); return; }

    const float* t       = (const float*)d_in[0];
    const float* frac    = (const float*)d_in[1];
    const float* lattice = (const float*)d_in[2];
    const float* type_emb = (const float*)d_in[3];

    detect_int_k<<<1, 256, 0, stream>>>((const unsigned int*)d_in[42], flags);

    // combined weight prep (one dispatch for the 9 transposes)
    {
        TArgs ta;
        const int srcIdx[9] = {4, 8, 10, 12, 14, 16, 18, 28, 37};
        const long dof[9]  = {O_NA, O_G1, O_G2, O_AI, O_AO, O_M1, O_M2, O_TRO, O_FC};
        const int Ks[9] = {512, 256, 256, 256, 256, 256, 512, 256, 256};
        const int Ns[9] = {256, 256, 256, 768, 256, 512, 256, 128, 128};
        const int Ls[9] = {1, 3, 3, 3, 3, 3, 3, 1, 1};
        int blk = 0;
        for (int s = 0; s < 9; ++s) {
            ta.src[s] = (const float*)d_in[srcIdx[s]];
            ta.dstOff[s] = dof[s];
            ta.K[s] = Ks[s]; ta.N[s] = Ns[s]; ta.L[s] = Ls[s];
            ta.blk0[s] = blk;
            blk += (Ks[s] * Ns[s] * Ls[s] + 255) / 256;
        }
        ta.blk0[9] = blk;
        transp_all<<<blk, 256, 0, stream>>>(ta, wt);
    }
    prep_gew<<<192, 256, 0, stream>>>((const float*)d_in[6], gewt_h, gewt_l);
    prep_etab<<<(ETAB_ELEMS + 255) / 256, 256, 0, stream>>>(frac, et_h, et_l);

    // x0 = concat(type_emb[atoms], time_emb) @ naW + nab
    build_A<<<(NN * 512 + 255) / 256, 256, 0, stream>>>(t, type_emb,
        (const unsigned int*)d_in[42], big, flags);
    gemmM(stream, big, wt + O_NA, (const float*)d_in[5], nullptr, x, NN, 512, 256, 0);

    for (int l = 0; l < LL; ++l) {
        // GINE: s1 = x + aggr
        gine4<<<GG * 4, 256, 0, stream>>>(x, lattice,
            (const float*)d_in[6], (const float*)d_in[7], gewt_h, gewt_l,
            et_h, et_l, s1, l);
        // s2 = silu(s1@gW1+gb1); s3 = s2@gW2+gb2 + x; h1 = BN(s3) -> s2
        gemmM(stream, s1, wt + O_G1 + (long)l * 65536, (const float*)d_in[9]  + l * 256, nullptr, s2, NN, 256, 256, 2);
        gemmM(stream, s2, wt + O_G2 + (long)l * 65536, (const float*)d_in[11] + l * 256, x, s3, NN, 256, 256, 0);
        run_bn(stream, s3, part, stats, (const float*)d_in[20] + l * 256, (const float*)d_in[21] + l * 256, nullptr, s2);
        // attention: qkv=big; o=s1; s3 = s1@aoW+aob + x; s1 = h1 + BN(s3)
        gemmM(stream, x, wt + O_AI + (long)l * 196608, (const float*)d_in[13] + l * 768, nullptr, big, NN, 256, 768, 0);
        attn2<<<GG, 256, 0, stream>>>(big, s1);
        gemmM(stream, s1, wt + O_AO + (long)l * 65536, (const float*)d_in[15] + l * 256, x, s3, NN, 256, 256, 0);
        run_bn(stream, s3, part, stats, (const float*)d_in[22] + l * 256, (const float*)d_in[23] + l * 256, s2, s1);
        // MLP: big = relu(s1@mW1+mb1); s3 = big@mW2+mb2 + s1; x = BN(s3)
        gemmM(stream, s1, wt + O_M1 + (long)l * 131072, (const float*)d_in[17] + l * 512, nullptr, big, NN, 256, 512, 1);
        gemmM(stream, big, wt + O_M2 + (long)l * 131072, (const float*)d_in[19] + l * 256, s1, s3, NN, 512, 256, 0);
        run_bn(stream, s3, part, stats, (const float*)d_in[24] + l * 256, (const float*)d_in[25] + l * 256, nullptr, x);
    }

    ln_kernel<<<NN, 256, 0, stream>>>(x, (const float*)d_in[26], (const float*)d_in[27], s1);
    pool_kernel<<<GG, 256, 0, stream>>>(s1, gf);

    // types_pred -> out[0 : N*100]
    gemmM(stream, s1, wt + O_TRO, (const float*)d_in[29], nullptr, s2, NN, 256, 128, 2);
    gemm(stream, s2, (const float*)d_in[30], (const float*)d_in[31], nullptr, out, NN, 128, 100, 0);
    // lattice_pred -> out[N*100 : +G*9]  (fused 3-stage head)
    lat_head<<<GG, 256, 0, stream>>>(gf, (const float*)d_in[32], (const float*)d_in[33],
        (const float*)d_in[34], (const float*)d_in[35], (const float*)d_in[36],
        out + (size_t)NN * 100);
    // frac_pred -> out[N*100+G*9 : ]
    gemmM(stream, s1, wt + O_FC, (const float*)d_in[38], nullptr, s2, NN, 256, 128, 2);
    gemm(stream, s2, (const float*)d_in[39], (const float*)d_in[40], nullptr, s3, NN, 128, 64, 2);
    gemm(stream, s3, (const float*)d_in[41], nullptr, nullptr, out + (size_t)NN * 100 + GG * 9, NN, 64, 3, 0);
}

// Round 10
// 749.503 us; speedup vs baseline: 1.3163x; 1.0195x over previous
//
#include <hip/hip_runtime.h>
#include <hip/hip_bf16.h>
#include <math.h>

#define GG 256
#define NP 24
#define LL 3
#define CC 256
#define NN (GG*NP)   // 6144 nodes
#define HH 4
#define DH 64

typedef __hip_bfloat16 bf;
typedef __attribute__((ext_vector_type(8))) short bfrag;   // 8 bf16 (4 VGPR)
typedef __attribute__((ext_vector_type(4))) float ffrag;   // 4 fp32 acc

__device__ __forceinline__ short pk(float x) {
    union { bf h; short s; } u; u.h = __float2bfloat16(x); return u.s;
}
__device__ __forceinline__ float b2f_s(short x) {
    union { short s; bf h; } u; u.s = x; return __bfloat162float(u.h);
}

// ---------------------------------------------------------------------------
__global__ void detect_int_k(const unsigned int* __restrict__ at, int* flags) {
    __shared__ int ok;
    if (threadIdx.x == 0) ok = 1;
    __syncthreads();
    if (at[2 * threadIdx.x + 1] != 0u) ok = 0;   // benign race
    __syncthreads();
    if (threadIdx.x == 0) flags[0] = ok;
}

__global__ void signal_k(float* out, int n, float val) {
    int i = blockIdx.x * 256 + threadIdx.x;
    if (i < n) out[i] = val;
}

// ---------------------------------------------------------------------------
// Combined weight prep (9 segments in ONE dispatch): fp32 [L][K][N] ->
// bf16 [L][N][K] at wt+dstOff.
// ---------------------------------------------------------------------------
struct TArgs {
    const float* src[9];
    long dstOff[9];
    int K[9], N[9], L[9];
    int blk0[10];
};
__global__ void transp_all(TArgs a, bf* __restrict__ wt) {
    int bid = blockIdx.x;
    int s = 0;
    while (s < 8 && bid >= a.blk0[s + 1]) ++s;
    long idx = (long)(bid - a.blk0[s]) * 256 + threadIdx.x;
    int KN = a.K[s] * a.N[s];
    long sz = (long)KN * a.L[s];
    if (idx >= sz) return;
    int l = (int)(idx / KN);
    int rem = (int)(idx % KN);
    int k = rem / a.N[s], n = rem % a.N[s];
    wt[a.dstOff[s] + (long)l * KN + (long)n * a.K[s] + k] =
        __float2bfloat16(a.src[s][idx]);
}

// ---------------------------------------------------------------------------
// GINE edge-weight prep: geW fp32 [L][69][256] -> split bf16 W^T
// [L][half][n 0..127][k 0..63] (k<60 real, else 0), hi and lo parts.
// ---------------------------------------------------------------------------
__global__ void prep_gew(const float* __restrict__ geW, short* __restrict__ wh,
                         short* __restrict__ wl) {
    int idx = blockIdx.x * 256 + threadIdx.x;   // 3*2*128*64 = 49152
    if (idx >= 49152) return;
    int k = idx & 63;
    int n = (idx >> 6) & 127;
    int half = (idx >> 13) & 1;
    int l = idx >> 14;
    float v = (k < 60) ? geW[(long)l * 69 * 256 + (long)k * 256 + half * 128 + n] : 0.f;
    short hi = pk(v);
    short lo = pk(v - b2f_s(hi));
    wh[idx] = hi;
    wl[idx] = lo;
}

// ---------------------------------------------------------------------------
// E-table precompute: sin/cos edge features depend only on frac — layer- and
// half-independent. Built once, bit-identically to the original in-kernel
// expression, in MFMA-fragment layout [(g*24+j)*24+i][k 0..63].
// ---------------------------------------------------------------------------
#define ETAB_ELEMS (GG * 24 * 24 * 64)   // 9437184
__global__ void prep_etab(const float* __restrict__ frac, short* __restrict__ eh,
                          short* __restrict__ el) {
    int idx = blockIdx.x * 256 + threadIdx.x;
    if (idx >= ETAB_ELEMS) return;
    int k = idx & 63;
    int rem = idx >> 6;           // (g*24 + j)*24 + i
    int i = rem % 24;
    int rem2 = rem / 24;
    int j = rem2 % 24;
    int g = rem2 / 24;
    float val = 0.f;
    if (k < 60) {
        int r = (k < 30) ? k : k - 30;
        int d = r / 10, f = r % 10;
        float fd = frac[g * 72 + j * 3 + d] - frac[g * 72 + i * 3 + d];
        fd -= floorf(fd);
        float ang = 6.283185307179586f * (float)f * fd;
        val = (k < 30) ? sinf(ang) : cosf(ang);
    }
    short hi = pk(val);
    eh[idx] = hi;
    el[idx] = pk(val - b2f_s(hi));
}

// ---------------------------------------------------------------------------
// A = [type_emb[atom_types] | time_emb]  (N x 512, fp32)
// ---------------------------------------------------------------------------
__global__ void build_A(const float* __restrict__ t, const float* __restrict__ type_emb,
                        const unsigned int* __restrict__ atoms,
                        float* __restrict__ A, const int* __restrict__ flags) {
    int i64 = flags[0];
    int idx = blockIdx.x * 256 + threadIdx.x;
    if (idx >= NN * 512) return;
    int n = idx >> 9;
    int k = idx & 511;
    if (k < 256) {
        int a = i64 ? (int)atoms[2 * n] : (int)atoms[n];
        A[idx] = type_emb[(long)a * CC + k];
    } else {
        int d = k - 256;
        int g = n / NP;
        float tv = t[g];
        int dd = (d < 128) ? d : d - 128;
        float tf = expf(dd * (-9.210340371976184f / 127.0f));
        float ang = tv * tf;
        A[idx] = (d < 128) ? sinf(ang) : cosf(ang);
    }
}

// ---------------------------------------------------------------------------
// MFMA bf16 GEMM — R10 retile 64x64 -> 32x64 (M-split). R9's 64x64 still
// left N=256 gemms at 384 blocks = 1.5/CU (6/32 waves) — latency/sync-bound
// on a near-empty machine. 32x64 doubles the grid: 768 blocks (3/CU) at
// N=256, 2304 for qkv, 384 for N=128 heads. Bit-exact by the R9 argument:
// each output's accumulator receives exactly one MFMA per ascending k0-step
// regardless of partition; epilogue text unchanged and contraction-safe
// (plain add / fmaxf / div+expf — no fusible mul->add chains).
// ---------------------------------------------------------------------------
__global__ __launch_bounds__(256) void gemm_mfma(
        const float* __restrict__ A, const bf* __restrict__ Wt,
        const float* __restrict__ bias, const float* __restrict__ res,
        float* __restrict__ C, int M, int K, int N, int act) {
    __shared__ __align__(16) short As[32 * 40];
    __shared__ __align__(16) short Bs[64 * 40];
    int tid = threadIdx.x;
    int lane = tid & 63, w = tid >> 6;
    int wm = w & 1, wn = w >> 1;
    int m0 = blockIdx.x * 32, n0 = blockIdx.y * 64;
    ffrag acc[2] = {};   // [nt]
    int sa_m = tid >> 3, sa_k = (tid & 7) << 2;   // 32 rows x 4 floats
    int sb_n = tid >> 2, sb_k = (tid & 3) << 3;   // 64 rows x 8 shorts
    int fr_row = lane & 15, fr_k = (lane >> 4) << 3;

    for (int k0 = 0; k0 < K; k0 += 32) {
        const float* Ap = A + (long)(m0 + sa_m) * K + k0 + sa_k;
        float4 a1 = *(const float4*)Ap;
        float4 b1 = *(const float4*)(Wt + (long)(n0 + sb_n) * K + k0 + sb_k);
        __syncthreads();
        short av0 = pk(a1.x), av1 = pk(a1.y), av2 = pk(a1.z), av3 = pk(a1.w);
        short* ap = &As[sa_m * 40 + sa_k];
        ap[0] = av0; ap[1] = av1; ap[2] = av2; ap[3] = av3;
        *(float4*)(&Bs[sb_n * 40 + sb_k]) = b1;
        __syncthreads();
        bfrag af = *(const bfrag*)(&As[(wm * 16 + fr_row) * 40 + fr_k]);
        bfrag bg0 = *(const bfrag*)(&Bs[(wn * 32 + fr_row) * 40 + fr_k]);
        bfrag bg1 = *(const bfrag*)(&Bs[(wn * 32 + 16 + fr_row) * 40 + fr_k]);
        acc[0] = __builtin_amdgcn_mfma_f32_16x16x32_bf16(af, bg0, acc[0], 0, 0, 0);
        acc[1] = __builtin_amdgcn_mfma_f32_16x16x32_bf16(af, bg1, acc[1], 0, 0, 0);
    }

    int mbase = (lane >> 4) << 2;
#pragma unroll
    for (int nt = 0; nt < 2; ++nt) {
        int n = n0 + wn * 32 + nt * 16 + (lane & 15);
        float bv = bias ? bias[n] : 0.f;
#pragma unroll
        for (int r = 0; r < 4; ++r) {
            int m = m0 + wm * 16 + mbase + r;
            float v = acc[nt][r] + bv;
            if (act == 1) v = fmaxf(v, 0.f);
            else if (act == 2) v = v / (1.f + expf(-v));
            if (res) v += res[(long)m * N + n];
            C[(long)m * N + n] = v;
        }
    }
}

// ---------------------------------------------------------------------------
// fp32 tiled GEMM (small/odd-N). Validated R9-R13.
// ---------------------------------------------------------------------------
__global__ __launch_bounds__(256) void gemm_k(
        const float* __restrict__ A, const float* __restrict__ W,
        const float* __restrict__ bias, const float* __restrict__ res,
        float* __restrict__ Cf, int M, int K, int Nc, int act) {
    __shared__ __align__(16) float Asf[32][64];
    __shared__ __align__(16) float Bsf[32][64];
    int tid = threadIdx.x;
    int tx = tid & 15, ty = tid >> 4;
    int m0 = blockIdx.x * 64, n0 = blockIdx.y * 64;
    float acc[4][4] = {{0.f}};
    int am = tid >> 2;
    int ak = (tid & 3) << 3;
    int bk = tid >> 4;
    int bn = (tid & 15) << 2;

    for (int k0 = 0; k0 < K; k0 += 32) {
        const float* Ap = A + (long)(m0 + am) * K + k0 + ak;
        float4 a1 = *(const float4*)Ap;
        float4 a2 = *(const float4*)(Ap + 4);
        float w1[4], w2[4];
#pragma unroll
        for (int u = 0; u < 4; ++u) {
            int n = n0 + bn + u;
            w1[u] = (n < Nc) ? W[(long)(k0 + bk) * Nc + n] : 0.f;
            w2[u] = (n < Nc) ? W[(long)(k0 + bk + 16) * Nc + n] : 0.f;
        }
        __syncthreads();
        Asf[ak + 0][am] = a1.x; Asf[ak + 1][am] = a1.y;
        Asf[ak + 2][am] = a1.z; Asf[ak + 3][am] = a1.w;
        Asf[ak + 4][am] = a2.x; Asf[ak + 5][am] = a2.y;
        Asf[ak + 6][am] = a2.z; Asf[ak + 7][am] = a2.w;
#pragma unroll
        for (int u = 0; u < 4; ++u) {
            Bsf[bk][bn + u] = w1[u];
            Bsf[bk + 16][bn + u] = w2[u];
        }
        __syncthreads();
#pragma unroll
        for (int k = 0; k < 32; ++k) {
            float4 a = *(const float4*)(&Asf[k][ty << 2]);
            float4 b = *(const float4*)(&Bsf[k][tx << 2]);
            acc[0][0] += a.x * b.x; acc[0][1] += a.x * b.y; acc[0][2] += a.x * b.z; acc[0][3] += a.x * b.w;
            acc[1][0] += a.y * b.x; acc[1][1] += a.y * b.y; acc[1][2] += a.y * b.z; acc[1][3] += a.y * b.w;
            acc[2][0] += a.z * b.x; acc[2][1] += a.z * b.y; acc[2][2] += a.z * b.z; acc[2][3] += a.z * b.w;
            acc[3][0] += a.w * b.x; acc[3][1] += a.w * b.y; acc[3][2] += a.w * b.z; acc[3][3] += a.w * b.w;
        }
    }
#pragma unroll
    for (int i = 0; i < 4; ++i) {
        int m = m0 + (ty << 2) + i;
#pragma unroll
        for (int j = 0; j < 4; ++j) {
            int n = n0 + (tx << 2) + j;
            if (n >= Nc) continue;
            float v = acc[i][j];
            if (bias) v += bias[n];
            if (act == 1) v = fmaxf(v, 0.f);
            else if (act == 2) v = v / (1.f + expf(-v));
            if (res) v += res[(long)m * Nc + n];
            Cf[(long)m * Nc + n] = v;
        }
    }
}

// ---------------------------------------------------------------------------
// GINE v13 — R1/R4 structure + async DMA double-buffered E staging.
// WIN R6: 957 -> 890 µs. Unchanged since.
// ---------------------------------------------------------------------------
#define MF(a, b, c) c = __builtin_amdgcn_mfma_f32_16x16x32_bf16(a, b, c, 0, 0, 0)

typedef __attribute__((address_space(1))) const void gv_t;
typedef __attribute__((address_space(3))) void lv_t;

// Stage one 24x64-short E-tile pair (eh->lds[0..1535], el->lds[2048..3583])
// as 6 DMA chunks of 512 shorts (64 lanes x 16 B). Wave w: chunks w, w+4.
__device__ __forceinline__ void stage_etile(const short* __restrict__ ej_h,
                                            const short* __restrict__ ej_l,
                                            short* lds_base, int w, int lane) {
    {
        int c = w;   // 0..3
        const short* src = (c < 3) ? (ej_h + c * 512) : (ej_l + (c - 3) * 512);
        int doff = (c < 3) ? c * 512 : 2048 + (c - 3) * 512;
        __builtin_amdgcn_global_load_lds((gv_t*)(src + lane * 8),
                                         (lv_t*)(lds_base + doff), 16, 0, 0);
    }
    if (w < 2) {
        int c = w + 4;   // 4,5 -> el chunks 1,2
        const short* src = ej_l + (c - 3) * 512;
        int doff = 2048 + (c - 3) * 512;
        __builtin_amdgcn_global_load_lds((gv_t*)(src + lane * 8),
                                         (lv_t*)(lds_base + doff), 16, 0, 0);
    }
}

__global__ __launch_bounds__(256, 4) void gine4(
        const float* __restrict__ x,
        const float* __restrict__ lattice, const float* __restrict__ geW,
        const float* __restrict__ geb, const short* __restrict__ gewt_h,
        const short* __restrict__ gewt_l, const short* __restrict__ et_h,
        const short* __restrict__ et_l, float* __restrict__ z, int l) {
    __shared__ __align__(16) float xls[24 * 132];  // 12672 B
    __shared__ float basel[128];                   // 512 B
    __shared__ __align__(16) short ebuf[8192];     // 2 x (eh 32r + el 32r) x 64

    int tid = threadIdx.x;
    int lane = tid & 63, w = tid >> 6, quad = lane >> 4, l16 = lane & 15;
    int g = blockIdx.x >> 2;
    int half = (blockIdx.x >> 1) & 1;
    int jh = blockIdx.x & 1;           // j range jh*12 .. jh*12+11

    // ---- stage x half (float4), base ----
    {
        const float4* xg = (const float4*)x;
        for (int idx = tid; idx < 768; idx += 256) {
            int i = idx >> 5, c4 = idx & 31;
            ((float4*)(xls + i * 132))[c4] =
                xg[((long)(g * NP + i) * CC + half * 128) / 4 + c4];
        }
    }
    if (tid < 128) {
        int cg = half * 128 + tid;
        float bv = geb[(long)l * CC + cg];
#pragma unroll
        for (int q = 0; q < 9; ++q)
            bv += lattice[(long)g * 9 + q] * geW[(long)l * 69 * 256 + (long)(60 + q) * 256 + cg];
        basel[tid] = bv;
    }

    // ---- B fragments direct from global (loop-invariant, named scalars) ----
    bfrag bh00, bh01, bh10, bh11, bl00, bl01, bl10, bl11;
    {
        long base = (long)(l * 2 + half) * 8192;   // shorts: 128 rows x 64
        int nrow0 = w * 32 + l16;                  // nt=0
        int nrow1 = w * 32 + 16 + l16;             // nt=1
        const short* p0h = gewt_h + base + nrow0 * 64 + quad * 8;
        const short* p1h = gewt_h + base + nrow1 * 64 + quad * 8;
        const short* p0l = gewt_l + base + nrow0 * 64 + quad * 8;
        const short* p1l = gewt_l + base + nrow1 * 64 + quad * 8;
        bh00 = *(const bfrag*)(p0h);      bh01 = *(const bfrag*)(p0h + 32);
        bh10 = *(const bfrag*)(p1h);      bh11 = *(const bfrag*)(p1h + 32);
        bl00 = *(const bfrag*)(p0l);      bl01 = *(const bfrag*)(p0l + 32);
        bl10 = *(const bfrag*)(p1l);      bl11 = *(const bfrag*)(p1l + 32);
    }

    const short* ehg = et_h + (long)g * (24 * 24 * 64);
    const short* elg = et_l + (long)g * (24 * 24 * 64);
    int j0 = jh * 12;

    // prologue: DMA first tile into buf 0
    stage_etile(ehg + (long)j0 * 1536, elg + (long)j0 * 1536, ebuf, w, lane);
    __syncthreads();   // drains DMA + makes xls/basel visible

    float bse0 = basel[w * 32 + l16];
    float bse1 = basel[w * 32 + 16 + l16];

    int cur = 0;
    for (int jc = 0; jc < 12; ++jc) {
        int j = j0 + jc;
        // issue next tile's DMA into the other buffer (hidden under compute)
        if (jc < 11) {
            stage_etile(ehg + (long)(j + 1) * 1536, elg + (long)(j + 1) * 1536,
                        ebuf + (cur ^ 1) * 4096, w, lane);
        }

        const short* eb = ebuf + cur * 4096;
        int r0 = l16 * 64 + quad * 8;          // mt=0 row offset (shorts)
        int r1 = (16 + l16) * 64 + quad * 8;   // mt=1
        bfrag ah00 = *(const bfrag*)(eb + r0);
        bfrag ah01 = *(const bfrag*)(eb + r0 + 32);
        bfrag ah10 = *(const bfrag*)(eb + r1);
        bfrag ah11 = *(const bfrag*)(eb + r1 + 32);
        bfrag al00 = *(const bfrag*)(eb + 2048 + r0);
        bfrag al01 = *(const bfrag*)(eb + 2048 + r0 + 32);
        bfrag al10 = *(const bfrag*)(eb + 2048 + r1);
        bfrag al11 = *(const bfrag*)(eb + 2048 + r1 + 32);

        ffrag a00 = {}, a01 = {}, a10 = {}, a11 = {};   // acc[mt][nt]
        // mt=0, ks=0
        MF(ah00, bh00, a00); MF(ah00, bl00, a00); MF(al00, bh00, a00);
        MF(ah00, bh10, a01); MF(ah00, bl10, a01); MF(al00, bh10, a01);
        // mt=0, ks=1
        MF(ah01, bh01, a00); MF(ah01, bl01, a00); MF(al01, bh01, a00);
        MF(ah01, bh11, a01); MF(ah01, bl11, a01); MF(al01, bh11, a01);
        // mt=1, ks=0
        MF(ah10, bh00, a10); MF(ah10, bl00, a10); MF(al10, bh00, a10);
        MF(ah10, bh10, a11); MF(ah10, bl10, a11); MF(al10, bh10, a11);
        // mt=1, ks=1
        MF(ah11, bh01, a10); MF(ah11, bl01, a10); MF(al11, bh01, a10);
        MF(ah11, bh11, a11); MF(ah11, bl11, a11); MF(al11, bh11, a11);

        // epilogue: relu + reduce over i, write z[g*24+j][cg]
#pragma unroll
        for (int nt = 0; nt < 2; ++nt) {
            int cl = w * 32 + nt * 16 + l16;
            float bse = nt ? bse1 : bse0;
            ffrag am0 = nt ? a01 : a00;   // mt=0 acc (ibase = quad*4, < 24)
            ffrag am1 = nt ? a11 : a10;   // mt=1 acc (valid only quad<2)
            float part = 0.f;
            {
                int ibase = quad * 4;
#pragma unroll
                for (int r = 0; r < 4; ++r) {
                    float xv = xls[(ibase + r) * 132 + cl];
                    part += fmaxf(xv + bse + am0[r], 0.f);
                }
            }
            if (quad < 2) {
                int ibase = 16 + quad * 4;
#pragma unroll
                for (int r = 0; r < 4; ++r) {
                    float xv = xls[(ibase + r) * 132 + cl];
                    part += fmaxf(xv + bse + am1[r], 0.f);
                }
            }
            part += __shfl_xor(part, 16);
            part += __shfl_xor(part, 32);
            if (lane < 16)
                z[(long)(g * NP + j) * CC + half * 128 + cl] = xls[j * 132 + cl] + part;
        }
        __syncthreads();
        cur ^= 1;
    }
}

// ---------------------------------------------------------------------------
// BN: R7-exact structure (contraction-sensitive expressions pinned to their
// original kernels — R8's relocation attempt shifted absmax one quantum).
// ---------------------------------------------------------------------------
__global__ void bn_stats1(const float* __restrict__ in, float* __restrict__ part) {
    int c = threadIdx.x, b = blockIdx.x;
    float s = 0.f, q = 0.f;
    for (int r = 0; r < 64; ++r) {
        float v = in[(long)(b * 64 + r) * CC + c];
        s += v; q += v * v;
    }
    part[b * 512 + c] = s;
    part[b * 512 + 256 + c] = q;
}
__global__ __launch_bounds__(256) void bn_apply2(
        const float* __restrict__ in, const float* __restrict__ part,
        const float* __restrict__ gma, const float* __restrict__ bta,
        const float* __restrict__ add, float* __restrict__ out) {
    int c = threadIdx.x;
    float s = 0.f, q = 0.f;
    for (int b = 0; b < 96; ++b) { s += part[b * 512 + c]; q += part[b * 512 + 256 + c]; }
    float m = s / (float)NN;
    float var = q / (float)NN - m * m;
    float stats_c = m;
    float stats_rs = rsqrtf(var + 1e-5f);
    float gc = gma[c], bc = bta[c];
    for (int r = blockIdx.x; r < NN; r += 768) {
        long idx = (long)r * CC + c;
        float v = (in[idx] - stats_c) * stats_rs * gc + bc;
        if (add) v += add[idx];
        out[idx] = v;
    }
}

// ---------------------------------------------------------------------------
// Attention v2 (validated R10).
// ---------------------------------------------------------------------------
__global__ __launch_bounds__(256, 2) void attn2(const float* __restrict__ qkv,
                                                float* __restrict__ o) {
    __shared__ __align__(16) float Kl[24 * 4 * 68];
    __shared__ __align__(16) float Vl[24 * 4 * 68];
    __shared__ float S[4 * 24 * 25];
    int tid = threadIdx.x, g = blockIdx.x;

    const float4* qkv4 = (const float4*)(qkv + (long)g * NP * 768);
    for (int idx = tid; idx < 24 * 128; idx += 256) {
        int row = idx >> 7;
        int c4 = idx & 127;
        int isV = c4 >> 6;
        int cc = c4 & 63;
        int h = cc >> 4, d4 = cc & 15;
        float4 val = qkv4[row * 192 + 64 + c4];
        float* dst = (isV ? Vl : Kl) + (row * 4 + h) * 68 + d4 * 4;
        *(float4*)dst = val;
    }
    __syncthreads();

    if (tid < 96) {
        int h = tid & 3, i = tid >> 2;
        const float4* qp = (const float4*)(qkv + ((long)(g * NP + i)) * 768 + h * 64);
        float4 q[16];
#pragma unroll
        for (int k = 0; k < 16; ++k) q[k] = qp[k];
        float sc[24];
        float mx = -1e30f;
        for (int j = 0; j < 24; ++j) {
            const float4* kp = (const float4*)(Kl + (j * 4 + h) * 68);
            float da = 0.f, db = 0.f;
#pragma unroll
            for (int k = 0; k < 16; k += 2) {
                float4 kv = kp[k];
                da += q[k].x * kv.x; da += q[k].y * kv.y;
                da += q[k].z * kv.z; da += q[k].w * kv.w;
                float4 kv2 = kp[k + 1];
                db += q[k + 1].x * kv2.x; db += q[k + 1].y * kv2.y;
                db += q[k + 1].z * kv2.z; db += q[k + 1].w * kv2.w;
            }
            float s = (da + db) * 0.125f;
            sc[j] = s;
            mx = fmaxf(mx, s);
        }
        float sum = 0.f;
#pragma unroll
        for (int j = 0; j < 24; ++j) { float p = expf(sc[j] - mx); sc[j] = p; sum += p; }
        float inv = 1.f / sum;
#pragma unroll
        for (int j = 0; j < 24; ++j) S[(h * 24 + i) * 25 + j] = sc[j] * inv;
    }
    __syncthreads();

    int h = tid >> 6, d = tid & 63;
    for (int i = 0; i < 24; ++i) {
        const float* Sp = S + (h * 24 + i) * 25;
        float a0 = 0.f, a1 = 0.f;
#pragma unroll
        for (int j = 0; j < 24; j += 2) {
            a0 += Sp[j] * Vl[(j * 4 + h) * 68 + d];
            a1 += Sp[j + 1] * Vl[((j + 1) * 4 + h) * 68 + d];
        }
        o[(long)(g * NP + i) * CC + h * 64 + d] = a0 + a1;
    }
}

// ---------------------------------------------------------------------------
__global__ __launch_bounds__(256) void ln_kernel(const float* __restrict__ x,
        const float* __restrict__ gma, const float* __restrict__ bta,
        float* __restrict__ out) {
    __shared__ float red[256];
    int n = blockIdx.x, c = threadIdx.x;
    float v = x[(long)n * CC + c];
    red[c] = v;
    __syncthreads();
    for (int s = 128; s > 0; s >>= 1) { if (c < s) red[c] += red[c + s]; __syncthreads(); }
    float m = red[0] * (1.f / 256.f);
    __syncthreads();
    float dv = v - m;
    red[c] = dv * dv;
    __syncthreads();
    for (int s = 128; s > 0; s >>= 1) { if (c < s) red[c] += red[c + s]; __syncthreads(); }
    float var = red[0] * (1.f / 256.f);
    out[(long)n * CC + c] = dv * rsqrtf(var + 1e-5f) * gma[c] + bta[c];
}

__global__ void pool_kernel(const float* __restrict__ hn, float* __restrict__ gf) {
    int g = blockIdx.x, c = threadIdx.x;
    float s = 0.f;
    for (int j = 0; j < NP; ++j) s += hn[(long)(g * NP + j) * CC + c];
    gf[g * CC + c] = s * (1.f / 24.f);
}

// ---------------------------------------------------------------------------
// Fused lattice head (R7, validated): silu(silu(gf@W1+b1)@W2+b2)@W3, one
// dispatch, bitwise ascending-k accumulation.
// ---------------------------------------------------------------------------
__global__ __launch_bounds__(256) void lat_head(
        const float* __restrict__ gf, const float* __restrict__ W1,
        const float* __restrict__ b1, const float* __restrict__ W2,
        const float* __restrict__ b2, const float* __restrict__ W3,
        float* __restrict__ out) {
    __shared__ float gfl[256];
    __shared__ float h1[128];
    __shared__ float h2[64];
    int g = blockIdx.x, t = threadIdx.x;
    gfl[t] = gf[(long)g * 256 + t];
    __syncthreads();
    if (t < 128) {
        float acc = 0.f;
        for (int k = 0; k < 256; ++k) acc += gfl[k] * W1[k * 128 + t];
        float v = acc;
        v += b1[t];
        v = v / (1.f + expf(-v));
        h1[t] = v;
    }
    __syncthreads();
    if (t < 64) {
        float acc = 0.f;
        for (int k = 0; k < 128; ++k) acc += h1[k] * W2[k * 64 + t];
        float v = acc;
        v += b2[t];
        v = v / (1.f + expf(-v));
        h2[t] = v;
    }
    __syncthreads();
    if (t < 9) {
        float acc = 0.f;
        for (int k = 0; k < 64; ++k) acc += h2[k] * W3[k * 9 + t];
        out[(long)g * 9 + t] = acc;
    }
}

// ---------------------------------------------------------------------------
static void gemm(hipStream_t st, const float* A, const float* W, const float* bias,
                 const float* res, float* Cf, int M, int K, int Nc, int act) {
    dim3 grid(M / 64, (Nc + 63) / 64);
    gemm_k<<<grid, 256, 0, st>>>(A, W, bias, res, Cf, M, K, Nc, act);
}

static void gemmM(hipStream_t st, const float* A, const bf* Wt, const float* bias,
                  const float* res, float* Cf, int M, int K, int N, int act) {
    dim3 grid(M / 32, N / 64);
    gemm_mfma<<<grid, 256, 0, st>>>(A, Wt, bias, res, Cf, M, K, N, act);
}

static void run_bn(hipStream_t st, const float* in, float* part, float* stats,
                   const float* g_, const float* b_, const float* add, float* out) {
    (void)stats;
    bn_stats1<<<96, 256, 0, st>>>(in, part);
    bn_apply2<<<768, 256, 0, st>>>(in, part, g_, b_, add, out);
}

extern "C" void kernel_launch(void* const* d_in, const int* in_sizes, int n_in,
                              void* d_out, int out_size, void* d_ws, size_t ws_size,
                              hipStream_t stream) {
    float* out = (float*)d_out;
    int sigN = out_size < 256 ? out_size : 256;

    static const int EXP_SIZES[46] = {
        256, 18432, 2304, 25600, 131072, 256, 52992, 768, 196608, 768,
        196608, 768, 589824, 2304, 196608, 768, 393216, 1536, 393216, 768,
        768, 768, 768, 768, 768, 768, 256, 256, 32768, 128,
        12800, 100, 32768, 128, 8192, 64, 576, 32768, 128, 8192,
        64, 192, 6144, 6144, 147456, 147456 };
    if (n_in != 46) { signal_k<<<1, 256, 0, stream>>>(out, sigN, 3000.f + 8.f * n_in); return; }
    for (int i = 0; i < 46; ++i)
        if (in_sizes[i] != EXP_SIZES[i]) { signal_k<<<1, 256, 0, stream>>>(out, sigN, 512.f + 8.f * i); return; }
    if (out_size != NN * 100 + GG * 9 + NN * 3) { signal_k<<<1, 256, 0, stream>>>(out, sigN, 7777.f); return; }

    // ---- workspace (R7-exact layout) ----
    char* base = (char*)d_ws;
    int* flags = (int*)base;                       // 256 B
    float* f32a = (float*)(base + 256);
    float* x  = f32a;                              // N*256
    float* s1 = x  + (size_t)NN * 256;             // N*256
    float* s2 = s1 + (size_t)NN * 256;             // N*256
    float* big = s2 + (size_t)NN * 256;            // N*768
    float* s3 = big + (size_t)NN * 512;            // alias of big's tail (lifetimes audited)
    float* part = big + (size_t)NN * 768;          // 96*512
    float* stats = part + 96 * 512;                // 512 (unused)
    float* gf  = stats + 512;                      // G*256
    float* l1b = gf + GG * 256;                    // G*128 (unused since lat_head)
    float* l2b = l1b + GG * 128;                   // G*64  (unused since lat_head)
    bf* wt = (bf*)(l2b + GG * 64);                 // bf16 W^T mirrors
    const long O_NA = 0, O_G1 = 131072, O_G2 = 327680, O_AI = 524288,
               O_AO = 1114112, O_M1 = 1310720, O_M2 = 1703936,
               O_TRO = 2097152, O_FC = 2129920, WT_TOT = 2162688;
    short* gewt_h = (short*)(wt + WT_TOT);         // 49152 shorts
    short* gewt_l = gewt_h + 49152;                // 49152 shorts
    // E tables: ETAB_ELEMS shorts each + 1024-short pad.
    short* et_h = gewt_l + 49152;
    short* et_l = et_h + (ETAB_ELEMS + 1024);
    size_t REQ = 256 + ((size_t)NN * 1536 + 96 * 512 + 512 + GG * 448) * 4
               + WT_TOT * 2 + 49152 * 2 * 2
               + ((size_t)ETAB_ELEMS + 1024) * 2 * 2;
    if (ws_size < REQ) { signal_k<<<1, 256, 0, stream>>>(out, sigN, 9999.f); return; }

    const float* t       = (const float*)d_in[0];
    const float* frac    = (const float*)d_in[1];
    const float* lattice = (const float*)d_in[2];
    const float* type_emb = (const float*)d_in[3];

    detect_int_k<<<1, 256, 0, stream>>>((const unsigned int*)d_in[42], flags);

    // combined weight prep (one dispatch for the 9 transposes)
    {
        TArgs ta;
        const int srcIdx[9] = {4, 8, 10, 12, 14, 16, 18, 28, 37};
        const long dof[9]  = {O_NA, O_G1, O_G2, O_AI, O_AO, O_M1, O_M2, O_TRO, O_FC};
        const int Ks[9] = {512, 256, 256, 256, 256, 256, 512, 256, 256};
        const int Ns[9] = {256, 256, 256, 768, 256, 512, 256, 128, 128};
        const int Ls[9] = {1, 3, 3, 3, 3, 3, 3, 1, 1};
        int blk = 0;
        for (int s = 0; s < 9; ++s) {
            ta.src[s] = (const float*)d_in[srcIdx[s]];
            ta.dstOff[s] = dof[s];
            ta.K[s] = Ks[s]; ta.N[s] = Ns[s]; ta.L[s] = Ls[s];
            ta.blk0[s] = blk;
            blk += (Ks[s] * Ns[s] * Ls[s] + 255) / 256;
        }
        ta.blk0[9] = blk;
        transp_all<<<blk, 256, 0, stream>>>(ta, wt);
    }
    prep_gew<<<192, 256, 0, stream>>>((const float*)d_in[6], gewt_h, gewt_l);
    prep_etab<<<(ETAB_ELEMS + 255) / 256, 256, 0, stream>>>(frac, et_h, et_l);

    // x0 = concat(type_emb[atoms], time_emb) @ naW + nab
    build_A<<<(NN * 512 + 255) / 256, 256, 0, stream>>>(t, type_emb,
        (const unsigned int*)d_in[42], big, flags);
    gemmM(stream, big, wt + O_NA, (const float*)d_in[5], nullptr, x, NN, 512, 256, 0);

    for (int l = 0; l < LL; ++l) {
        // GINE: s1 = x + aggr
        gine4<<<GG * 4, 256, 0, stream>>>(x, lattice,
            (const float*)d_in[6], (const float*)d_in[7], gewt_h, gewt_l,
            et_h, et_l, s1, l);
        // s2 = silu(s1@gW1+gb1); s3 = s2@gW2+gb2 + x; h1 = BN(s3) -> s2
        gemmM(stream, s1, wt + O_G1 + (long)l * 65536, (const float*)d_in[9]  + l * 256, nullptr, s2, NN, 256, 256, 2);
        gemmM(stream, s2, wt + O_G2 + (long)l * 65536, (const float*)d_in[11] + l * 256, x, s3, NN, 256, 256, 0);
        run_bn(stream, s3, part, stats, (const float*)d_in[20] + l * 256, (const float*)d_in[21] + l * 256, nullptr, s2);
        // attention: qkv=big; o=s1; s3 = s1@aoW+aob + x; s1 = h1 + BN(s3)
        gemmM(stream, x, wt + O_AI + (long)l * 196608, (const float*)d_in[13] + l * 768, nullptr, big, NN, 256, 768, 0);
        attn2<<<GG, 256, 0, stream>>>(big, s1);
        gemmM(stream, s1, wt + O_AO + (long)l * 65536, (const float*)d_in[15] + l * 256, x, s3, NN, 256, 256, 0);
        run_bn(stream, s3, part, stats, (const float*)d_in[22] + l * 256, (const float*)d_in[23] + l * 256, s2, s1);
        // MLP: big = relu(s1@mW1+mb1); s3 = big@mW2+mb2 + s1; x = BN(s3)
        gemmM(stream, s1, wt + O_M1 + (long)l * 131072, (const float*)d_in[17] + l * 512, nullptr, big, NN, 256, 512, 1);
        gemmM(stream, big, wt + O_M2 + (long)l * 131072, (const float*)d_in[19] + l * 256, s1, s3, NN, 512, 256, 0);
        run_bn(stream, s3, part, stats, (const float*)d_in[24] + l * 256, (const float*)d_in[25] + l * 256, nullptr, x);
    }

    ln_kernel<<<NN, 256, 0, stream>>>(x, (const float*)d_in[26], (const float*)d_in[27], s1);
    pool_kernel<<<GG, 256, 0, stream>>>(s1, gf);

    // types_pred -> out[0 : N*100]
    gemmM(stream, s1, wt + O_TRO, (const float*)d_in[29], nullptr, s2, NN, 256, 128, 2);
    gemm(stream, s2, (const float*)d_in[30], (const float*)d_in[31], nullptr, out, NN, 128, 100, 0);
    // lattice_pred -> out[N*100 : +G*9]  (fused 3-stage head)
    lat_head<<<GG, 256, 0, stream>>>(gf, (const float*)d_in[32], (const float*)d_in[33],
        (const float*)d_in[34], (const float*)d_in[35], (const float*)d_in[36],
        out + (size_t)NN * 100);
    // frac_pred -> out[N*100+G*9 : ]
    gemmM(stream, s1, wt + O_FC, (const float*)d_in[38], nullptr, s2, NN, 256, 128, 2);
    gemm(stream, s2, (const float*)d_in[39], (const float*)d_in[40], nullptr, s3, NN, 128, 64, 2);
    gemm(stream, s3, (const float*)d_in[41], nullptr, nullptr, out + (size_t)NN * 100 + GG * 9, NN, 64, 3, 0);
}

// Round 11
// 712.457 us; speedup vs baseline: 1.3847x; 1.0520x over previous
//
#include <hip/hip_runtime.h>
#include <hip/hip_bf16.h>
#include <math.h>

#define GG 256
#define NP 24
#define LL 3
#define CC 256
#define NN (GG*NP)   // 6144 nodes
#define HH 4
#define DH 64

typedef __hip_bfloat16 bf;
typedef __attribute__((ext_vector_type(8))) short bfrag;   // 8 bf16 (4 VGPR)
typedef __attribute__((ext_vector_type(4))) float ffrag;   // 4 fp32 acc

__device__ __forceinline__ short pk(float x) {
    union { bf h; short s; } u; u.h = __float2bfloat16(x); return u.s;
}
__device__ __forceinline__ float b2f_s(short x) {
    union { short s; bf h; } u; u.s = x; return __bfloat162float(u.h);
}

typedef __attribute__((address_space(1))) const void gv_t;
typedef __attribute__((address_space(3))) void lv_t;

// ---------------------------------------------------------------------------
__global__ void detect_int_k(const unsigned int* __restrict__ at, int* flags) {
    __shared__ int ok;
    if (threadIdx.x == 0) ok = 1;
    __syncthreads();
    if (at[2 * threadIdx.x + 1] != 0u) ok = 0;   // benign race
    __syncthreads();
    if (threadIdx.x == 0) flags[0] = ok;
}

__global__ void signal_k(float* out, int n, float val) {
    int i = blockIdx.x * 256 + threadIdx.x;
    if (i < n) out[i] = val;
}

// ---------------------------------------------------------------------------
// Combined weight prep (9 segments in ONE dispatch): fp32 [L][K][N] ->
// bf16 [L][N][K] at wt+dstOff.
// ---------------------------------------------------------------------------
struct TArgs {
    const float* src[9];
    long dstOff[9];
    int K[9], N[9], L[9];
    int blk0[10];
};
__global__ void transp_all(TArgs a, bf* __restrict__ wt) {
    int bid = blockIdx.x;
    int s = 0;
    while (s < 8 && bid >= a.blk0[s + 1]) ++s;
    long idx = (long)(bid - a.blk0[s]) * 256 + threadIdx.x;
    int KN = a.K[s] * a.N[s];
    long sz = (long)KN * a.L[s];
    if (idx >= sz) return;
    int l = (int)(idx / KN);
    int rem = (int)(idx % KN);
    int k = rem / a.N[s], n = rem % a.N[s];
    wt[a.dstOff[s] + (long)l * KN + (long)n * a.K[s] + k] =
        __float2bfloat16(a.src[s][idx]);
}

// ---------------------------------------------------------------------------
// prep_gewtab (R11): prep_gew + prep_etab merged via block-range switch.
// Both bodies VERBATIM (R1 already proved the sinf/cosf expression relocates
// between kernels bit-exactly). Blocks 0..191: gew; 192..: etab.
// ---------------------------------------------------------------------------
#define ETAB_ELEMS (GG * 24 * 24 * 64)   // 9437184
__global__ void prep_gewtab(const float* __restrict__ geW, short* __restrict__ wh,
                            short* __restrict__ wl, const float* __restrict__ frac,
                            short* __restrict__ eh, short* __restrict__ el) {
    int bid = blockIdx.x;
    if (bid < 192) {
        int idx = bid * 256 + threadIdx.x;   // 3*2*128*64 = 49152
        if (idx >= 49152) return;
        int k = idx & 63;
        int n = (idx >> 6) & 127;
        int half = (idx >> 13) & 1;
        int l = idx >> 14;
        float v = (k < 60) ? geW[(long)l * 69 * 256 + (long)k * 256 + half * 128 + n] : 0.f;
        short hi = pk(v);
        short lo = pk(v - b2f_s(hi));
        wh[idx] = hi;
        wl[idx] = lo;
    } else {
        int idx = (bid - 192) * 256 + threadIdx.x;
        if (idx >= ETAB_ELEMS) return;
        int k = idx & 63;
        int rem = idx >> 6;           // (g*24 + j)*24 + i
        int i = rem % 24;
        int rem2 = rem / 24;
        int j = rem2 % 24;
        int g = rem2 / 24;
        float val = 0.f;
        if (k < 60) {
            int r = (k < 30) ? k : k - 30;
            int d = r / 10, f = r % 10;
            float fd = frac[g * 72 + j * 3 + d] - frac[g * 72 + i * 3 + d];
            fd -= floorf(fd);
            float ang = 6.283185307179586f * (float)f * fd;
            val = (k < 30) ? sinf(ang) : cosf(ang);
        }
        short hi = pk(val);
        eh[idx] = hi;
        el[idx] = pk(val - b2f_s(hi));
    }
}

// ---------------------------------------------------------------------------
// A = [type_emb[atom_types] | time_emb]  (N x 512, fp32)
// ---------------------------------------------------------------------------
__global__ void build_A(const float* __restrict__ t, const float* __restrict__ type_emb,
                        const unsigned int* __restrict__ atoms,
                        float* __restrict__ A, const int* __restrict__ flags) {
    int i64 = flags[0];
    int idx = blockIdx.x * 256 + threadIdx.x;
    if (idx >= NN * 512) return;
    int n = idx >> 9;
    int k = idx & 511;
    if (k < 256) {
        int a = i64 ? (int)atoms[2 * n] : (int)atoms[n];
        A[idx] = type_emb[(long)a * CC + k];
    } else {
        int d = k - 256;
        int g = n / NP;
        float tv = t[g];
        int dd = (d < 128) ? d : d - 128;
        float tf = expf(dd * (-9.210340371976184f / 127.0f));
        float ang = tv * tf;
        A[idx] = (d < 128) ? sinf(ang) : cosf(ang);
    }
}

// ---------------------------------------------------------------------------
// MFMA bf16 GEMM — R11: gine4's proven DMA double-buffer applied here.
// K_STEP=64 (two 32-substeps, ascending): B half-tiles staged by
// global_load_lds (B is bf16 in memory — DMA-able; 64x32 contiguous chunks),
// A staged regs->pk->LDS; both 1 step ahead so the end-of-iter barrier drains
// a DMA that overlapped the MFMAs + As-write. Bit-exact by construction:
// identical bytes enter identical MFMAs in identical per-output ascending-k
// order; epilogue text unchanged (bias2 = concat-select load only, for the
// merged TRO|FC head gemm whose weight mirrors are adjacent).
// ---------------------------------------------------------------------------
__global__ __launch_bounds__(256) void gemm_mfma(
        const float* __restrict__ A, const bf* __restrict__ Wt,
        const float* __restrict__ bias, const float* __restrict__ bias2,
        const float* __restrict__ res,
        float* __restrict__ C, int M, int K, int N, int act) {
    __shared__ __align__(16) short As[2][32 * 72];      // 9.2 KB
    __shared__ __align__(16) short Bs[2][2][64 * 32];   // 16 KB
    int tid = threadIdx.x;
    int lane = tid & 63, w = tid >> 6;
    int wm = w & 1, wn = w >> 1;
    int m0 = blockIdx.x * 32, n0 = blockIdx.y * 64;
    ffrag acc[2] = {};   // [nt]
    int sa_m = tid >> 3, sa_k = (tid & 7) << 3;   // 32 rows x 8 floats
    int fr_row = lane & 15, quad = lane >> 4, fr_k = quad << 3;
    int brow = w * 16 + (lane >> 2);              // 4 waves x 16 rows
    int bko = (lane & 3) << 3;                    // 4 lanes x 8 shorts per row
    const short* wsrc = (const short*)Wt + (long)(n0 + brow) * K + bko;

    // prologue: stage tile 0
    {
        const float* Ap = A + (long)(m0 + sa_m) * K + sa_k;
        float4 a1 = *(const float4*)Ap;
        float4 a2 = *(const float4*)(Ap + 4);
        __builtin_amdgcn_global_load_lds((gv_t*)(wsrc), (lv_t*)(&Bs[0][0][w * 512]), 16, 0, 0);
        __builtin_amdgcn_global_load_lds((gv_t*)(wsrc + 32), (lv_t*)(&Bs[0][1][w * 512]), 16, 0, 0);
        short* ap = &As[0][sa_m * 72 + sa_k];
        ap[0] = pk(a1.x); ap[1] = pk(a1.y); ap[2] = pk(a1.z); ap[3] = pk(a1.w);
        ap[4] = pk(a2.x); ap[5] = pk(a2.y); ap[6] = pk(a2.z); ap[7] = pk(a2.w);
    }
    __syncthreads();   // As[0] visible, B(0) DMA drained

    int nk = K >> 6;
    int cur = 0;
    for (int i = 0; i < nk; ++i) {
        float4 a1n, a2n;
        bool more = (i + 1) < nk;
        if (more) {
            int kn = (i + 1) << 6;
            __builtin_amdgcn_global_load_lds((gv_t*)(wsrc + kn),
                (lv_t*)(&Bs[cur ^ 1][0][w * 512]), 16, 0, 0);
            __builtin_amdgcn_global_load_lds((gv_t*)(wsrc + kn + 32),
                (lv_t*)(&Bs[cur ^ 1][1][w * 512]), 16, 0, 0);
            const float* Ap = A + (long)(m0 + sa_m) * K + kn + sa_k;
            a1n = *(const float4*)Ap;
            a2n = *(const float4*)(Ap + 4);
        }
        bfrag af0  = *(const bfrag*)(&As[cur][(wm * 16 + fr_row) * 72 + fr_k]);
        bfrag af1  = *(const bfrag*)(&As[cur][(wm * 16 + fr_row) * 72 + 32 + fr_k]);
        bfrag bg00 = *(const bfrag*)(&Bs[cur][0][(wn * 32 + fr_row) * 32 + fr_k]);
        bfrag bg01 = *(const bfrag*)(&Bs[cur][0][(wn * 32 + 16 + fr_row) * 32 + fr_k]);
        bfrag bg10 = *(const bfrag*)(&Bs[cur][1][(wn * 32 + fr_row) * 32 + fr_k]);
        bfrag bg11 = *(const bfrag*)(&Bs[cur][1][(wn * 32 + 16 + fr_row) * 32 + fr_k]);
        acc[0] = __builtin_amdgcn_mfma_f32_16x16x32_bf16(af0, bg00, acc[0], 0, 0, 0);
        acc[1] = __builtin_amdgcn_mfma_f32_16x16x32_bf16(af0, bg01, acc[1], 0, 0, 0);
        acc[0] = __builtin_amdgcn_mfma_f32_16x16x32_bf16(af1, bg10, acc[0], 0, 0, 0);
        acc[1] = __builtin_amdgcn_mfma_f32_16x16x32_bf16(af1, bg11, acc[1], 0, 0, 0);
        if (more) {
            short* ap = &As[cur ^ 1][sa_m * 72 + sa_k];
            ap[0] = pk(a1n.x); ap[1] = pk(a1n.y); ap[2] = pk(a1n.z); ap[3] = pk(a1n.w);
            ap[4] = pk(a2n.x); ap[5] = pk(a2n.y); ap[6] = pk(a2n.z); ap[7] = pk(a2n.w);
        }
        __syncthreads();   // buffers reusable; next DMA drained (overlapped MFMA)
        cur ^= 1;
    }

    int mbase = (lane >> 4) << 2;
#pragma unroll
    for (int nt = 0; nt < 2; ++nt) {
        int n = n0 + wn * 32 + nt * 16 + (lane & 15);
        float bv = bias ? ((bias2 && n >= 128) ? bias2[n - 128] : bias[n]) : 0.f;
#pragma unroll
        for (int r = 0; r < 4; ++r) {
            int m = m0 + wm * 16 + mbase + r;
            float v = acc[nt][r] + bv;
            if (act == 1) v = fmaxf(v, 0.f);
            else if (act == 2) v = v / (1.f + expf(-v));
            if (res) v += res[(long)m * N + n];
            C[(long)m * N + n] = v;
        }
    }
}

// ---------------------------------------------------------------------------
// fp32 tiled GEMM (small/odd-N). R11: +lda param (address-only change; all
// old calls pass lda=K; head tails read the combined TRO|FC buffer).
// ---------------------------------------------------------------------------
__global__ __launch_bounds__(256) void gemm_k(
        const float* __restrict__ A, int lda, const float* __restrict__ W,
        const float* __restrict__ bias, const float* __restrict__ res,
        float* __restrict__ Cf, int M, int K, int Nc, int act) {
    __shared__ __align__(16) float Asf[32][64];
    __shared__ __align__(16) float Bsf[32][64];
    int tid = threadIdx.x;
    int tx = tid & 15, ty = tid >> 4;
    int m0 = blockIdx.x * 64, n0 = blockIdx.y * 64;
    float acc[4][4] = {{0.f}};
    int am = tid >> 2;
    int ak = (tid & 3) << 3;
    int bk = tid >> 4;
    int bn = (tid & 15) << 2;

    for (int k0 = 0; k0 < K; k0 += 32) {
        const float* Ap = A + (long)(m0 + am) * lda + k0 + ak;
        float4 a1 = *(const float4*)Ap;
        float4 a2 = *(const float4*)(Ap + 4);
        float w1[4], w2[4];
#pragma unroll
        for (int u = 0; u < 4; ++u) {
            int n = n0 + bn + u;
            w1[u] = (n < Nc) ? W[(long)(k0 + bk) * Nc + n] : 0.f;
            w2[u] = (n < Nc) ? W[(long)(k0 + bk + 16) * Nc + n] : 0.f;
        }
        __syncthreads();
        Asf[ak + 0][am] = a1.x; Asf[ak + 1][am] = a1.y;
        Asf[ak + 2][am] = a1.z; Asf[ak + 3][am] = a1.w;
        Asf[ak + 4][am] = a2.x; Asf[ak + 5][am] = a2.y;
        Asf[ak + 6][am] = a2.z; Asf[ak + 7][am] = a2.w;
#pragma unroll
        for (int u = 0; u < 4; ++u) {
            Bsf[bk][bn + u] = w1[u];
            Bsf[bk + 16][bn + u] = w2[u];
        }
        __syncthreads();
#pragma unroll
        for (int k = 0; k < 32; ++k) {
            float4 a = *(const float4*)(&Asf[k][ty << 2]);
            float4 b = *(const float4*)(&Bsf[k][tx << 2]);
            acc[0][0] += a.x * b.x; acc[0][1] += a.x * b.y; acc[0][2] += a.x * b.z; acc[0][3] += a.x * b.w;
            acc[1][0] += a.y * b.x; acc[1][1] += a.y * b.y; acc[1][2] += a.y * b.z; acc[1][3] += a.y * b.w;
            acc[2][0] += a.z * b.x; acc[2][1] += a.z * b.y; acc[2][2] += a.z * b.z; acc[2][3] += a.z * b.w;
            acc[3][0] += a.w * b.x; acc[3][1] += a.w * b.y; acc[3][2] += a.w * b.z; acc[3][3] += a.w * b.w;
        }
    }
#pragma unroll
    for (int i = 0; i < 4; ++i) {
        int m = m0 + (ty << 2) + i;
#pragma unroll
        for (int j = 0; j < 4; ++j) {
            int n = n0 + (tx << 2) + j;
            if (n >= Nc) continue;
            float v = acc[i][j];
            if (bias) v += bias[n];
            if (act == 1) v = fmaxf(v, 0.f);
            else if (act == 2) v = v / (1.f + expf(-v));
            if (res) v += res[(long)m * Nc + n];
            Cf[(long)m * Nc + n] = v;
        }
    }
}

// ---------------------------------------------------------------------------
// GINE v13 — R1/R4 structure + async DMA double-buffered E staging.
// WIN R6: 957 -> 890 µs. Unchanged since.
// ---------------------------------------------------------------------------
#define MF(a, b, c) c = __builtin_amdgcn_mfma_f32_16x16x32_bf16(a, b, c, 0, 0, 0)

// Stage one 24x64-short E-tile pair (eh->lds[0..1535], el->lds[2048..3583])
// as 6 DMA chunks of 512 shorts (64 lanes x 16 B). Wave w: chunks w, w+4.
__device__ __forceinline__ void stage_etile(const short* __restrict__ ej_h,
                                            const short* __restrict__ ej_l,
                                            short* lds_base, int w, int lane) {
    {
        int c = w;   // 0..3
        const short* src = (c < 3) ? (ej_h + c * 512) : (ej_l + (c - 3) * 512);
        int doff = (c < 3) ? c * 512 : 2048 + (c - 3) * 512;
        __builtin_amdgcn_global_load_lds((gv_t*)(src + lane * 8),
                                         (lv_t*)(lds_base + doff), 16, 0, 0);
    }
    if (w < 2) {
        int c = w + 4;   // 4,5 -> el chunks 1,2
        const short* src = ej_l + (c - 3) * 512;
        int doff = 2048 + (c - 3) * 512;
        __builtin_amdgcn_global_load_lds((gv_t*)(src + lane * 8),
                                         (lv_t*)(lds_base + doff), 16, 0, 0);
    }
}

__global__ __launch_bounds__(256, 4) void gine4(
        const float* __restrict__ x,
        const float* __restrict__ lattice, const float* __restrict__ geW,
        const float* __restrict__ geb, const short* __restrict__ gewt_h,
        const short* __restrict__ gewt_l, const short* __restrict__ et_h,
        const short* __restrict__ et_l, float* __restrict__ z, int l) {
    __shared__ __align__(16) float xls[24 * 132];  // 12672 B
    __shared__ float basel[128];                   // 512 B
    __shared__ __align__(16) short ebuf[8192];     // 2 x (eh 32r + el 32r) x 64

    int tid = threadIdx.x;
    int lane = tid & 63, w = tid >> 6, quad = lane >> 4, l16 = lane & 15;
    int g = blockIdx.x >> 2;
    int half = (blockIdx.x >> 1) & 1;
    int jh = blockIdx.x & 1;           // j range jh*12 .. jh*12+11

    // ---- stage x half (float4), base ----
    {
        const float4* xg = (const float4*)x;
        for (int idx = tid; idx < 768; idx += 256) {
            int i = idx >> 5, c4 = idx & 31;
            ((float4*)(xls + i * 132))[c4] =
                xg[((long)(g * NP + i) * CC + half * 128) / 4 + c4];
        }
    }
    if (tid < 128) {
        int cg = half * 128 + tid;
        float bv = geb[(long)l * CC + cg];
#pragma unroll
        for (int q = 0; q < 9; ++q)
            bv += lattice[(long)g * 9 + q] * geW[(long)l * 69 * 256 + (long)(60 + q) * 256 + cg];
        basel[tid] = bv;
    }

    // ---- B fragments direct from global (loop-invariant, named scalars) ----
    bfrag bh00, bh01, bh10, bh11, bl00, bl01, bl10, bl11;
    {
        long base = (long)(l * 2 + half) * 8192;   // shorts: 128 rows x 64
        int nrow0 = w * 32 + l16;                  // nt=0
        int nrow1 = w * 32 + 16 + l16;             // nt=1
        const short* p0h = gewt_h + base + nrow0 * 64 + quad * 8;
        const short* p1h = gewt_h + base + nrow1 * 64 + quad * 8;
        const short* p0l = gewt_l + base + nrow0 * 64 + quad * 8;
        const short* p1l = gewt_l + base + nrow1 * 64 + quad * 8;
        bh00 = *(const bfrag*)(p0h);      bh01 = *(const bfrag*)(p0h + 32);
        bh10 = *(const bfrag*)(p1h);      bh11 = *(const bfrag*)(p1h + 32);
        bl00 = *(const bfrag*)(p0l);      bl01 = *(const bfrag*)(p0l + 32);
        bl10 = *(const bfrag*)(p1l);      bl11 = *(const bfrag*)(p1l + 32);
    }

    const short* ehg = et_h + (long)g * (24 * 24 * 64);
    const short* elg = et_l + (long)g * (24 * 24 * 64);
    int j0 = jh * 12;

    // prologue: DMA first tile into buf 0
    stage_etile(ehg + (long)j0 * 1536, elg + (long)j0 * 1536, ebuf, w, lane);
    __syncthreads();   // drains DMA + makes xls/basel visible

    float bse0 = basel[w * 32 + l16];
    float bse1 = basel[w * 32 + 16 + l16];

    int cur = 0;
    for (int jc = 0; jc < 12; ++jc) {
        int j = j0 + jc;
        // issue next tile's DMA into the other buffer (hidden under compute)
        if (jc < 11) {
            stage_etile(ehg + (long)(j + 1) * 1536, elg + (long)(j + 1) * 1536,
                        ebuf + (cur ^ 1) * 4096, w, lane);
        }

        const short* eb = ebuf + cur * 4096;
        int r0 = l16 * 64 + quad * 8;          // mt=0 row offset (shorts)
        int r1 = (16 + l16) * 64 + quad * 8;   // mt=1
        bfrag ah00 = *(const bfrag*)(eb + r0);
        bfrag ah01 = *(const bfrag*)(eb + r0 + 32);
        bfrag ah10 = *(const bfrag*)(eb + r1);
        bfrag ah11 = *(const bfrag*)(eb + r1 + 32);
        bfrag al00 = *(const bfrag*)(eb + 2048 + r0);
        bfrag al01 = *(const bfrag*)(eb + 2048 + r0 + 32);
        bfrag al10 = *(const bfrag*)(eb + 2048 + r1);
        bfrag al11 = *(const bfrag*)(eb + 2048 + r1 + 32);

        ffrag a00 = {}, a01 = {}, a10 = {}, a11 = {};   // acc[mt][nt]
        // mt=0, ks=0
        MF(ah00, bh00, a00); MF(ah00, bl00, a00); MF(al00, bh00, a00);
        MF(ah00, bh10, a01); MF(ah00, bl10, a01); MF(al00, bh10, a01);
        // mt=0, ks=1
        MF(ah01, bh01, a00); MF(ah01, bl01, a00); MF(al01, bh01, a00);
        MF(ah01, bh11, a01); MF(ah01, bl11, a01); MF(al01, bh11, a01);
        // mt=1, ks=0
        MF(ah10, bh00, a10); MF(ah10, bl00, a10); MF(al10, bh00, a10);
        MF(ah10, bh10, a11); MF(ah10, bl10, a11); MF(al10, bh10, a11);
        // mt=1, ks=1
        MF(ah11, bh01, a10); MF(ah11, bl01, a10); MF(al11, bh01, a10);
        MF(ah11, bh11, a11); MF(ah11, bl11, a11); MF(al11, bh11, a11);

        // epilogue: relu + reduce over i, write z[g*24+j][cg]
#pragma unroll
        for (int nt = 0; nt < 2; ++nt) {
            int cl = w * 32 + nt * 16 + l16;
            float bse = nt ? bse1 : bse0;
            ffrag am0 = nt ? a01 : a00;   // mt=0 acc (ibase = quad*4, < 24)
            ffrag am1 = nt ? a11 : a10;   // mt=1 acc (valid only quad<2)
            float part = 0.f;
            {
                int ibase = quad * 4;
#pragma unroll
                for (int r = 0; r < 4; ++r) {
                    float xv = xls[(ibase + r) * 132 + cl];
                    part += fmaxf(xv + bse + am0[r], 0.f);
                }
            }
            if (quad < 2) {
                int ibase = 16 + quad * 4;
#pragma unroll
                for (int r = 0; r < 4; ++r) {
                    float xv = xls[(ibase + r) * 132 + cl];
                    part += fmaxf(xv + bse + am1[r], 0.f);
                }
            }
            part += __shfl_xor(part, 16);
            part += __shfl_xor(part, 32);
            if (lane < 16)
                z[(long)(g * NP + j) * CC + half * 128 + cl] = xls[j * 132 + cl] + part;
        }
        __syncthreads();
        cur ^= 1;
    }
}

// ---------------------------------------------------------------------------
// BN: R7-exact structure (contraction-sensitive expressions pinned to their
// original kernels — R8's relocation attempt shifted absmax one quantum).
// ---------------------------------------------------------------------------
__global__ void bn_stats1(const float* __restrict__ in, float* __restrict__ part) {
    int c = threadIdx.x, b = blockIdx.x;
    float s = 0.f, q = 0.f;
    for (int r = 0; r < 64; ++r) {
        float v = in[(long)(b * 64 + r) * CC + c];
        s += v; q += v * v;
    }
    part[b * 512 + c] = s;
    part[b * 512 + 256 + c] = q;
}
__global__ __launch_bounds__(256) void bn_apply2(
        const float* __restrict__ in, const float* __restrict__ part,
        const float* __restrict__ gma, const float* __restrict__ bta,
        const float* __restrict__ add, float* __restrict__ out) {
    int c = threadIdx.x;
    float s = 0.f, q = 0.f;
    for (int b = 0; b < 96; ++b) { s += part[b * 512 + c]; q += part[b * 512 + 256 + c]; }
    float m = s / (float)NN;
    float var = q / (float)NN - m * m;
    float stats_c = m;
    float stats_rs = rsqrtf(var + 1e-5f);
    float gc = gma[c], bc = bta[c];
    for (int r = blockIdx.x; r < NN; r += 768) {
        long idx = (long)r * CC + c;
        float v = (in[idx] - stats_c) * stats_rs * gc + bc;
        if (add) v += add[idx];
        out[idx] = v;
    }
}

// ---------------------------------------------------------------------------
// Attention v2 (validated R10).
// ---------------------------------------------------------------------------
__global__ __launch_bounds__(256, 2) void attn2(const float* __restrict__ qkv,
                                                float* __restrict__ o) {
    __shared__ __align__(16) float Kl[24 * 4 * 68];
    __shared__ __align__(16) float Vl[24 * 4 * 68];
    __shared__ float S[4 * 24 * 25];
    int tid = threadIdx.x, g = blockIdx.x;

    const float4* qkv4 = (const float4*)(qkv + (long)g * NP * 768);
    for (int idx = tid; idx < 24 * 128; idx += 256) {
        int row = idx >> 7;
        int c4 = idx & 127;
        int isV = c4 >> 6;
        int cc = c4 & 63;
        int h = cc >> 4, d4 = cc & 15;
        float4 val = qkv4[row * 192 + 64 + c4];
        float* dst = (isV ? Vl : Kl) + (row * 4 + h) * 68 + d4 * 4;
        *(float4*)dst = val;
    }
    __syncthreads();

    if (tid < 96) {
        int h = tid & 3, i = tid >> 2;
        const float4* qp = (const float4*)(qkv + ((long)(g * NP + i)) * 768 + h * 64);
        float4 q[16];
#pragma unroll
        for (int k = 0; k < 16; ++k) q[k] = qp[k];
        float sc[24];
        float mx = -1e30f;
        for (int j = 0; j < 24; ++j) {
            const float4* kp = (const float4*)(Kl + (j * 4 + h) * 68);
            float da = 0.f, db = 0.f;
#pragma unroll
            for (int k = 0; k < 16; k += 2) {
                float4 kv = kp[k];
                da += q[k].x * kv.x; da += q[k].y * kv.y;
                da += q[k].z * kv.z; da += q[k].w * kv.w;
                float4 kv2 = kp[k + 1];
                db += q[k + 1].x * kv2.x; db += q[k + 1].y * kv2.y;
                db += q[k + 1].z * kv2.z; db += q[k + 1].w * kv2.w;
            }
            float s = (da + db) * 0.125f;
            sc[j] = s;
            mx = fmaxf(mx, s);
        }
        float sum = 0.f;
#pragma unroll
        for (int j = 0; j < 24; ++j) { float p = expf(sc[j] - mx); sc[j] = p; sum += p; }
        float inv = 1.f / sum;
#pragma unroll
        for (int j = 0; j < 24; ++j) S[(h * 24 + i) * 25 + j] = sc[j] * inv;
    }
    __syncthreads();

    int h = tid >> 6, d = tid & 63;
    for (int i = 0; i < 24; ++i) {
        const float* Sp = S + (h * 24 + i) * 25;
        float a0 = 0.f, a1 = 0.f;
#pragma unroll
        for (int j = 0; j < 24; j += 2) {
            a0 += Sp[j] * Vl[(j * 4 + h) * 68 + d];
            a1 += Sp[j + 1] * Vl[((j + 1) * 4 + h) * 68 + d];
        }
        o[(long)(g * NP + i) * CC + h * 64 + d] = a0 + a1;
    }
}

// ---------------------------------------------------------------------------
__global__ __launch_bounds__(256) void ln_kernel(const float* __restrict__ x,
        const float* __restrict__ gma, const float* __restrict__ bta,
        float* __restrict__ out) {
    __shared__ float red[256];
    int n = blockIdx.x, c = threadIdx.x;
    float v = x[(long)n * CC + c];
    red[c] = v;
    __syncthreads();
    for (int s = 128; s > 0; s >>= 1) { if (c < s) red[c] += red[c + s]; __syncthreads(); }
    float m = red[0] * (1.f / 256.f);
    __syncthreads();
    float dv = v - m;
    red[c] = dv * dv;
    __syncthreads();
    for (int s = 128; s > 0; s >>= 1) { if (c < s) red[c] += red[c + s]; __syncthreads(); }
    float var = red[0] * (1.f / 256.f);
    out[(long)n * CC + c] = dv * rsqrtf(var + 1e-5f) * gma[c] + bta[c];
}

// ---------------------------------------------------------------------------
// Fused lattice head — R11: pool folded in (verbatim ascending-j adds, then
// the same *1/24; gf buffer eliminated). Rest identical to validated R7.
// ---------------------------------------------------------------------------
__global__ __launch_bounds__(256) void lat_head(
        const float* __restrict__ hn, const float* __restrict__ W1,
        const float* __restrict__ b1, const float* __restrict__ W2,
        const float* __restrict__ b2, const float* __restrict__ W3,
        float* __restrict__ out) {
    __shared__ float gfl[256];
    __shared__ float h1[128];
    __shared__ float h2[64];
    int g = blockIdx.x, t = threadIdx.x;
    {
        float s = 0.f;
        for (int j = 0; j < NP; ++j) s += hn[(long)(g * NP + j) * CC + t];
        gfl[t] = s * (1.f / 24.f);
    }
    __syncthreads();
    if (t < 128) {
        float acc = 0.f;
        for (int k = 0; k < 256; ++k) acc += gfl[k] * W1[k * 128 + t];
        float v = acc;
        v += b1[t];
        v = v / (1.f + expf(-v));
        h1[t] = v;
    }
    __syncthreads();
    if (t < 64) {
        float acc = 0.f;
        for (int k = 0; k < 128; ++k) acc += h1[k] * W2[k * 64 + t];
        float v = acc;
        v += b2[t];
        v = v / (1.f + expf(-v));
        h2[t] = v;
    }
    __syncthreads();
    if (t < 9) {
        float acc = 0.f;
        for (int k = 0; k < 64; ++k) acc += h2[k] * W3[k * 9 + t];
        out[(long)g * 9 + t] = acc;
    }
}

// ---------------------------------------------------------------------------
static void gemm(hipStream_t st, const float* A, int lda, const float* W,
                 const float* bias, const float* res, float* Cf,
                 int M, int K, int Nc, int act) {
    dim3 grid(M / 64, (Nc + 63) / 64);
    gemm_k<<<grid, 256, 0, st>>>(A, lda, W, bias, res, Cf, M, K, Nc, act);
}

static void gemmM(hipStream_t st, const float* A, const bf* Wt, const float* bias,
                  const float* bias2, const float* res, float* Cf,
                  int M, int K, int N, int act) {
    dim3 grid(M / 32, N / 64);
    gemm_mfma<<<grid, 256, 0, st>>>(A, Wt, bias, bias2, res, Cf, M, K, N, act);
}

static void run_bn(hipStream_t st, const float* in, float* part,
                   const float* g_, const float* b_, const float* add, float* out) {
    bn_stats1<<<96, 256, 0, st>>>(in, part);
    bn_apply2<<<768, 256, 0, st>>>(in, part, g_, b_, add, out);
}

extern "C" void kernel_launch(void* const* d_in, const int* in_sizes, int n_in,
                              void* d_out, int out_size, void* d_ws, size_t ws_size,
                              hipStream_t stream) {
    float* out = (float*)d_out;
    int sigN = out_size < 256 ? out_size : 256;

    static const int EXP_SIZES[46] = {
        256, 18432, 2304, 25600, 131072, 256, 52992, 768, 196608, 768,
        196608, 768, 589824, 2304, 196608, 768, 393216, 1536, 393216, 768,
        768, 768, 768, 768, 768, 768, 256, 256, 32768, 128,
        12800, 100, 32768, 128, 8192, 64, 576, 32768, 128, 8192,
        64, 192, 6144, 6144, 147456, 147456 };
    if (n_in != 46) { signal_k<<<1, 256, 0, stream>>>(out, sigN, 3000.f + 8.f * n_in); return; }
    for (int i = 0; i < 46; ++i)
        if (in_sizes[i] != EXP_SIZES[i]) { signal_k<<<1, 256, 0, stream>>>(out, sigN, 512.f + 8.f * i); return; }
    if (out_size != NN * 100 + GG * 9 + NN * 3) { signal_k<<<1, 256, 0, stream>>>(out, sigN, 7777.f); return; }

    // ---- workspace (R7-exact layout) ----
    char* base = (char*)d_ws;
    int* flags = (int*)base;                       // 256 B
    float* f32a = (float*)(base + 256);
    float* x  = f32a;                              // N*256
    float* s1 = x  + (size_t)NN * 256;             // N*256
    float* s2 = s1 + (size_t)NN * 256;             // N*256
    float* big = s2 + (size_t)NN * 256;            // N*768
    float* s3 = big + (size_t)NN * 512;            // alias of big's tail (lifetimes audited)
    float* part = big + (size_t)NN * 768;          // 96*512
    float* stats = part + 96 * 512;                // 512 (unused)
    float* gf  = stats + 512;                      // G*256 (unused since R11 pool fold)
    float* l1b = gf + GG * 256;                    // G*128 (unused)
    float* l2b = l1b + GG * 128;                   // G*64  (unused)
    bf* wt = (bf*)(l2b + GG * 64);                 // bf16 W^T mirrors
    const long O_NA = 0, O_G1 = 131072, O_G2 = 327680, O_AI = 524288,
               O_AO = 1114112, O_M1 = 1310720, O_M2 = 1703936,
               O_TRO = 2097152, O_FC = 2129920, WT_TOT = 2162688;
    short* gewt_h = (short*)(wt + WT_TOT);         // 49152 shorts
    short* gewt_l = gewt_h + 49152;                // 49152 shorts
    short* et_h = gewt_l + 49152;
    short* et_l = et_h + (ETAB_ELEMS + 1024);
    size_t REQ = 256 + ((size_t)NN * 1536 + 96 * 512 + 512 + GG * 448) * 4
               + WT_TOT * 2 + 49152 * 2 * 2
               + ((size_t)ETAB_ELEMS + 1024) * 2 * 2;
    if (ws_size < REQ) { signal_k<<<1, 256, 0, stream>>>(out, sigN, 9999.f); return; }

    const float* t       = (const float*)d_in[0];
    const float* frac    = (const float*)d_in[1];
    const float* lattice = (const float*)d_in[2];
    const float* type_emb = (const float*)d_in[3];

    detect_int_k<<<1, 256, 0, stream>>>((const unsigned int*)d_in[42], flags);

    // combined weight prep (one dispatch for the 9 transposes)
    {
        TArgs ta;
        const int srcIdx[9] = {4, 8, 10, 12, 14, 16, 18, 28, 37};
        const long dof[9]  = {O_NA, O_G1, O_G2, O_AI, O_AO, O_M1, O_M2, O_TRO, O_FC};
        const int Ks[9] = {512, 256, 256, 256, 256, 256, 512, 256, 256};
        const int Ns[9] = {256, 256, 256, 768, 256, 512, 256, 128, 128};
        const int Ls[9] = {1, 3, 3, 3, 3, 3, 3, 1, 1};
        int blk = 0;
        for (int s = 0; s < 9; ++s) {
            ta.src[s] = (const float*)d_in[srcIdx[s]];
            ta.dstOff[s] = dof[s];
            ta.K[s] = Ks[s]; ta.N[s] = Ns[s]; ta.L[s] = Ls[s];
            ta.blk0[s] = blk;
            blk += (Ks[s] * Ns[s] * Ls[s] + 255) / 256;
        }
        ta.blk0[9] = blk;
        transp_all<<<blk, 256, 0, stream>>>(ta, wt);
    }
    // merged gew + etab prep (R11): blocks 0..191 gew, rest etab
    prep_gewtab<<<192 + (ETAB_ELEMS + 255) / 256, 256, 0, stream>>>(
        (const float*)d_in[6], gewt_h, gewt_l, frac, et_h, et_l);

    // x0 = concat(type_emb[atoms], time_emb) @ naW + nab
    build_A<<<(NN * 512 + 255) / 256, 256, 0, stream>>>(t, type_emb,
        (const unsigned int*)d_in[42], big, flags);
    gemmM(stream, big, wt + O_NA, (const float*)d_in[5], nullptr, nullptr, x, NN, 512, 256, 0);

    for (int l = 0; l < LL; ++l) {
        // GINE: s1 = x + aggr
        gine4<<<GG * 4, 256, 0, stream>>>(x, lattice,
            (const float*)d_in[6], (const float*)d_in[7], gewt_h, gewt_l,
            et_h, et_l, s1, l);
        // s2 = silu(s1@gW1+gb1); s3 = s2@gW2+gb2 + x; h1 = BN(s3) -> s2
        gemmM(stream, s1, wt + O_G1 + (long)l * 65536, (const float*)d_in[9]  + l * 256, nullptr, nullptr, s2, NN, 256, 256, 2);
        gemmM(stream, s2, wt + O_G2 + (long)l * 65536, (const float*)d_in[11] + l * 256, nullptr, x, s3, NN, 256, 256, 0);
        run_bn(stream, s3, part, (const float*)d_in[20] + l * 256, (const float*)d_in[21] + l * 256, nullptr, s2);
        // attention: qkv=big; o=s1; s3 = s1@aoW+aob + x; s1 = h1 + BN(s3)
        gemmM(stream, x, wt + O_AI + (long)l * 196608, (const float*)d_in[13] + l * 768, nullptr, nullptr, big, NN, 256, 768, 0);
        attn2<<<GG, 256, 0, stream>>>(big, s1);
        gemmM(stream, s1, wt + O_AO + (long)l * 65536, (const float*)d_in[15] + l * 256, nullptr, x, s3, NN, 256, 256, 0);
        run_bn(stream, s3, part, (const float*)d_in[22] + l * 256, (const float*)d_in[23] + l * 256, s2, s1);
        // MLP: big = relu(s1@mW1+mb1); s3 = big@mW2+mb2 + s1; x = BN(s3)
        gemmM(stream, s1, wt + O_M1 + (long)l * 131072, (const float*)d_in[17] + l * 512, nullptr, nullptr, big, NN, 256, 512, 1);
        gemmM(stream, big, wt + O_M2 + (long)l * 131072, (const float*)d_in[19] + l * 256, nullptr, s1, s3, NN, 512, 256, 0);
        run_bn(stream, s3, part, (const float*)d_in[24] + l * 256, (const float*)d_in[25] + l * 256, nullptr, x);
    }

    ln_kernel<<<NN, 256, 0, stream>>>(x, (const float*)d_in[26], (const float*)d_in[27], s1);

    // heads: combined TRO|FC gemm (adjacent mirrors, concat bias) -> s2 [NN x 256]
    gemmM(stream, s1, wt + O_TRO, (const float*)d_in[29], (const float*)d_in[38],
          nullptr, s2, NN, 256, 256, 2);
    // types_pred -> out[0 : N*100]   (A = s2 cols 0..127, lda=256)
    gemm(stream, s2, 256, (const float*)d_in[30], (const float*)d_in[31], nullptr, out, NN, 128, 100, 0);
    // lattice_pred -> out[N*100 : +G*9]  (pool folded into lat_head)
    lat_head<<<GG, 256, 0, stream>>>(s1, (const float*)d_in[32], (const float*)d_in[33],
        (const float*)d_in[34], (const float*)d_in[35], (const float*)d_in[36],
        out + (size_t)NN * 100);
    // frac_pred -> out[N*100+G*9 : ]  (A = s2 cols 128..255)
    gemm(stream, s2 + 128, 256, (const float*)d_in[39], (const float*)d_in[40], nullptr, s3, NN, 128, 64, 2);
    gemm(stream, s3, 64, (const float*)d_in[41], nullptr, nullptr, out + (size_t)NN * 100 + GG * 9, NN, 64, 3, 0);
}